// Round 1
// baseline (101371.228 us; speedup 1.0000x reference)
//
#include <hip/hip_runtime.h>
#include <math.h>

// LatentFNO: B=32, T=24, R=512, W=128, M=64 modes, 4 layers, 12 steps.
// Round 0: fp32 correctness-first. FFT pair replaced by exact truncated
// DFT/iDFT matmuls (only modes 0..63 are used by the reference).
// Workspace requirement: ~58 MB (see carve-up in kernel_launch).

#define NB 32
#define NR 512
#define NW 128
#define NM 64
#define NTH 24
#define NLAY 4
#define NSTEPS 12
#define SEQROWS 36   // 24 history + 12 appended steps (circular-free sliding window)

__device__ __forceinline__ float gelu_exact(float x) {
    return 0.5f * x * (1.0f + erff(x * 0.70710678118654752f));
}

// ---------------------------------------------------------------------------
// Setup: DFT/iDFT tables.
// F[mc][r], mc<64: cos(2*pi*m*r/512); mc>=64: -sin(...)   (rfft: X=sum x e^{-j.})
// G[mc][r], mc<64: c_m*cos(...); mc>=64: -c_m*sin(...), with c_0=1/512, c_m=2/512.
// G row for im(m=0) is ZERO: irfft ignores the DC imaginary part.
// ---------------------------------------------------------------------------
__global__ void build_tables_kernel(float* __restrict__ F, float* __restrict__ G) {
    int idx = blockIdx.x * 256 + threadIdx.x;   // 0..65535
    int mc = idx >> 9;
    int r = idx & 511;
    int m = mc & 63;
    int p = (m * r) & 511;                       // exact phase reduction
    float a = (float)p * (1.0f / 256.0f);        // angle in units of pi
    float c = cospif(a);
    float s = sinpif(a);
    F[idx] = (mc < 64) ? c : -s;
    float cm = (m == 0) ? (1.0f / 512.0f) : (2.0f / 512.0f);
    float g;
    if (mc < 64) g = cm * c;
    else         g = (m == 0) ? 0.0f : -cm * s;
    G[idx] = g;
}

// seq[b][t][r] (t<24) = z[b][t][r]
__global__ void init_seq_kernel(const float* __restrict__ z, float* __restrict__ seq) {
    int idx = blockIdx.x * 256 + threadIdx.x;    // < 32*24*512
    int b = idx / (NTH * NR);
    int rem = idx - b * (NTH * NR);
    seq[(size_t)b * SEQROWS * NR + rem] = z[idx];
}

// spec_w (l,i,o,m) -> Wt (l,m,i,o) so the per-mode matmul reads contiguously.
// One block per (l,i); LDS transpose of the (o=128, m=64) slab.
__global__ void transpose_specw_kernel(const float* __restrict__ wr, const float* __restrict__ wi,
                                       float* __restrict__ Wtr, float* __restrict__ Wti) {
    __shared__ float lds[64 * 129];              // [m][o], padded stride 129
    int l = blockIdx.x >> 7;
    int i = blockIdx.x & 127;
    size_t src_off = (size_t)(l * 128 + i) * (128 * 64);
    size_t dst_off = (size_t)l * 64 * 16384 + (size_t)i * 128;
    for (int pass = 0; pass < 2; pass++) {
        const float* src = (pass == 0 ? wr : wi) + src_off;
        float* dst = (pass == 0 ? Wtr : Wti) + dst_off;
        for (int t = threadIdx.x; t < 8192; t += 256) {
            int o = t >> 6, m = t & 63;
            lds[m * 129 + o] = src[t];
        }
        __syncthreads();
        for (int t = threadIdx.x; t < 8192; t += 256) {
            int m = t >> 7, o = t & 127;
            dst[(size_t)m * 16384 + o] = lds[m * 129 + o];
        }
        __syncthreads();
    }
}

// ---------------------------------------------------------------------------
// K1: fc0. h[b][w][r] = bias + sum_t seq[b][step+t][r]*W[t][w] + time/coord feats.
// grid (8 rblk, 32 b), 256 thr = 64 r-lanes x 4 w-quarters.
// ---------------------------------------------------------------------------
__global__ __launch_bounds__(256) void fc0_kernel(const float* __restrict__ seq,
        const float* __restrict__ t_grid, const float* __restrict__ fc0_w,
        const float* __restrict__ fc0_b, float* __restrict__ h, int step) {
    __shared__ float wlds[28 * 128];
    __shared__ float blds[128];
    int b = blockIdx.y, rblk = blockIdx.x;
    int tid = threadIdx.x;
    for (int t = tid; t < 28 * 128; t += 256) wlds[t] = fc0_w[t];
    if (tid < 128) blds[tid] = fc0_b[tid];
    __syncthreads();
    int lane = tid & 63, wq = tid >> 6;
    int r = rblk * 64 + lane;
    float sv[24];
    const float* sp = seq + ((size_t)b * SEQROWS + step) * NR + r;
#pragma unroll
    for (int t = 0; t < 24; t++) sv[t] = sp[(size_t)t * NR];
    float tt = t_grid[b * 24 + 23] + (float)(step + 1);
    float ang24 = 6.28318530717958647692f * tt * (1.0f / 24.0f);
    float ang168 = 6.28318530717958647692f * tt * (1.0f / 168.0f);
    float s24 = sinf(ang24), c24 = cosf(ang24), s168 = sinf(ang168);
    float xc = (float)r * (1.0f / 511.0f);
    float* outp = h + ((size_t)b * NW) * NR + r;
    for (int w0 = 0; w0 < 32; w0++) {
        int w = wq * 32 + w0;
        float acc = blds[w];
#pragma unroll
        for (int t = 0; t < 24; t++) acc += sv[t] * wlds[t * 128 + w];
        acc += s24 * wlds[24 * 128 + w] + c24 * wlds[25 * 128 + w]
             + s168 * wlds[26 * 128 + w] + xc * wlds[27 * 128 + w];
        outp[(size_t)w * NR] = acc;
    }
}

// ---------------------------------------------------------------------------
// K2: truncated DFT as GEMM. X[mc][n] = sum_r h[n][r] * F[mc][r],
// n = b*128+i (4096 rows). grid (64 n-tiles, 4 mc-tiles), 256 thr.
// Tile: 64n x 32mc, K-tile 64. LDS transposed for float4 inner reads.
// ---------------------------------------------------------------------------
__global__ __launch_bounds__(256) void dft_kernel(const float* __restrict__ hin,
        const float* __restrict__ F, float* __restrict__ X) {
    __shared__ __align__(16) float hT[64][64];   // [k][n]
    __shared__ float fT[64][33];                 // [k][mc], padded
    int ntile = blockIdx.x * 64;
    int mctile = blockIdx.y * 32;
    int tid = threadIdx.x;
    int nl = tid & 15, ml = tid >> 4;
    int n0 = nl * 4, mc0 = ml * 2;
    float acc[2][4] = {{0.f, 0.f, 0.f, 0.f}, {0.f, 0.f, 0.f, 0.f}};
    int hrow = tid >> 2, hcb = (tid & 3) * 16;
    int fr = tid >> 3, fkb = (tid & 7) * 8;
    for (int k0 = 0; k0 < 512; k0 += 64) {
        const float* hsrc = hin + (size_t)(ntile + hrow) * NR + k0 + hcb;
#pragma unroll
        for (int j = 0; j < 4; j++) {
            float4 v = *(const float4*)(hsrc + j * 4);
            hT[hcb + j * 4 + 0][hrow] = v.x;
            hT[hcb + j * 4 + 1][hrow] = v.y;
            hT[hcb + j * 4 + 2][hrow] = v.z;
            hT[hcb + j * 4 + 3][hrow] = v.w;
        }
        const float* fsrc = F + (size_t)(mctile + fr) * NR + k0 + fkb;
        float4 f0 = *(const float4*)(fsrc);
        float4 f1 = *(const float4*)(fsrc + 4);
        fT[fkb + 0][fr] = f0.x; fT[fkb + 1][fr] = f0.y;
        fT[fkb + 2][fr] = f0.z; fT[fkb + 3][fr] = f0.w;
        fT[fkb + 4][fr] = f1.x; fT[fkb + 5][fr] = f1.y;
        fT[fkb + 6][fr] = f1.z; fT[fkb + 7][fr] = f1.w;
        __syncthreads();
#pragma unroll
        for (int k = 0; k < 64; k++) {
            float4 hv = *(const float4*)&hT[k][n0];
            float fa = fT[k][mc0];
            float fb = fT[k][mc0 + 1];
            acc[0][0] += fa * hv.x; acc[0][1] += fa * hv.y;
            acc[0][2] += fa * hv.z; acc[0][3] += fa * hv.w;
            acc[1][0] += fb * hv.x; acc[1][1] += fb * hv.y;
            acc[1][2] += fb * hv.z; acc[1][3] += fb * hv.w;
        }
        __syncthreads();
    }
#pragma unroll
    for (int q = 0; q < 2; q++) {
        float4 o4 = make_float4(acc[q][0], acc[q][1], acc[q][2], acc[q][3]);
        *(float4*)(X + (size_t)(mctile + mc0 + q) * 4096 + ntile + n0) = o4;
    }
}

// ---------------------------------------------------------------------------
// K3: per-mode complex mix. Y[b][o][mc] (mc<64 re, >=64 im) =
//   sum_i X[b,i,m] * W[i,o,m] (complex). grid (64 m, 2 b-half), 256 thr.
// ---------------------------------------------------------------------------
__global__ __launch_bounds__(256) void modemix_kernel(const float* __restrict__ X,
        const float* __restrict__ Wtr, const float* __restrict__ Wti,
        float* __restrict__ Y, int layer) {
    __shared__ float xr[16 * 128];
    __shared__ float xi[16 * 128];
    __shared__ __align__(16) float wr[32][128];
    __shared__ __align__(16) float wi[32][128];
    int m = blockIdx.x, bh = blockIdx.y;
    int tid = threadIdx.x;
    const float* Xr = X + (size_t)m * 4096 + bh * 2048;
    const float* Xi = X + (size_t)(64 + m) * 4096 + bh * 2048;
    for (int t = tid; t < 2048; t += 256) { xr[t] = Xr[t]; xi[t] = Xi[t]; }
    int ol = tid & 31, bl = tid >> 5;
    int o0 = ol * 4;
    int lb0 = bl * 2;
    float ar[2][4] = {{0.f,0.f,0.f,0.f},{0.f,0.f,0.f,0.f}};
    float ai[2][4] = {{0.f,0.f,0.f,0.f},{0.f,0.f,0.f,0.f}};
    const float* wrsrc = Wtr + ((size_t)layer * 64 + m) * 16384;
    const float* wisrc = Wti + ((size_t)layer * 64 + m) * 16384;
    for (int k0 = 0; k0 < 128; k0 += 32) {
        __syncthreads();
        for (int t = tid; t < 4096; t += 256) {
            ((float*)wr)[ (t >> 7) * 128 + (t & 127) ] = wrsrc[(size_t)k0 * 128 + t];
            ((float*)wi)[ (t >> 7) * 128 + (t & 127) ] = wisrc[(size_t)k0 * 128 + t];
        }
        __syncthreads();
#pragma unroll
        for (int k = 0; k < 32; k++) {
            int kk = k0 + k;
            float x0r = xr[lb0 * 128 + kk];
            float x1r = xr[(lb0 + 1) * 128 + kk];
            float x0i = xi[lb0 * 128 + kk];
            float x1i = xi[(lb0 + 1) * 128 + kk];
            float4 wrv = *(const float4*)&wr[k][o0];
            float4 wiv = *(const float4*)&wi[k][o0];
            ar[0][0] += x0r * wrv.x - x0i * wiv.x;  ai[0][0] += x0r * wiv.x + x0i * wrv.x;
            ar[0][1] += x0r * wrv.y - x0i * wiv.y;  ai[0][1] += x0r * wiv.y + x0i * wrv.y;
            ar[0][2] += x0r * wrv.z - x0i * wiv.z;  ai[0][2] += x0r * wiv.z + x0i * wrv.z;
            ar[0][3] += x0r * wrv.w - x0i * wiv.w;  ai[0][3] += x0r * wiv.w + x0i * wrv.w;
            ar[1][0] += x1r * wrv.x - x1i * wiv.x;  ai[1][0] += x1r * wiv.x + x1i * wrv.x;
            ar[1][1] += x1r * wrv.y - x1i * wiv.y;  ai[1][1] += x1r * wiv.y + x1i * wrv.y;
            ar[1][2] += x1r * wrv.z - x1i * wiv.z;  ai[1][2] += x1r * wiv.z + x1i * wrv.z;
            ar[1][3] += x1r * wrv.w - x1i * wiv.w;  ai[1][3] += x1r * wiv.w + x1i * wrv.w;
        }
    }
    int bglob = bh * 16 + lb0;
#pragma unroll
    for (int bb = 0; bb < 2; bb++) {
#pragma unroll
        for (int j = 0; j < 4; j++) {
            size_t base = ((size_t)(bglob + bb) * 128 + (o0 + j)) * 128;
            Y[base + m] = ar[bb][j];
            Y[base + 64 + m] = ai[bb][j];
        }
    }
}

// ---------------------------------------------------------------------------
// K4: iDFT + pointwise conv + bias + GELU.
// out[b][o][r] = gelu( sum_mc Y[b,o,mc]*G[mc][r] + sum_i cw[o,i]*h[b,i,r] + cb[o] )
// grid (8 r-tiles, 4 o-tiles, 32 b), 256 thr, K staged in 32-chunks.
// ---------------------------------------------------------------------------
__global__ __launch_bounds__(256) void idft_conv_kernel(const float* __restrict__ Y,
        const float* __restrict__ G, const float* __restrict__ hin,
        const float* __restrict__ conv_w, const float* __restrict__ conv_b,
        float* __restrict__ hout, int layer) {
    __shared__ float ldsY[32 * 130];
    __shared__ float ldsC[32 * 130];
    __shared__ __align__(16) float ldsK[32][64];
    int rt = blockIdx.x * 64, ot = blockIdx.y * 32, b = blockIdx.z;
    int tid = threadIdx.x;
    for (int t = tid; t < 4096; t += 256) {
        int o = t >> 7, c = t & 127;
        ldsY[o * 130 + c] = Y[((size_t)b * 128 + ot) * 128 + t];
        ldsC[o * 130 + c] = conv_w[((size_t)layer * 128 + ot) * 128 + t];
    }
    int rl = tid & 15, og = tid >> 4;
    int r0 = rl * 4, o0 = og * 2;
    float acc[2][4] = {{0.f,0.f,0.f,0.f},{0.f,0.f,0.f,0.f}};
    // iDFT over 128 mc
    for (int ch = 0; ch < 4; ch++) {
        __syncthreads();
        for (int t = tid; t < 2048; t += 256) {
            int kk = t >> 6, c = t & 63;
            ldsK[kk][c] = G[(size_t)(ch * 32 + kk) * NR + rt + c];
        }
        __syncthreads();
#pragma unroll
        for (int k = 0; k < 32; k++) {
            int mc = ch * 32 + k;
            float4 g4 = *(const float4*)&ldsK[k][r0];
            float y0 = ldsY[o0 * 130 + mc];
            float y1 = ldsY[(o0 + 1) * 130 + mc];
            acc[0][0] += y0 * g4.x; acc[0][1] += y0 * g4.y;
            acc[0][2] += y0 * g4.z; acc[0][3] += y0 * g4.w;
            acc[1][0] += y1 * g4.x; acc[1][1] += y1 * g4.y;
            acc[1][2] += y1 * g4.z; acc[1][3] += y1 * g4.w;
        }
    }
    // pointwise conv over 128 i
    for (int ch = 0; ch < 4; ch++) {
        __syncthreads();
        for (int t = tid; t < 2048; t += 256) {
            int kk = t >> 6, c = t & 63;
            ldsK[kk][c] = hin[((size_t)b * 128 + ch * 32 + kk) * NR + rt + c];
        }
        __syncthreads();
#pragma unroll
        for (int k = 0; k < 32; k++) {
            int i = ch * 32 + k;
            float4 h4 = *(const float4*)&ldsK[k][r0];
            float c0 = ldsC[o0 * 130 + i];
            float c1 = ldsC[(o0 + 1) * 130 + i];
            acc[0][0] += c0 * h4.x; acc[0][1] += c0 * h4.y;
            acc[0][2] += c0 * h4.z; acc[0][3] += c0 * h4.w;
            acc[1][0] += c1 * h4.x; acc[1][1] += c1 * h4.y;
            acc[1][2] += c1 * h4.z; acc[1][3] += c1 * h4.w;
        }
    }
#pragma unroll
    for (int q = 0; q < 2; q++) {
        float cb = conv_b[layer * 128 + ot + o0 + q];
        float4 o4;
        o4.x = gelu_exact(acc[q][0] + cb);
        o4.y = gelu_exact(acc[q][1] + cb);
        o4.z = gelu_exact(acc[q][2] + cb);
        o4.w = gelu_exact(acc[q][3] + cb);
        *(float4*)(hout + ((size_t)b * 128 + ot + o0 + q) * NR + rt + r0) = o4;
    }
}

// ---------------------------------------------------------------------------
// K5: head. dx[b][r] = fc2( gelu(fc1(h[b,:,r])) ); z_next = seq[last] + dx.
// Writes z_next into seq row (step+24) and into preds.
// grid (8 r-tiles, 32 b), 256 thr = 64 r-lanes x 4 j-groups.
// ---------------------------------------------------------------------------
__global__ __launch_bounds__(256) void head_kernel(const float* __restrict__ hin,
        const float* __restrict__ fc1_w, const float* __restrict__ fc1_b,
        const float* __restrict__ fc2_w, const float* __restrict__ fc2_b,
        float* __restrict__ seq, float* __restrict__ preds, int step) {
    __shared__ float ldsH[128][64];
    __shared__ __align__(16) float ldsW[128][64];
    int rt = blockIdx.x * 64, b = blockIdx.y;
    int tid = threadIdx.x;
    int rl = tid & 63, jg = tid >> 6;
    for (int t = tid; t < 8192; t += 256) {
        int w = t >> 6, c = t & 63;
        ldsH[w][c] = hin[((size_t)b * 128 + w) * NR + rt + c];
    }
    float dx = 0.0f;
    for (int jt = 0; jt < 4; jt++) {
        __syncthreads();
        for (int t = tid; t < 8192; t += 256) {
            int w = t >> 6, c = t & 63;
            ldsW[w][c] = fc1_w[(size_t)w * 256 + jt * 64 + c];
        }
        __syncthreads();
        float accj[16];
        int jb = jt * 64 + jg * 16;
#pragma unroll
        for (int jj = 0; jj < 16; jj++) accj[jj] = fc1_b[jb + jj];
        for (int w = 0; w < 128; w++) {
            float hv = ldsH[w][rl];
            const float* wp = &ldsW[w][jg * 16];
            float4 w0 = *(const float4*)(wp);
            float4 w1 = *(const float4*)(wp + 4);
            float4 w2 = *(const float4*)(wp + 8);
            float4 w3 = *(const float4*)(wp + 12);
            accj[0]  += hv * w0.x; accj[1]  += hv * w0.y;
            accj[2]  += hv * w0.z; accj[3]  += hv * w0.w;
            accj[4]  += hv * w1.x; accj[5]  += hv * w1.y;
            accj[6]  += hv * w1.z; accj[7]  += hv * w1.w;
            accj[8]  += hv * w2.x; accj[9]  += hv * w2.y;
            accj[10] += hv * w2.z; accj[11] += hv * w2.w;
            accj[12] += hv * w3.x; accj[13] += hv * w3.y;
            accj[14] += hv * w3.z; accj[15] += hv * w3.w;
        }
#pragma unroll
        for (int jj = 0; jj < 16; jj++) {
            dx += gelu_exact(accj[jj]) * fc2_w[jb + jj];
        }
    }
    // reduce the 4 j-group partials per r (reuse ldsW as scratch after sync)
    __syncthreads();
    float* red = (float*)ldsW;
    red[jg * 64 + rl] = dx;
    __syncthreads();
    if (jg == 0) {
        float s = red[rl] + red[64 + rl] + red[128 + rl] + red[192 + rl] + fc2_b[0];
        int r = rt + rl;
        float zn = seq[((size_t)b * SEQROWS + step + 23) * NR + r] + s;
        seq[((size_t)b * SEQROWS + step + 24) * NR + r] = zn;
        preds[((size_t)b * NSTEPS + step) * NR + r] = zn;
    }
}

// ---------------------------------------------------------------------------
extern "C" void kernel_launch(void* const* d_in, const int* in_sizes, int n_in,
                              void* d_out, int out_size, void* d_ws, size_t ws_size,
                              hipStream_t stream) {
    (void)in_sizes; (void)n_in; (void)out_size; (void)ws_size;
    const float* z       = (const float*)d_in[0];
    const float* t_grid  = (const float*)d_in[1];
    const float* fc0_w   = (const float*)d_in[2];
    const float* fc0_b   = (const float*)d_in[3];
    const float* spec_wr = (const float*)d_in[4];
    const float* spec_wi = (const float*)d_in[5];
    const float* conv_w  = (const float*)d_in[6];
    const float* conv_b  = (const float*)d_in[7];
    const float* fc1_w   = (const float*)d_in[8];
    const float* fc1_b   = (const float*)d_in[9];
    const float* fc2_w   = (const float*)d_in[10];
    const float* fc2_b   = (const float*)d_in[11];
    float* preds = (float*)d_out;

    // workspace carve-up (floats); total ~57.4M floats (~58 MB)
    float* p = (float*)d_ws;
    float* seq = p;  p += (size_t)NB * SEQROWS * NR;       // 589824
    float* hA  = p;  p += (size_t)NB * NW * NR;            // 2097152
    float* hB  = p;  p += (size_t)NB * NW * NR;            // 2097152
    float* X   = p;  p += (size_t)128 * 4096;              // 524288
    float* Yb  = p;  p += (size_t)NB * NW * 128;           // 524288
    float* F   = p;  p += (size_t)128 * 512;               // 65536
    float* G   = p;  p += (size_t)128 * 512;               // 65536
    float* Wtr = p;  p += (size_t)NLAY * NM * NW * NW;     // 4194304
    float* Wti = p;  p += (size_t)NLAY * NM * NW * NW;     // 4194304

    build_tables_kernel<<<256, 256, 0, stream>>>(F, G);
    transpose_specw_kernel<<<512, 256, 0, stream>>>(spec_wr, spec_wi, Wtr, Wti);
    init_seq_kernel<<<(NB * NTH * NR) / 256, 256, 0, stream>>>(z, seq);

    for (int step = 0; step < NSTEPS; step++) {
        fc0_kernel<<<dim3(8, 32), 256, 0, stream>>>(seq, t_grid, fc0_w, fc0_b, hA, step);
        float* hin = hA;
        float* hout = hB;
        for (int l = 0; l < NLAY; l++) {
            dft_kernel<<<dim3(64, 4), 256, 0, stream>>>(hin, F, X);
            modemix_kernel<<<dim3(64, 2), 256, 0, stream>>>(X, Wtr, Wti, Yb, l);
            idft_conv_kernel<<<dim3(8, 4, 32), 256, 0, stream>>>(Yb, G, hin, conv_w, conv_b, hout, l);
            float* t = hin; hin = hout; hout = t;
        }
        // after 4 layers, hin == hA
        head_kernel<<<dim3(8, 32), 256, 0, stream>>>(hin, fc1_w, fc1_b, fc2_w, fc2_b,
                                                     seq, preds, step);
    }
}

// Round 2
// 4630.897 us; speedup vs baseline: 21.8902x; 21.8902x over previous
//
#include <hip/hip_runtime.h>
#include <math.h>

// LatentFNO: B=32, T=24, R=512, W=128, M=64 modes, 4 layers, 12 steps.
// Round 1: fp32, spill-free rewrite. Round-0 failure mode: fully-unrolled
// inner loops hoisted LDS loads past the 256-VGPR cap -> scratch thrash
// (2.2 GB HBM fetch/dispatch, VALUBusy 1%). All hot loops now use bounded
// unrolls; iDFT+conv fused into one K=256 GEMM; modemix writes coalesced.

#define NB 32
#define NR 512
#define NW 128
#define NM 64
#define NTH 24
#define NLAY 4
#define NSTEPS 12
#define SEQROWS 36   // 24 history + 12 appended steps

__device__ __forceinline__ float gelu_exact(float x) {
    return 0.5f * x * (1.0f + erff(x * 0.70710678118654752f));
}

// ---------------------------------------------------------------------------
// Setup: DFT/iDFT tables.
// F[mc][r], mc<64: cos(2*pi*m*r/512); mc>=64: -sin(...)
// G[mc][r], mc<64: c_m*cos(...); mc>=64: -c_m*sin(...), c_0=1/512, c_m=2/512.
// G row for im(m=0) is ZERO (irfft ignores DC imaginary part).
// ---------------------------------------------------------------------------
__global__ void build_tables_kernel(float* __restrict__ F, float* __restrict__ G) {
    int idx = blockIdx.x * 256 + threadIdx.x;   // 0..65535
    int mc = idx >> 9;
    int r = idx & 511;
    int m = mc & 63;
    int p = (m * r) & 511;
    float a = (float)p * (1.0f / 256.0f);        // angle in units of pi
    float c = cospif(a);
    float s = sinpif(a);
    F[idx] = (mc < 64) ? c : -s;
    float cm = (m == 0) ? (1.0f / 512.0f) : (2.0f / 512.0f);
    float g;
    if (mc < 64) g = cm * c;
    else         g = (m == 0) ? 0.0f : -cm * s;
    G[idx] = g;
}

__global__ void init_seq_kernel(const float* __restrict__ z, float* __restrict__ seq) {
    int idx = blockIdx.x * 256 + threadIdx.x;    // < 32*24*512
    int b = idx / (NTH * NR);
    int rem = idx - b * (NTH * NR);
    seq[(size_t)b * SEQROWS * NR + rem] = z[idx];
}

// spec_w (l,i,o,m) -> Wt (l,m,i,o)
__global__ void transpose_specw_kernel(const float* __restrict__ wr, const float* __restrict__ wi,
                                       float* __restrict__ Wtr, float* __restrict__ Wti) {
    __shared__ float lds[64 * 129];
    int l = blockIdx.x >> 7;
    int i = blockIdx.x & 127;
    size_t src_off = (size_t)(l * 128 + i) * (128 * 64);
    size_t dst_off = (size_t)l * 64 * 16384 + (size_t)i * 128;
    for (int pass = 0; pass < 2; pass++) {
        const float* src = (pass == 0 ? wr : wi) + src_off;
        float* dst = (pass == 0 ? Wtr : Wti) + dst_off;
        for (int t = threadIdx.x; t < 8192; t += 256) {
            int o = t >> 6, m = t & 63;
            lds[m * 129 + o] = src[t];
        }
        __syncthreads();
        for (int t = threadIdx.x; t < 8192; t += 256) {
            int m = t >> 7, o = t & 127;
            dst[(size_t)m * 16384 + o] = lds[m * 129 + o];
        }
        __syncthreads();
    }
}

// ---------------------------------------------------------------------------
// K1: fc0. h[b][w][r] = bias + sum_t seq[b][step+t][r]*W[t][w] + feats.
// grid (8 rblk, 32 b), 256 thr.
// ---------------------------------------------------------------------------
__global__ __launch_bounds__(256) void fc0_kernel(const float* __restrict__ seq,
        const float* __restrict__ t_grid, const float* __restrict__ fc0_w,
        const float* __restrict__ fc0_b, float* __restrict__ h, int step) {
    __shared__ float wlds[28 * 128];
    __shared__ float blds[128];
    int b = blockIdx.y, rblk = blockIdx.x;
    int tid = threadIdx.x;
    for (int t = tid; t < 28 * 128; t += 256) wlds[t] = fc0_w[t];
    if (tid < 128) blds[tid] = fc0_b[tid];
    __syncthreads();
    int lane = tid & 63, wq = tid >> 6;
    int r = rblk * 64 + lane;
    float sv[24];
    const float* sp = seq + ((size_t)b * SEQROWS + step) * NR + r;
#pragma unroll
    for (int t = 0; t < 24; t++) sv[t] = sp[(size_t)t * NR];
    float tt = t_grid[b * 24 + 23] + (float)(step + 1);
    float ang24 = 6.28318530717958647692f * tt * (1.0f / 24.0f);
    float ang168 = 6.28318530717958647692f * tt * (1.0f / 168.0f);
    float s24 = sinf(ang24), c24 = cosf(ang24), s168 = sinf(ang168);
    float xc = (float)r * (1.0f / 511.0f);
    float* outp = h + ((size_t)b * NW) * NR + r;
#pragma unroll 2
    for (int w0 = 0; w0 < 32; w0++) {
        int w = wq * 32 + w0;
        float acc = blds[w];
#pragma unroll
        for (int t = 0; t < 24; t++) acc += sv[t] * wlds[t * 128 + w];
        acc += s24 * wlds[24 * 128 + w] + c24 * wlds[25 * 128 + w]
             + s168 * wlds[26 * 128 + w] + xc * wlds[27 * 128 + w];
        outp[(size_t)w * NR] = acc;
    }
}

// ---------------------------------------------------------------------------
// K2: truncated DFT. X[mc][n] = sum_r h[n][r]*F[mc][r], n = b*128+i.
// grid (64 n-tiles, 4 mc-tiles), 256 thr. Tile 64n x 32mc, K-chunk 64.
// ---------------------------------------------------------------------------
__global__ __launch_bounds__(256) void dft_kernel(const float* __restrict__ hin,
        const float* __restrict__ F, float* __restrict__ X) {
    __shared__ __align__(16) float hT[64][64];   // [k][n]
    __shared__ float fT[64][33];                 // [k][mc]
    int ntile = blockIdx.x * 64;
    int mctile = blockIdx.y * 32;
    int tid = threadIdx.x;
    int nl = tid & 15, ml = tid >> 4;
    int n0 = nl * 4, mc0 = ml * 2;
    float acc[2][4] = {{0.f, 0.f, 0.f, 0.f}, {0.f, 0.f, 0.f, 0.f}};
    int hrow = tid >> 2, hcb = (tid & 3) * 16;
    int fr = tid >> 3, fkb = (tid & 7) * 8;
    for (int k0 = 0; k0 < 512; k0 += 64) {
        const float* hsrc = hin + (size_t)(ntile + hrow) * NR + k0 + hcb;
#pragma unroll
        for (int j = 0; j < 4; j++) {
            float4 v = *(const float4*)(hsrc + j * 4);
            hT[hcb + j * 4 + 0][hrow] = v.x;
            hT[hcb + j * 4 + 1][hrow] = v.y;
            hT[hcb + j * 4 + 2][hrow] = v.z;
            hT[hcb + j * 4 + 3][hrow] = v.w;
        }
        const float* fsrc = F + (size_t)(mctile + fr) * NR + k0 + fkb;
        float4 f0 = *(const float4*)(fsrc);
        float4 f1 = *(const float4*)(fsrc + 4);
        fT[fkb + 0][fr] = f0.x; fT[fkb + 1][fr] = f0.y;
        fT[fkb + 2][fr] = f0.z; fT[fkb + 3][fr] = f0.w;
        fT[fkb + 4][fr] = f1.x; fT[fkb + 5][fr] = f1.y;
        fT[fkb + 6][fr] = f1.z; fT[fkb + 7][fr] = f1.w;
        __syncthreads();
#pragma unroll 4
        for (int k = 0; k < 64; k++) {
            float4 hv = *(const float4*)&hT[k][n0];
            float fa = fT[k][mc0];
            float fb = fT[k][mc0 + 1];
            acc[0][0] += fa * hv.x; acc[0][1] += fa * hv.y;
            acc[0][2] += fa * hv.z; acc[0][3] += fa * hv.w;
            acc[1][0] += fb * hv.x; acc[1][1] += fb * hv.y;
            acc[1][2] += fb * hv.z; acc[1][3] += fb * hv.w;
        }
        __syncthreads();
    }
#pragma unroll
    for (int q = 0; q < 2; q++) {
        float4 o4 = make_float4(acc[q][0], acc[q][1], acc[q][2], acc[q][3]);
        *(float4*)(X + (size_t)(mctile + mc0 + q) * 4096 + ntile + n0) = o4;
    }
}

// ---------------------------------------------------------------------------
// K3: per-mode complex mix. YT[b][mc][o] (mc<64 re, >=64 im) =
//   sum_i X[b,i,m]*W[i,o,m] (complex). grid (64 m, 4 bq), 256 thr.
// Per thread: 1 b x 4 o complex. W streamed in 16-i chunks.
// ---------------------------------------------------------------------------
__global__ __launch_bounds__(256) void modemix_kernel(const float* __restrict__ X,
        const float* __restrict__ Wtr, const float* __restrict__ Wti,
        float* __restrict__ YT, int layer) {
    __shared__ float xr[8 * 128];
    __shared__ float xi[8 * 128];
    __shared__ __align__(16) float wr[16][128];
    __shared__ __align__(16) float wi[16][128];
    int m = blockIdx.x, bq = blockIdx.y;
    int tid = threadIdx.x;
    const float* Xr = X + (size_t)m * 4096 + bq * 1024;
    const float* Xi = X + (size_t)(64 + m) * 4096 + bq * 1024;
    for (int t = tid; t < 1024; t += 256) { xr[t] = Xr[t]; xi[t] = Xi[t]; }
    int ol = tid & 31, bl = tid >> 5;
    int o0 = ol * 4;
    float ar[4] = {0.f, 0.f, 0.f, 0.f};
    float ai[4] = {0.f, 0.f, 0.f, 0.f};
    const float* wrsrc = Wtr + ((size_t)layer * 64 + m) * 16384;
    const float* wisrc = Wti + ((size_t)layer * 64 + m) * 16384;
    for (int k0 = 0; k0 < 128; k0 += 16) {
        __syncthreads();
        for (int t = tid; t < 2048; t += 256) {
            wr[t >> 7][t & 127] = wrsrc[(size_t)k0 * 128 + t];
            wi[t >> 7][t & 127] = wisrc[(size_t)k0 * 128 + t];
        }
        __syncthreads();
#pragma unroll 4
        for (int k = 0; k < 16; k++) {
            int kk = k0 + k;
            float x0r = xr[bl * 128 + kk];
            float x0i = xi[bl * 128 + kk];
            float4 wrv = *(const float4*)&wr[k][o0];
            float4 wiv = *(const float4*)&wi[k][o0];
            ar[0] += x0r * wrv.x - x0i * wiv.x;  ai[0] += x0r * wiv.x + x0i * wrv.x;
            ar[1] += x0r * wrv.y - x0i * wiv.y;  ai[1] += x0r * wiv.y + x0i * wrv.y;
            ar[2] += x0r * wrv.z - x0i * wiv.z;  ai[2] += x0r * wiv.z + x0i * wrv.z;
            ar[3] += x0r * wrv.w - x0i * wiv.w;  ai[3] += x0r * wiv.w + x0i * wrv.w;
        }
    }
    int b = bq * 8 + bl;
    float4 rr = make_float4(ar[0], ar[1], ar[2], ar[3]);
    float4 ii = make_float4(ai[0], ai[1], ai[2], ai[3]);
    *(float4*)(YT + ((size_t)b * 128 + m) * 128 + o0) = rr;
    *(float4*)(YT + ((size_t)b * 128 + 64 + m) * 128 + o0) = ii;
}

// ---------------------------------------------------------------------------
// K4: fused iDFT + pointwise conv + bias + GELU as ONE K=256 GEMM.
// out[b][o][r] = gelu( sum_{k<128} YT[b][k][o]*G[k][r]
//                    + sum_{k>=128} convT[k-128][o]*hin[b][k-128][r] + cb[o] )
// grid (8 r-tiles, 4 o-tiles, 32 b), 256 thr. A staged once ([k][o], pad 33),
// B streamed in 32-k chunks.
// ---------------------------------------------------------------------------
__global__ __launch_bounds__(256) void idft_conv_kernel(const float* __restrict__ YT,
        const float* __restrict__ G, const float* __restrict__ hin,
        const float* __restrict__ conv_w, const float* __restrict__ conv_b,
        float* __restrict__ hout, int layer) {
    __shared__ float ldsA[256][33];              // [k][o], 33.8 KB
    __shared__ __align__(16) float ldsB[32][64]; // [k][r], 8 KB
    int rt = blockIdx.x * 64, ot = blockIdx.y * 32, b = blockIdx.z;
    int tid = threadIdx.x;
    // A part 1: k<128 from YT[b][mc][ot..ot+32)
    for (int t = tid; t < 4096; t += 256) {
        int mc = t >> 5, o = t & 31;
        ldsA[mc][o] = YT[((size_t)b * 128 + mc) * 128 + ot + o];
    }
    // A part 2: k>=128 from conv_w[l][ot+o][i], transposed into [128+i][o]
    for (int t = tid; t < 4096; t += 256) {
        int o = t >> 7, i = t & 127;
        ldsA[128 + i][o] = conv_w[((size_t)layer * 128 + ot + o) * 128 + i];
    }
    int rl = tid & 15, og = tid >> 4;
    int r0 = rl * 4, o0 = og * 2;
    float acc[2][4] = {{0.f, 0.f, 0.f, 0.f}, {0.f, 0.f, 0.f, 0.f}};
    for (int ch = 0; ch < 8; ch++) {
        __syncthreads();
        const float* bsrc = (ch < 4)
            ? (G + (size_t)(ch * 32) * NR + rt)
            : (hin + ((size_t)b * 128 + (ch - 4) * 32) * NR + rt);
        for (int t = tid; t < 2048; t += 256) {
            int kk = t >> 6, c = t & 63;
            ldsB[kk][c] = bsrc[(size_t)kk * NR + c];
        }
        __syncthreads();
        int kbase = ch * 32;
#pragma unroll 4
        for (int k = 0; k < 32; k++) {
            float4 b4 = *(const float4*)&ldsB[k][r0];
            float a0 = ldsA[kbase + k][o0];
            float a1 = ldsA[kbase + k][o0 + 1];
            acc[0][0] += a0 * b4.x; acc[0][1] += a0 * b4.y;
            acc[0][2] += a0 * b4.z; acc[0][3] += a0 * b4.w;
            acc[1][0] += a1 * b4.x; acc[1][1] += a1 * b4.y;
            acc[1][2] += a1 * b4.z; acc[1][3] += a1 * b4.w;
        }
    }
#pragma unroll
    for (int q = 0; q < 2; q++) {
        float cb = conv_b[layer * 128 + ot + o0 + q];
        float4 o4;
        o4.x = gelu_exact(acc[q][0] + cb);
        o4.y = gelu_exact(acc[q][1] + cb);
        o4.z = gelu_exact(acc[q][2] + cb);
        o4.w = gelu_exact(acc[q][3] + cb);
        *(float4*)(hout + ((size_t)b * 128 + ot + o0 + q) * NR + rt + r0) = o4;
    }
}

// ---------------------------------------------------------------------------
// K5: head. dx[b][r] = fc2( gelu(fc1(h[b,:,r])) ); z_next = seq[last] + dx.
// grid (8 r-tiles, 32 b), 256 thr = 64 r-lanes x 4 j-groups.
// ---------------------------------------------------------------------------
__global__ __launch_bounds__(256) void head_kernel(const float* __restrict__ hin,
        const float* __restrict__ fc1_w, const float* __restrict__ fc1_b,
        const float* __restrict__ fc2_w, const float* __restrict__ fc2_b,
        float* __restrict__ seq, float* __restrict__ preds, int step) {
    __shared__ float ldsH[128][64];
    __shared__ __align__(16) float ldsW[128][64];
    int rt = blockIdx.x * 64, b = blockIdx.y;
    int tid = threadIdx.x;
    int rl = tid & 63, jg = tid >> 6;
    for (int t = tid; t < 8192; t += 256) {
        int w = t >> 6, c = t & 63;
        ldsH[w][c] = hin[((size_t)b * 128 + w) * NR + rt + c];
    }
    float dx = 0.0f;
    for (int jt = 0; jt < 4; jt++) {
        __syncthreads();
        for (int t = tid; t < 8192; t += 256) {
            int w = t >> 6, c = t & 63;
            ldsW[w][c] = fc1_w[(size_t)w * 256 + jt * 64 + c];
        }
        __syncthreads();
        float accj[16];
        int jb = jt * 64 + jg * 16;
#pragma unroll
        for (int jj = 0; jj < 16; jj++) accj[jj] = fc1_b[jb + jj];
#pragma unroll 8
        for (int w = 0; w < 128; w++) {
            float hv = ldsH[w][rl];
            const float* wp = &ldsW[w][jg * 16];
            float4 w0 = *(const float4*)(wp);
            float4 w1 = *(const float4*)(wp + 4);
            float4 w2 = *(const float4*)(wp + 8);
            float4 w3 = *(const float4*)(wp + 12);
            accj[0]  += hv * w0.x; accj[1]  += hv * w0.y;
            accj[2]  += hv * w0.z; accj[3]  += hv * w0.w;
            accj[4]  += hv * w1.x; accj[5]  += hv * w1.y;
            accj[6]  += hv * w1.z; accj[7]  += hv * w1.w;
            accj[8]  += hv * w2.x; accj[9]  += hv * w2.y;
            accj[10] += hv * w2.z; accj[11] += hv * w2.w;
            accj[12] += hv * w3.x; accj[13] += hv * w3.y;
            accj[14] += hv * w3.z; accj[15] += hv * w3.w;
        }
#pragma unroll
        for (int jj = 0; jj < 16; jj++) {
            dx += gelu_exact(accj[jj]) * fc2_w[jb + jj];
        }
    }
    __syncthreads();
    float* red = (float*)ldsW;
    red[jg * 64 + rl] = dx;
    __syncthreads();
    if (jg == 0) {
        float s = red[rl] + red[64 + rl] + red[128 + rl] + red[192 + rl] + fc2_b[0];
        int r = rt + rl;
        float zn = seq[((size_t)b * SEQROWS + step + 23) * NR + r] + s;
        seq[((size_t)b * SEQROWS + step + 24) * NR + r] = zn;
        preds[((size_t)b * NSTEPS + step) * NR + r] = zn;
    }
}

// ---------------------------------------------------------------------------
extern "C" void kernel_launch(void* const* d_in, const int* in_sizes, int n_in,
                              void* d_out, int out_size, void* d_ws, size_t ws_size,
                              hipStream_t stream) {
    (void)in_sizes; (void)n_in; (void)out_size; (void)ws_size;
    const float* z       = (const float*)d_in[0];
    const float* t_grid  = (const float*)d_in[1];
    const float* fc0_w   = (const float*)d_in[2];
    const float* fc0_b   = (const float*)d_in[3];
    const float* spec_wr = (const float*)d_in[4];
    const float* spec_wi = (const float*)d_in[5];
    const float* conv_w  = (const float*)d_in[6];
    const float* conv_b  = (const float*)d_in[7];
    const float* fc1_w   = (const float*)d_in[8];
    const float* fc1_b   = (const float*)d_in[9];
    const float* fc2_w   = (const float*)d_in[10];
    const float* fc2_b   = (const float*)d_in[11];
    float* preds = (float*)d_out;

    float* p = (float*)d_ws;
    float* seq = p;  p += (size_t)NB * SEQROWS * NR;       // 589824
    float* hA  = p;  p += (size_t)NB * NW * NR;            // 2097152
    float* hB  = p;  p += (size_t)NB * NW * NR;            // 2097152
    float* X   = p;  p += (size_t)128 * 4096;              // 524288
    float* Yb  = p;  p += (size_t)NB * NW * 128;           // 524288
    float* F   = p;  p += (size_t)128 * 512;               // 65536
    float* G   = p;  p += (size_t)128 * 512;               // 65536
    float* Wtr = p;  p += (size_t)NLAY * NM * NW * NW;     // 4194304
    float* Wti = p;  p += (size_t)NLAY * NM * NW * NW;     // 4194304

    build_tables_kernel<<<256, 256, 0, stream>>>(F, G);
    transpose_specw_kernel<<<512, 256, 0, stream>>>(spec_wr, spec_wi, Wtr, Wti);
    init_seq_kernel<<<(NB * NTH * NR) / 256, 256, 0, stream>>>(z, seq);

    for (int step = 0; step < NSTEPS; step++) {
        fc0_kernel<<<dim3(8, 32), 256, 0, stream>>>(seq, t_grid, fc0_w, fc0_b, hA, step);
        float* hin = hA;
        float* hout = hB;
        for (int l = 0; l < NLAY; l++) {
            dft_kernel<<<dim3(64, 4), 256, 0, stream>>>(hin, F, X);
            modemix_kernel<<<dim3(64, 4), 256, 0, stream>>>(X, Wtr, Wti, Yb, l);
            idft_conv_kernel<<<dim3(8, 4, 32), 256, 0, stream>>>(Yb, G, hin, conv_w, conv_b, hout, l);
            float* t = hin; hin = hout; hout = t;
        }
        head_kernel<<<dim3(8, 32), 256, 0, stream>>>(hin, fc1_w, fc1_b, fc2_w, fc2_b,
                                                     seq, preds, step);
    }
}

// Round 3
// 2884.306 us; speedup vs baseline: 35.1458x; 1.6055x over previous
//
#include <hip/hip_runtime.h>
#include <math.h>

// LatentFNO: B=32, T=24, R=512, W=128, M=64 modes, 4 layers, 12 steps.
// Round 2: spectral path (dft / modemix / idft+conv) converted to bf16 MFMA
// with exact 3-term split precision (A1B1 + A1B2 + A2B1; per-product error
// ~3*2^-16 relative => fp32-grade through the 12-step feedback).
// h lives ONLY as bf16 hi/lo planes ht[b][r][c] (transposed), double-buffered.
// fc0 / head remain fp32 (15% of flops), head reads the planes.

#define NB 32
#define NR 512
#define NW 128
#define NM 64
#define NTH 24
#define NLAY 4
#define NSTEPS 12
#define SEQROWS 36

typedef unsigned short u16;
typedef __attribute__((ext_vector_type(8))) short bf16x8;
typedef __attribute__((ext_vector_type(4))) float f32x4;
#define MFMA16(a, b, c) __builtin_amdgcn_mfma_f32_16x16x32_bf16((a), (b), (c), 0, 0, 0)

__device__ __forceinline__ float gelu_exact(float x) {
    return 0.5f * x * (1.0f + erff(x * 0.70710678118654752f));
}
__device__ __forceinline__ float bf2f(u16 u) {
    union { unsigned int i; float f; } v; v.i = ((unsigned int)u) << 16; return v.f;
}
__device__ __forceinline__ u16 f2bf_hi(float x) {
    union { float f; unsigned int i; } v; v.f = x; return (u16)(v.i >> 16);
}
__device__ __forceinline__ u16 f2bf_lo(float x) {
    float h = bf2f(f2bf_hi(x));
    return f2bf_hi(x - h);
}
__device__ __forceinline__ bf16x8 negbf(bf16x8 a) {
#pragma unroll
    for (int i = 0; i < 8; i++) a[i] ^= (short)0x8000;
    return a;
}

// ---------------------------------------------------------------------------
// Tables: F planes [mc=128][r=512] (A for dft): mc<64 cos(2pi m r/512), >=64 -sin.
// GT planes [r=512][mc=128] (B^T for idft): mc<64 c_m cos, >=64 -c_m sin,
// c_0=1/512 else 2/512; im-DC row zero (irfft drops DC imag).
// ---------------------------------------------------------------------------
__global__ void build_tables_planes(u16* __restrict__ f1, u16* __restrict__ f2,
                                    u16* __restrict__ gt1, u16* __restrict__ gt2) {
    int idx = blockIdx.x * 256 + threadIdx.x;   // 65536: mc*512 + r
    int mc = idx >> 9, r = idx & 511, m = mc & 63;
    int p = (m * r) & 511;
    float a = (float)p * (1.0f / 256.0f);
    float c = cospif(a), s = sinpif(a);
    float Fv = (mc < 64) ? c : -s;
    float cm = (m == 0) ? (1.0f / 512.0f) : (2.0f / 512.0f);
    float Gv = (mc < 64) ? cm * c : ((m == 0) ? 0.0f : -cm * s);
    f1[idx] = f2bf_hi(Fv); f2[idx] = f2bf_lo(Fv);
    size_t g = (size_t)r * 128 + mc;
    gt1[g] = f2bf_hi(Gv); gt2[g] = f2bf_lo(Gv);
}

// spec_w (l,i,o,m) -> planes [l][m][o][i] hi/lo for re and im
__global__ void prep_specw(const float* __restrict__ wr, const float* __restrict__ wi,
                           u16* __restrict__ wr1, u16* __restrict__ wr2,
                           u16* __restrict__ wi1, u16* __restrict__ wi2) {
    int l = blockIdx.x >> 6, m = blockIdx.x & 63;
    size_t dstb = ((size_t)l * 64 + m) * 16384;
    for (int e = threadIdx.x; e < 16384; e += 256) {
        int o = e >> 7, i = e & 127;
        size_t s = (((size_t)l * 128 + i) * 128 + o) * 64 + m;
        float vr = wr[s], vi = wi[s];
        size_t d = dstb + (size_t)o * 128 + i;
        wr1[d] = f2bf_hi(vr); wr2[d] = f2bf_lo(vr);
        wi1[d] = f2bf_hi(vi); wi2[d] = f2bf_lo(vi);
    }
}

__global__ void prep_cw(const float* __restrict__ cw, u16* __restrict__ c1, u16* __restrict__ c2) {
    int idx = blockIdx.x * 256 + threadIdx.x;   // 65536
    float v = cw[idx];
    c1[idx] = f2bf_hi(v); c2[idx] = f2bf_lo(v);
}

__global__ void init_seq_kernel(const float* __restrict__ z, float* __restrict__ seq) {
    int idx = blockIdx.x * 256 + threadIdx.x;    // < 32*24*512
    int b = idx / (NTH * NR);
    int rem = idx - b * (NTH * NR);
    seq[(size_t)b * SEQROWS * NR + rem] = z[idx];
}

// ---------------------------------------------------------------------------
// fc0 (fp32): h = seq-window @ fc0_w + time/coord feats. Writes bf16 planes
// ht[b][r][c] (hi/lo). grid (8 rblk, 32 b), 256 thr.
// ---------------------------------------------------------------------------
__global__ __launch_bounds__(256) void fc0_kernel(const float* __restrict__ seq,
        const float* __restrict__ t_grid, const float* __restrict__ fc0_w,
        const float* __restrict__ fc0_b, u16* __restrict__ ht1, u16* __restrict__ ht2,
        int step) {
    __shared__ float wlds[28 * 128];
    __shared__ float blds[128];
    int b = blockIdx.y, rblk = blockIdx.x;
    int tid = threadIdx.x;
    for (int t = tid; t < 28 * 128; t += 256) wlds[t] = fc0_w[t];
    if (tid < 128) blds[tid] = fc0_b[tid];
    __syncthreads();
    int lane = tid & 63, wq = tid >> 6;
    int r = rblk * 64 + lane;
    float sv[24];
    const float* sp = seq + ((size_t)b * SEQROWS + step) * NR + r;
#pragma unroll
    for (int t = 0; t < 24; t++) sv[t] = sp[(size_t)t * NR];
    float tt = t_grid[b * 24 + 23] + (float)(step + 1);
    float ang24 = 6.28318530717958647692f * tt * (1.0f / 24.0f);
    float ang168 = 6.28318530717958647692f * tt * (1.0f / 168.0f);
    float s24 = sinf(ang24), c24 = cosf(ang24), s168 = sinf(ang168);
    float xc = (float)r * (1.0f / 511.0f);
    size_t rowoff = ((size_t)b * NR + r) * NW;
#pragma unroll 2
    for (int w0 = 0; w0 < 32; w0 += 2) {
        float acc2[2];
#pragma unroll
        for (int q = 0; q < 2; q++) {
            int w = wq * 32 + w0 + q;
            float acc = blds[w];
#pragma unroll
            for (int t = 0; t < 24; t++) acc += sv[t] * wlds[t * 128 + w];
            acc += s24 * wlds[24 * 128 + w] + c24 * wlds[25 * 128 + w]
                 + s168 * wlds[26 * 128 + w] + xc * wlds[27 * 128 + w];
            acc2[q] = acc;
        }
        unsigned int hi = (unsigned int)f2bf_hi(acc2[0]) | ((unsigned int)f2bf_hi(acc2[1]) << 16);
        unsigned int lo = (unsigned int)f2bf_lo(acc2[0]) | ((unsigned int)f2bf_lo(acc2[1]) << 16);
        size_t off = rowoff + wq * 32 + w0;
        *(unsigned int*)&ht1[off] = hi;
        *(unsigned int*)&ht2[off] = lo;
    }
}

// ---------------------------------------------------------------------------
// dft (MFMA): X[mc=128][n=4096] = F[mc][r] * h[n][r]^T, K=512, split-3.
// grid (64 n-tiles, 4 mc-tiles), 256 thr = 4 waves (2 mc x 2 n).
// Block tile 32mc x 64n; wave 16mc x 32n. B staged by transpose from ht.
// Output: X bf16 planes x1/x2 [mc][n].
// ---------------------------------------------------------------------------
__global__ __launch_bounds__(256) void dft_mfma(const u16* __restrict__ f1, const u16* __restrict__ f2,
        const u16* __restrict__ ht1, const u16* __restrict__ ht2,
        u16* __restrict__ x1, u16* __restrict__ x2) {
    __shared__ __align__(16) u16 A1[32 * 40], A2[32 * 40];
    __shared__ __align__(16) u16 B1[64 * 40], B2[64 * 40];
    int bx = blockIdx.x;             // n-tile
    int b = bx >> 1, ch = bx & 1;    // which 64-c half
    int mct = blockIdx.y * 32;
    int tid = threadIdx.x, wid = tid >> 6, l = tid & 63;
    int wm0 = (wid >> 1) * 16, wn0 = (wid & 1) * 32;
    int arow = (l & 15), kgrp = (l >> 4) * 8;
    f32x4 acc0 = {0.f, 0.f, 0.f, 0.f}, acc1 = {0.f, 0.f, 0.f, 0.f};
    for (int k0 = 0; k0 < 512; k0 += 32) {
        __syncthreads();
        {   // stage A: 2 planes x 32 rows x 4 segs = 256 tasks
            int pl = tid >> 7, row = (tid >> 2) & 31, seg = tid & 3;
            const u16* src = (pl ? f2 : f1) + (size_t)(mct + row) * 512 + k0 + seg * 8;
            u16* dst = (pl ? A2 : A1) + row * 40 + seg * 8;
            *(uint4*)dst = *(const uint4*)src;
        }
        {   // stage B (transpose): 2 planes x 32 kk x 8 segs = 512 tasks
#pragma unroll
            for (int q = 0; q < 2; q++) {
                int t = tid + q * 256;
                int pl = t >> 8, kk = (t >> 3) & 31, seg = t & 7;
                const u16* src = (pl ? ht2 : ht1) + ((size_t)b * 512 + k0 + kk) * 128 + ch * 64 + seg * 8;
                uint4 v = *(const uint4*)src;
                const u16* e = (const u16*)&v;
                u16* dst = (pl ? B2 : B1);
                int cc = seg * 8;
#pragma unroll
                for (int j = 0; j < 8; j++) dst[(cc + j) * 40 + kk] = e[j];
            }
        }
        __syncthreads();
        bf16x8 a1 = *(const bf16x8*)&A1[(wm0 + arow) * 40 + kgrp];
        bf16x8 a2 = *(const bf16x8*)&A2[(wm0 + arow) * 40 + kgrp];
        bf16x8 b10 = *(const bf16x8*)&B1[(wn0 + arow) * 40 + kgrp];
        bf16x8 b20 = *(const bf16x8*)&B2[(wn0 + arow) * 40 + kgrp];
        bf16x8 b11 = *(const bf16x8*)&B1[(wn0 + 16 + arow) * 40 + kgrp];
        bf16x8 b21 = *(const bf16x8*)&B2[(wn0 + 16 + arow) * 40 + kgrp];
        acc0 = MFMA16(a1, b10, acc0);
        acc0 = MFMA16(a1, b20, acc0);
        acc0 = MFMA16(a2, b10, acc0);
        acc1 = MFMA16(a1, b11, acc1);
        acc1 = MFMA16(a1, b21, acc1);
        acc1 = MFMA16(a2, b11, acc1);
    }
    int mcr = mct + wm0 + (l >> 4) * 4;
    int n0 = bx * 64 + wn0 + (l & 15);
#pragma unroll
    for (int j = 0; j < 4; j++) {
        size_t o0 = (size_t)(mcr + j) * 4096 + n0;
        x1[o0] = f2bf_hi(acc0[j]); x2[o0] = f2bf_lo(acc0[j]);
        size_t o1 = o0 + 16;
        x1[o1] = f2bf_hi(acc1[j]); x2[o1] = f2bf_lo(acc1[j]);
    }
}

// ---------------------------------------------------------------------------
// modemix (MFMA): per mode m: Y[o][b] = W[m](o,i) *c X[b,i,m], complex, K=128.
// grid (64 m, 4 o-quarters), 256 thr = 4 waves (2 o x 2 b), wave 16o x 16b.
// Output: Y planes y1/y2 [b][o][mc] (mc<64 re, >=64 im).
// ---------------------------------------------------------------------------
__global__ __launch_bounds__(256) void modemix_mfma(const u16* __restrict__ x1, const u16* __restrict__ x2,
        const u16* __restrict__ wr1, const u16* __restrict__ wr2,
        const u16* __restrict__ wi1, const u16* __restrict__ wi2,
        u16* __restrict__ y1, u16* __restrict__ y2, int layer) {
    __shared__ __align__(16) u16 WR1[32 * 40], WR2[32 * 40], WI1[32 * 40], WI2[32 * 40];
    __shared__ __align__(16) u16 XR1[32 * 40], XR2[32 * 40], XI1[32 * 40], XI2[32 * 40];
    int m = blockIdx.x, oq = blockIdx.y;
    int tid = threadIdx.x, wid = tid >> 6, l = tid & 63;
    int wo0 = (wid >> 1) * 16, wb0 = (wid & 1) * 16;
    int arow = (l & 15), kgrp = (l >> 4) * 8;
    f32x4 ar = {0.f, 0.f, 0.f, 0.f}, ai = {0.f, 0.f, 0.f, 0.f};
    size_t wbase = (((size_t)layer * 64 + m) * 128 + oq * 32) * 128;
    for (int k0 = 0; k0 < 128; k0 += 32) {
        __syncthreads();
        {   // stage W: 4 slabs x 32 rows x 4 segs = 512 tasks
#pragma unroll
            for (int q = 0; q < 2; q++) {
                int t = tid + q * 256;
                int slab = t >> 7, row = (t >> 2) & 31, seg = t & 3;
                const u16* src = (slab == 0 ? wr1 : slab == 1 ? wr2 : slab == 2 ? wi1 : wi2)
                                 + wbase + (size_t)row * 128 + k0 + seg * 8;
                u16* dst = (slab == 0 ? WR1 : slab == 1 ? WR2 : slab == 2 ? WI1 : WI2) + row * 40 + seg * 8;
                *(uint4*)dst = *(const uint4*)src;
            }
        }
        {   // stage X: 4 slabs (re-hi, re-lo, im-hi, im-lo) x 32 b x 4 segs
#pragma unroll
            for (int q = 0; q < 2; q++) {
                int t = tid + q * 256;
                int slab = t >> 7, row = (t >> 2) & 31, seg = t & 3;
                int mrow = (slab >= 2) ? (64 + m) : m;
                const u16* base = (slab & 1) ? x2 : x1;
                const u16* src = base + (size_t)mrow * 4096 + row * 128 + k0 + seg * 8;
                u16* dst = (slab == 0 ? XR1 : slab == 1 ? XR2 : slab == 2 ? XI1 : XI2) + row * 40 + seg * 8;
                *(uint4*)dst = *(const uint4*)src;
            }
        }
        __syncthreads();
        int ao = (wo0 + arow) * 40 + kgrp;
        int bo = (wb0 + arow) * 40 + kgrp;
        bf16x8 Wr1 = *(const bf16x8*)&WR1[ao], Wr2 = *(const bf16x8*)&WR2[ao];
        bf16x8 Wi1 = *(const bf16x8*)&WI1[ao], Wi2 = *(const bf16x8*)&WI2[ao];
        bf16x8 Xr1 = *(const bf16x8*)&XR1[bo], Xr2 = *(const bf16x8*)&XR2[bo];
        bf16x8 Xi1 = *(const bf16x8*)&XI1[bo], Xi2 = *(const bf16x8*)&XI2[bo];
        bf16x8 nWi1 = negbf(Wi1), nWi2 = negbf(Wi2);
        ar = MFMA16(Wr1, Xr1, ar); ar = MFMA16(Wr1, Xr2, ar); ar = MFMA16(Wr2, Xr1, ar);
        ar = MFMA16(nWi1, Xi1, ar); ar = MFMA16(nWi1, Xi2, ar); ar = MFMA16(nWi2, Xi1, ar);
        ai = MFMA16(Wi1, Xr1, ai); ai = MFMA16(Wi1, Xr2, ai); ai = MFMA16(Wi2, Xr1, ai);
        ai = MFMA16(Wr1, Xi1, ai); ai = MFMA16(Wr1, Xi2, ai); ai = MFMA16(Wr2, Xi1, ai);
    }
    int ob = oq * 32 + wo0 + (l >> 4) * 4;
    int bb = wb0 + (l & 15);
#pragma unroll
    for (int j = 0; j < 4; j++) {
        size_t o = ((size_t)bb * 128 + ob + j) * 128;
        y1[o + m] = f2bf_hi(ar[j]); y2[o + m] = f2bf_lo(ar[j]);
        y1[o + 64 + m] = f2bf_hi(ai[j]); y2[o + 64 + m] = f2bf_lo(ai[j]);
    }
}

// ---------------------------------------------------------------------------
// idft+conv (MFMA): per b: C[o=128][r=512] = [Y|CW](o, k=256) * [GT;ht](k, r),
// split-3, + bias + GELU. grid (8 r-tiles, 2 o-tiles, 32 b), 256 thr,
// block tile 64o x 64r, wave 32o x 32r (2x2 frags). All staging is direct
// row copies (GT and ht both stored [r][k]-major). Writes ht-next planes.
// ---------------------------------------------------------------------------
__global__ __launch_bounds__(256) void idft_conv_mfma(const u16* __restrict__ y1, const u16* __restrict__ y2,
        const u16* __restrict__ gt1, const u16* __restrict__ gt2,
        const u16* __restrict__ htc1, const u16* __restrict__ htc2,
        const u16* __restrict__ cw1, const u16* __restrict__ cw2,
        const float* __restrict__ conv_b,
        u16* __restrict__ hn1, u16* __restrict__ hn2, int layer) {
    __shared__ __align__(16) u16 A1[64 * 40], A2[64 * 40];
    __shared__ __align__(16) u16 B1[64 * 40], B2[64 * 40];
    int rt = blockIdx.x * 64, ot = blockIdx.y * 64, b = blockIdx.z;
    int tid = threadIdx.x, wid = tid >> 6, l = tid & 63;
    int wo0 = (wid >> 1) * 32, wr0 = (wid & 1) * 32;
    int arow = (l & 15), kgrp = (l >> 4) * 8;
    f32x4 acc[2][2] = {{{0.f,0.f,0.f,0.f},{0.f,0.f,0.f,0.f}},{{0.f,0.f,0.f,0.f},{0.f,0.f,0.f,0.f}}};
    for (int chk = 0; chk < 8; chk++) {
        int k0 = (chk & 3) * 32;
        bool conv = chk >= 4;
        __syncthreads();
        {   // stage A: 2 planes x 64 rows x 4 segs = 512 tasks
#pragma unroll
            for (int q = 0; q < 2; q++) {
                int t = tid + q * 256;
                int pl = t >> 8, row = (t >> 2) & 63, seg = t & 3;
                const u16* src;
                if (!conv) src = (pl ? y2 : y1) + ((size_t)b * 128 + ot + row) * 128 + k0 + seg * 8;
                else       src = (pl ? cw2 : cw1) + ((size_t)layer * 128 + ot + row) * 128 + k0 + seg * 8;
                u16* dst = (pl ? A2 : A1) + row * 40 + seg * 8;
                *(uint4*)dst = *(const uint4*)src;
            }
        }
        {   // stage B: 2 planes x 64 rows x 4 segs = 512 tasks
#pragma unroll
            for (int q = 0; q < 2; q++) {
                int t = tid + q * 256;
                int pl = t >> 8, row = (t >> 2) & 63, seg = t & 3;
                const u16* src;
                if (!conv) src = (pl ? gt2 : gt1) + (size_t)(rt + row) * 128 + k0 + seg * 8;
                else       src = (pl ? htc2 : htc1) + ((size_t)b * 512 + rt + row) * 128 + k0 + seg * 8;
                u16* dst = (pl ? B2 : B1) + row * 40 + seg * 8;
                *(uint4*)dst = *(const uint4*)src;
            }
        }
        __syncthreads();
        bf16x8 bfr[2][2];
#pragma unroll
        for (int rf = 0; rf < 2; rf++) {
            bfr[rf][0] = *(const bf16x8*)&B1[(wr0 + rf * 16 + arow) * 40 + kgrp];
            bfr[rf][1] = *(const bf16x8*)&B2[(wr0 + rf * 16 + arow) * 40 + kgrp];
        }
#pragma unroll
        for (int of = 0; of < 2; of++) {
            bf16x8 a1 = *(const bf16x8*)&A1[(wo0 + of * 16 + arow) * 40 + kgrp];
            bf16x8 a2 = *(const bf16x8*)&A2[(wo0 + of * 16 + arow) * 40 + kgrp];
#pragma unroll
            for (int rf = 0; rf < 2; rf++) {
                acc[of][rf] = MFMA16(a1, bfr[rf][0], acc[of][rf]);
                acc[of][rf] = MFMA16(a1, bfr[rf][1], acc[of][rf]);
                acc[of][rf] = MFMA16(a2, bfr[rf][0], acc[of][rf]);
            }
        }
    }
#pragma unroll
    for (int of = 0; of < 2; of++) {
        int ob = ot + wo0 + of * 16 + (l >> 4) * 4;
#pragma unroll
        for (int rf = 0; rf < 2; rf++) {
            int r = rt + wr0 + rf * 16 + (l & 15);
            ushort4 hv, lv;
            float v0 = gelu_exact(acc[of][rf][0] + conv_b[layer * 128 + ob + 0]);
            float v1 = gelu_exact(acc[of][rf][1] + conv_b[layer * 128 + ob + 1]);
            float v2 = gelu_exact(acc[of][rf][2] + conv_b[layer * 128 + ob + 2]);
            float v3 = gelu_exact(acc[of][rf][3] + conv_b[layer * 128 + ob + 3]);
            hv.x = f2bf_hi(v0); hv.y = f2bf_hi(v1); hv.z = f2bf_hi(v2); hv.w = f2bf_hi(v3);
            lv.x = f2bf_lo(v0); lv.y = f2bf_lo(v1); lv.z = f2bf_lo(v2); lv.w = f2bf_lo(v3);
            size_t off = ((size_t)b * 512 + r) * 128 + ob;
            *(ushort4*)&hn1[off] = hv;
            *(ushort4*)&hn2[off] = lv;
        }
    }
}

// ---------------------------------------------------------------------------
// head (fp32): dx = fc2(gelu(fc1(h))); z_next = seq_last + dx. Reads ht planes.
// grid (8 r-tiles, 32 b), 256 thr.
// ---------------------------------------------------------------------------
__global__ __launch_bounds__(256) void head_kernel(const u16* __restrict__ ht1, const u16* __restrict__ ht2,
        const float* __restrict__ fc1_w, const float* __restrict__ fc1_b,
        const float* __restrict__ fc2_w, const float* __restrict__ fc2_b,
        float* __restrict__ seq, float* __restrict__ preds, int step) {
    __shared__ float ldsH[128][64];
    __shared__ __align__(16) float ldsW[128][64];
    int rt = blockIdx.x * 64, b = blockIdx.y;
    int tid = threadIdx.x;
    int rl = tid & 63, jg = tid >> 6;
    for (int t = tid; t < 8192; t += 256) {
        int rr = t >> 7, c = t & 127;
        size_t off = ((size_t)b * 512 + rt + rr) * 128 + c;
        ldsH[c][rr] = bf2f(ht1[off]) + bf2f(ht2[off]);
    }
    float dx = 0.0f;
    for (int jt = 0; jt < 4; jt++) {
        __syncthreads();
        for (int t = tid; t < 8192; t += 256) {
            int w = t >> 6, c = t & 63;
            ldsW[w][c] = fc1_w[(size_t)w * 256 + jt * 64 + c];
        }
        __syncthreads();
        float accj[16];
        int jb = jt * 64 + jg * 16;
#pragma unroll
        for (int jj = 0; jj < 16; jj++) accj[jj] = fc1_b[jb + jj];
#pragma unroll 8
        for (int w = 0; w < 128; w++) {
            float hv = ldsH[w][rl];
            const float* wp = &ldsW[w][jg * 16];
            float4 w0 = *(const float4*)(wp);
            float4 w1 = *(const float4*)(wp + 4);
            float4 w2 = *(const float4*)(wp + 8);
            float4 w3 = *(const float4*)(wp + 12);
            accj[0]  += hv * w0.x; accj[1]  += hv * w0.y;
            accj[2]  += hv * w0.z; accj[3]  += hv * w0.w;
            accj[4]  += hv * w1.x; accj[5]  += hv * w1.y;
            accj[6]  += hv * w1.z; accj[7]  += hv * w1.w;
            accj[8]  += hv * w2.x; accj[9]  += hv * w2.y;
            accj[10] += hv * w2.z; accj[11] += hv * w2.w;
            accj[12] += hv * w3.x; accj[13] += hv * w3.y;
            accj[14] += hv * w3.z; accj[15] += hv * w3.w;
        }
#pragma unroll
        for (int jj = 0; jj < 16; jj++) {
            dx += gelu_exact(accj[jj]) * fc2_w[jb + jj];
        }
    }
    __syncthreads();
    float* red = (float*)ldsW;
    red[jg * 64 + rl] = dx;
    __syncthreads();
    if (jg == 0) {
        float s = red[rl] + red[64 + rl] + red[128 + rl] + red[192 + rl] + fc2_b[0];
        int r = rt + rl;
        float zn = seq[((size_t)b * SEQROWS + step + 23) * NR + r] + s;
        seq[((size_t)b * SEQROWS + step + 24) * NR + r] = zn;
        preds[((size_t)b * NSTEPS + step) * NR + r] = zn;
    }
}

// ---------------------------------------------------------------------------
extern "C" void kernel_launch(void* const* d_in, const int* in_sizes, int n_in,
                              void* d_out, int out_size, void* d_ws, size_t ws_size,
                              hipStream_t stream) {
    (void)in_sizes; (void)n_in; (void)out_size; (void)ws_size;
    const float* z       = (const float*)d_in[0];
    const float* t_grid  = (const float*)d_in[1];
    const float* fc0_w   = (const float*)d_in[2];
    const float* fc0_b   = (const float*)d_in[3];
    const float* spec_wr = (const float*)d_in[4];
    const float* spec_wi = (const float*)d_in[5];
    const float* conv_w  = (const float*)d_in[6];
    const float* conv_b  = (const float*)d_in[7];
    const float* fc1_w   = (const float*)d_in[8];
    const float* fc1_b   = (const float*)d_in[9];
    const float* fc2_w   = (const float*)d_in[10];
    const float* fc2_b   = (const float*)d_in[11];
    float* preds = (float*)d_out;

    // workspace carve-up: seq f32 (2.36 MB) + bf16 planes (~55 MB) = ~57.7 MB
    char* p = (char*)d_ws;
    float* seq = (float*)p;  p += (size_t)NB * SEQROWS * NR * 4;      // 589824 f
    u16* ht1 = (u16*)p;  p += (size_t)2 * NB * NR * NW * 2;           // [2][32][512][128]
    u16* ht2 = (u16*)p;  p += (size_t)2 * NB * NR * NW * 2;
    u16* x1  = (u16*)p;  p += (size_t)128 * 4096 * 2;
    u16* x2  = (u16*)p;  p += (size_t)128 * 4096 * 2;
    u16* y1  = (u16*)p;  p += (size_t)NB * NW * 128 * 2;
    u16* y2  = (u16*)p;  p += (size_t)NB * NW * 128 * 2;
    u16* f1  = (u16*)p;  p += (size_t)128 * 512 * 2;
    u16* f2  = (u16*)p;  p += (size_t)128 * 512 * 2;
    u16* gt1 = (u16*)p;  p += (size_t)512 * 128 * 2;
    u16* gt2 = (u16*)p;  p += (size_t)512 * 128 * 2;
    u16* wr1 = (u16*)p;  p += (size_t)NLAY * NM * NW * NW * 2;
    u16* wr2 = (u16*)p;  p += (size_t)NLAY * NM * NW * NW * 2;
    u16* wi1 = (u16*)p;  p += (size_t)NLAY * NM * NW * NW * 2;
    u16* wi2 = (u16*)p;  p += (size_t)NLAY * NM * NW * NW * 2;
    u16* cw1 = (u16*)p;  p += (size_t)NLAY * NW * NW * 2;
    u16* cw2 = (u16*)p;  p += (size_t)NLAY * NW * NW * 2;

    const size_t htplane = (size_t)NB * NR * NW;   // one buffer within ht1/ht2

    build_tables_planes<<<256, 256, 0, stream>>>(f1, f2, gt1, gt2);
    prep_specw<<<256, 256, 0, stream>>>(spec_wr, spec_wi, wr1, wr2, wi1, wi2);
    prep_cw<<<256, 256, 0, stream>>>(conv_w, cw1, cw2);
    init_seq_kernel<<<(NB * NTH * NR) / 256, 256, 0, stream>>>(z, seq);

    for (int step = 0; step < NSTEPS; step++) {
        fc0_kernel<<<dim3(8, 32), 256, 0, stream>>>(seq, t_grid, fc0_w, fc0_b,
                                                    ht1, ht2, step);
        int cur = 0;
        for (int l = 0; l < NLAY; l++) {
            const u16* hc1 = ht1 + (size_t)cur * htplane;
            const u16* hc2 = ht2 + (size_t)cur * htplane;
            u16* hn1 = ht1 + (size_t)(cur ^ 1) * htplane;
            u16* hn2 = ht2 + (size_t)(cur ^ 1) * htplane;
            dft_mfma<<<dim3(64, 4), 256, 0, stream>>>(f1, f2, hc1, hc2, x1, x2);
            modemix_mfma<<<dim3(64, 4), 256, 0, stream>>>(x1, x2, wr1, wr2, wi1, wi2,
                                                          y1, y2, l);
            idft_conv_mfma<<<dim3(8, 2, 32), 256, 0, stream>>>(y1, y2, gt1, gt2,
                                                               hc1, hc2, cw1, cw2,
                                                               conv_b, hn1, hn2, l);
            cur ^= 1;
        }
        // after 4 layers cur == 0
        head_kernel<<<dim3(8, 32), 256, 0, stream>>>(ht1, ht2, fc1_w, fc1_b,
                                                     fc2_w, fc2_b, seq, preds, step);
    }
}

// Round 4
// 2233.104 us; speedup vs baseline: 45.3948x; 1.2916x over previous
//
#include <hip/hip_runtime.h>
#include <math.h>

// LatentFNO: B=32, T=24, R=512, W=128, M=64 modes, 4 layers, 12 steps.
// Round 4: (a) head converted to bf16-MFMA split-3 (fc1 GEMM + gelu + fc2
// in-register reduce + z update, one kernel); (b) dual-layout h planes:
// ht[b][r][c] (for idft-conv B and head B) AND htc[b][c][r] (for dft B),
// so dft staging is pure uint4 row copies (no LDS scatter-transpose).
// All GEMMs remain exact 3-term split precision (A1B1+A1B2+A2B1).

#define NB 32
#define NR 512
#define NW 128
#define NM 64
#define NTH 24
#define NLAY 4
#define NSTEPS 12
#define SEQROWS 36

typedef unsigned short u16;
typedef unsigned int u32;
typedef __attribute__((ext_vector_type(8))) short bf16x8;
typedef __attribute__((ext_vector_type(4))) float f32x4;
#define MFMA16(a, b, c) __builtin_amdgcn_mfma_f32_16x16x32_bf16((a), (b), (c), 0, 0, 0)

__device__ __forceinline__ float gelu_exact(float x) {
    return 0.5f * x * (1.0f + erff(x * 0.70710678118654752f));
}
__device__ __forceinline__ float bf2f(u16 u) {
    union { u32 i; float f; } v; v.i = ((u32)u) << 16; return v.f;
}
__device__ __forceinline__ u16 f2bf_hi(float x) {
    union { float f; u32 i; } v; v.f = x; return (u16)(v.i >> 16);
}
__device__ __forceinline__ u16 f2bf_lo(float x) {
    float h = bf2f(f2bf_hi(x));
    return f2bf_hi(x - h);
}
__device__ __forceinline__ bf16x8 negbf(bf16x8 a) {
#pragma unroll
    for (int i = 0; i < 8; i++) a[i] ^= (short)0x8000;
    return a;
}

// ---------------------------------------------------------------------------
// Tables: F planes [mc=128][r=512]; GT planes [r=512][mc=128].
// ---------------------------------------------------------------------------
__global__ void build_tables_planes(u16* __restrict__ f1, u16* __restrict__ f2,
                                    u16* __restrict__ gt1, u16* __restrict__ gt2) {
    int idx = blockIdx.x * 256 + threadIdx.x;   // 65536: mc*512 + r
    int mc = idx >> 9, r = idx & 511, m = mc & 63;
    int p = (m * r) & 511;
    float a = (float)p * (1.0f / 256.0f);
    float c = cospif(a), s = sinpif(a);
    float Fv = (mc < 64) ? c : -s;
    float cm = (m == 0) ? (1.0f / 512.0f) : (2.0f / 512.0f);
    float Gv = (mc < 64) ? cm * c : ((m == 0) ? 0.0f : -cm * s);
    f1[idx] = f2bf_hi(Fv); f2[idx] = f2bf_lo(Fv);
    size_t g = (size_t)r * 128 + mc;
    gt1[g] = f2bf_hi(Gv); gt2[g] = f2bf_lo(Gv);
}

// spec_w (l,i,o,m) -> planes [l][m][o][i] hi/lo for re and im
__global__ void prep_specw(const float* __restrict__ wr, const float* __restrict__ wi,
                           u16* __restrict__ wr1, u16* __restrict__ wr2,
                           u16* __restrict__ wi1, u16* __restrict__ wi2) {
    int l = blockIdx.x >> 6, m = blockIdx.x & 63;
    size_t dstb = ((size_t)l * 64 + m) * 16384;
    for (int e = threadIdx.x; e < 16384; e += 256) {
        int o = e >> 7, i = e & 127;
        size_t s = (((size_t)l * 128 + i) * 128 + o) * 64 + m;
        float vr = wr[s], vi = wi[s];
        size_t d = dstb + (size_t)o * 128 + i;
        wr1[d] = f2bf_hi(vr); wr2[d] = f2bf_lo(vr);
        wi1[d] = f2bf_hi(vi); wi2[d] = f2bf_lo(vi);
    }
}

__global__ void prep_cw(const float* __restrict__ cw, u16* __restrict__ c1, u16* __restrict__ c2) {
    int idx = blockIdx.x * 256 + threadIdx.x;   // 65536
    float v = cw[idx];
    c1[idx] = f2bf_hi(v); c2[idx] = f2bf_lo(v);
}

// fc1_w [c=128][j=256] -> fc1t planes [j][c] hi/lo
__global__ void prep_fc1t(const float* __restrict__ fc1_w,
                          u16* __restrict__ f11, u16* __restrict__ f12) {
    int idx = blockIdx.x * 256 + threadIdx.x;   // 32768: j*128 + c
    int j = idx >> 7, c = idx & 127;
    float v = fc1_w[(size_t)c * 256 + j];
    f11[idx] = f2bf_hi(v); f12[idx] = f2bf_lo(v);
}

__global__ void init_seq_kernel(const float* __restrict__ z, float* __restrict__ seq) {
    int idx = blockIdx.x * 256 + threadIdx.x;    // < 32*24*512
    int b = idx / (NTH * NR);
    int rem = idx - b * (NTH * NR);
    seq[(size_t)b * SEQROWS * NR + rem] = z[idx];
}

// ---------------------------------------------------------------------------
// fc0 (fp32): writes ht[b][r][c] AND htc[b][c][r] planes (hi/lo).
// ---------------------------------------------------------------------------
__global__ __launch_bounds__(256) void fc0_kernel(const float* __restrict__ seq,
        const float* __restrict__ t_grid, const float* __restrict__ fc0_w,
        const float* __restrict__ fc0_b, u16* __restrict__ ht1, u16* __restrict__ ht2,
        u16* __restrict__ htc1, u16* __restrict__ htc2, int step) {
    __shared__ float wlds[28 * 128];
    __shared__ float blds[128];
    int b = blockIdx.y, rblk = blockIdx.x;
    int tid = threadIdx.x;
    for (int t = tid; t < 28 * 128; t += 256) wlds[t] = fc0_w[t];
    if (tid < 128) blds[tid] = fc0_b[tid];
    __syncthreads();
    int lane = tid & 63, wq = tid >> 6;
    int r = rblk * 64 + lane;
    float sv[24];
    const float* sp = seq + ((size_t)b * SEQROWS + step) * NR + r;
#pragma unroll
    for (int t = 0; t < 24; t++) sv[t] = sp[(size_t)t * NR];
    float tt = t_grid[b * 24 + 23] + (float)(step + 1);
    float ang24 = 6.28318530717958647692f * tt * (1.0f / 24.0f);
    float ang168 = 6.28318530717958647692f * tt * (1.0f / 168.0f);
    float s24 = sinf(ang24), c24 = cosf(ang24), s168 = sinf(ang168);
    float xc = (float)r * (1.0f / 511.0f);
    size_t rowoff = ((size_t)b * NR + r) * NW;
#pragma unroll 2
    for (int w0 = 0; w0 < 32; w0 += 2) {
        float acc2[2];
#pragma unroll
        for (int q = 0; q < 2; q++) {
            int w = wq * 32 + w0 + q;
            float acc = blds[w];
#pragma unroll
            for (int t = 0; t < 24; t++) acc += sv[t] * wlds[t * 128 + w];
            acc += s24 * wlds[24 * 128 + w] + c24 * wlds[25 * 128 + w]
                 + s168 * wlds[26 * 128 + w] + xc * wlds[27 * 128 + w];
            acc2[q] = acc;
        }
        u16 h0 = f2bf_hi(acc2[0]), h1 = f2bf_hi(acc2[1]);
        u16 l0 = f2bf_lo(acc2[0]), l1 = f2bf_lo(acc2[1]);
        size_t off = rowoff + wq * 32 + w0;
        *(u32*)&ht1[off] = (u32)h0 | ((u32)h1 << 16);
        *(u32*)&ht2[off] = (u32)l0 | ((u32)l1 << 16);
        int w = wq * 32 + w0;
        size_t coff = ((size_t)b * 128 + w) * 512 + r;
        htc1[coff] = h0; htc1[coff + 512] = h1;
        htc2[coff] = l0; htc2[coff + 512] = l1;
    }
}

// ---------------------------------------------------------------------------
// dft (MFMA): X[mc=128][n=4096] = F[mc][r] * h[n][r]^T, K=512, split-3.
// B staged as pure uint4 row copies from htc[b][c][r].
// grid (64 n-tiles, 4 mc-tiles), 256 thr = 4 waves (2 mc x 2 n).
// ---------------------------------------------------------------------------
__global__ __launch_bounds__(256) void dft_mfma(const u16* __restrict__ f1, const u16* __restrict__ f2,
        const u16* __restrict__ htc1, const u16* __restrict__ htc2,
        u16* __restrict__ x1, u16* __restrict__ x2) {
    __shared__ __align__(16) u16 A1[32 * 40], A2[32 * 40];
    __shared__ __align__(16) u16 B1[64 * 40], B2[64 * 40];
    int bx = blockIdx.x;             // n-tile
    int b = bx >> 1, ch = bx & 1;
    int mct = blockIdx.y * 32;
    int tid = threadIdx.x, wid = tid >> 6, l = tid & 63;
    int wm0 = (wid >> 1) * 16, wn0 = (wid & 1) * 32;
    int arow = (l & 15), kgrp = (l >> 4) * 8;
    f32x4 acc0 = {0.f, 0.f, 0.f, 0.f}, acc1 = {0.f, 0.f, 0.f, 0.f};
    const u16* hb1 = htc1 + ((size_t)b * 128 + ch * 64) * 512;
    const u16* hb2 = htc2 + ((size_t)b * 128 + ch * 64) * 512;
    for (int k0 = 0; k0 < 512; k0 += 32) {
        __syncthreads();
        {   // stage A: 2 planes x 32 rows x 4 segs = 256 tasks
            int pl = tid >> 7, row = (tid >> 2) & 31, seg = tid & 3;
            const u16* src = (pl ? f2 : f1) + (size_t)(mct + row) * 512 + k0 + seg * 8;
            *(uint4*)((pl ? A2 : A1) + row * 40 + seg * 8) = *(const uint4*)src;
        }
        {   // stage B: 2 planes x 64 rows x 4 segs = 512 tasks (row copies!)
#pragma unroll
            for (int q = 0; q < 2; q++) {
                int t = tid + q * 256;
                int pl = t >> 8, row = (t >> 2) & 63, seg = t & 3;
                const u16* src = (pl ? hb2 : hb1) + (size_t)row * 512 + k0 + seg * 8;
                *(uint4*)((pl ? B2 : B1) + row * 40 + seg * 8) = *(const uint4*)src;
            }
        }
        __syncthreads();
        bf16x8 a1 = *(const bf16x8*)&A1[(wm0 + arow) * 40 + kgrp];
        bf16x8 a2 = *(const bf16x8*)&A2[(wm0 + arow) * 40 + kgrp];
        bf16x8 b10 = *(const bf16x8*)&B1[(wn0 + arow) * 40 + kgrp];
        bf16x8 b20 = *(const bf16x8*)&B2[(wn0 + arow) * 40 + kgrp];
        bf16x8 b11 = *(const bf16x8*)&B1[(wn0 + 16 + arow) * 40 + kgrp];
        bf16x8 b21 = *(const bf16x8*)&B2[(wn0 + 16 + arow) * 40 + kgrp];
        acc0 = MFMA16(a1, b10, acc0);
        acc0 = MFMA16(a1, b20, acc0);
        acc0 = MFMA16(a2, b10, acc0);
        acc1 = MFMA16(a1, b11, acc1);
        acc1 = MFMA16(a1, b21, acc1);
        acc1 = MFMA16(a2, b11, acc1);
    }
    int mcr = mct + wm0 + (l >> 4) * 4;
    int n0 = bx * 64 + wn0 + (l & 15);
#pragma unroll
    for (int j = 0; j < 4; j++) {
        size_t o0 = (size_t)(mcr + j) * 4096 + n0;
        x1[o0] = f2bf_hi(acc0[j]); x2[o0] = f2bf_lo(acc0[j]);
        size_t o1 = o0 + 16;
        x1[o1] = f2bf_hi(acc1[j]); x2[o1] = f2bf_lo(acc1[j]);
    }
}

// ---------------------------------------------------------------------------
// modemix (MFMA): per mode m: Y[o][b] = W[m](o,i) *c X[b,i,m], K=128, split-3.
// grid (64 m, 4 o-quarters), 256 thr = 4 waves (2 o x 2 b).
// ---------------------------------------------------------------------------
__global__ __launch_bounds__(256) void modemix_mfma(const u16* __restrict__ x1, const u16* __restrict__ x2,
        const u16* __restrict__ wr1, const u16* __restrict__ wr2,
        const u16* __restrict__ wi1, const u16* __restrict__ wi2,
        u16* __restrict__ y1, u16* __restrict__ y2, int layer) {
    __shared__ __align__(16) u16 WR1[32 * 40], WR2[32 * 40], WI1[32 * 40], WI2[32 * 40];
    __shared__ __align__(16) u16 XR1[32 * 40], XR2[32 * 40], XI1[32 * 40], XI2[32 * 40];
    int m = blockIdx.x, oq = blockIdx.y;
    int tid = threadIdx.x, wid = tid >> 6, l = tid & 63;
    int wo0 = (wid >> 1) * 16, wb0 = (wid & 1) * 16;
    int arow = (l & 15), kgrp = (l >> 4) * 8;
    f32x4 ar = {0.f, 0.f, 0.f, 0.f}, ai = {0.f, 0.f, 0.f, 0.f};
    size_t wbase = (((size_t)layer * 64 + m) * 128 + oq * 32) * 128;
    for (int k0 = 0; k0 < 128; k0 += 32) {
        __syncthreads();
        {   // stage W: 4 slabs x 32 rows x 4 segs = 512 tasks
#pragma unroll
            for (int q = 0; q < 2; q++) {
                int t = tid + q * 256;
                int slab = t >> 7, row = (t >> 2) & 31, seg = t & 3;
                const u16* src = (slab == 0 ? wr1 : slab == 1 ? wr2 : slab == 2 ? wi1 : wi2)
                                 + wbase + (size_t)row * 128 + k0 + seg * 8;
                u16* dst = (slab == 0 ? WR1 : slab == 1 ? WR2 : slab == 2 ? WI1 : WI2) + row * 40 + seg * 8;
                *(uint4*)dst = *(const uint4*)src;
            }
        }
        {   // stage X: 4 slabs x 32 b x 4 segs = 512 tasks
#pragma unroll
            for (int q = 0; q < 2; q++) {
                int t = tid + q * 256;
                int slab = t >> 7, row = (t >> 2) & 31, seg = t & 3;
                int mrow = (slab >= 2) ? (64 + m) : m;
                const u16* base = (slab & 1) ? x2 : x1;
                const u16* src = base + (size_t)mrow * 4096 + row * 128 + k0 + seg * 8;
                u16* dst = (slab == 0 ? XR1 : slab == 1 ? XR2 : slab == 2 ? XI1 : XI2) + row * 40 + seg * 8;
                *(uint4*)dst = *(const uint4*)src;
            }
        }
        __syncthreads();
        int ao = (wo0 + arow) * 40 + kgrp;
        int bo = (wb0 + arow) * 40 + kgrp;
        bf16x8 Wr1 = *(const bf16x8*)&WR1[ao], Wr2 = *(const bf16x8*)&WR2[ao];
        bf16x8 Wi1 = *(const bf16x8*)&WI1[ao], Wi2 = *(const bf16x8*)&WI2[ao];
        bf16x8 Xr1 = *(const bf16x8*)&XR1[bo], Xr2 = *(const bf16x8*)&XR2[bo];
        bf16x8 Xi1 = *(const bf16x8*)&XI1[bo], Xi2 = *(const bf16x8*)&XI2[bo];
        bf16x8 nWi1 = negbf(Wi1), nWi2 = negbf(Wi2);
        ar = MFMA16(Wr1, Xr1, ar); ar = MFMA16(Wr1, Xr2, ar); ar = MFMA16(Wr2, Xr1, ar);
        ar = MFMA16(nWi1, Xi1, ar); ar = MFMA16(nWi1, Xi2, ar); ar = MFMA16(nWi2, Xi1, ar);
        ai = MFMA16(Wi1, Xr1, ai); ai = MFMA16(Wi1, Xr2, ai); ai = MFMA16(Wi2, Xr1, ai);
        ai = MFMA16(Wr1, Xi1, ai); ai = MFMA16(Wr1, Xi2, ai); ai = MFMA16(Wr2, Xi1, ai);
    }
    int ob = oq * 32 + wo0 + (l >> 4) * 4;
    int bb = wb0 + (l & 15);
#pragma unroll
    for (int j = 0; j < 4; j++) {
        size_t o = ((size_t)bb * 128 + ob + j) * 128;
        y1[o + m] = f2bf_hi(ar[j]); y2[o + m] = f2bf_lo(ar[j]);
        y1[o + 64 + m] = f2bf_hi(ai[j]); y2[o + 64 + m] = f2bf_lo(ai[j]);
    }
}

// ---------------------------------------------------------------------------
// idft+conv (MFMA): per b: C[o][r] = [Y|CW](o,k=256)*[GT;ht](k,r) +bias, GELU.
// Writes ht-next [r][c] (direct) and, when wtr!=0, htc [c][r] via padded
// LDS transpose tile. grid (8 r-tiles, 2 o-tiles, 32 b), 256 thr.
// ---------------------------------------------------------------------------
__global__ __launch_bounds__(256) void idft_conv_mfma(const u16* __restrict__ y1, const u16* __restrict__ y2,
        const u16* __restrict__ gt1, const u16* __restrict__ gt2,
        const u16* __restrict__ hc1, const u16* __restrict__ hc2,
        const u16* __restrict__ cw1, const u16* __restrict__ cw2,
        const float* __restrict__ conv_b,
        u16* __restrict__ hn1, u16* __restrict__ hn2,
        u16* __restrict__ htc1, u16* __restrict__ htc2, int layer, int wtr) {
    __shared__ __align__(16) u16 A1[64 * 40], A2[64 * 40];
    __shared__ __align__(16) u16 B1[64 * 40], B2[64 * 40];
    __shared__ __align__(16) u16 T1[64 * 66], T2[64 * 66];
    int rt = blockIdx.x * 64, ot = blockIdx.y * 64, b = blockIdx.z;
    int tid = threadIdx.x, wid = tid >> 6, l = tid & 63;
    int wo0 = (wid >> 1) * 32, wr0 = (wid & 1) * 32;
    int arow = (l & 15), kgrp = (l >> 4) * 8;
    f32x4 acc[2][2] = {{{0.f,0.f,0.f,0.f},{0.f,0.f,0.f,0.f}},{{0.f,0.f,0.f,0.f},{0.f,0.f,0.f,0.f}}};
    for (int chk = 0; chk < 8; chk++) {
        int k0 = (chk & 3) * 32;
        bool conv = chk >= 4;
        __syncthreads();
        {   // stage A: 2 planes x 64 rows x 4 segs = 512 tasks
#pragma unroll
            for (int q = 0; q < 2; q++) {
                int t = tid + q * 256;
                int pl = t >> 8, row = (t >> 2) & 63, seg = t & 3;
                const u16* src;
                if (!conv) src = (pl ? y2 : y1) + ((size_t)b * 128 + ot + row) * 128 + k0 + seg * 8;
                else       src = (pl ? cw2 : cw1) + ((size_t)layer * 128 + ot + row) * 128 + k0 + seg * 8;
                *(uint4*)((pl ? A2 : A1) + row * 40 + seg * 8) = *(const uint4*)src;
            }
        }
        {   // stage B: 2 planes x 64 rows x 4 segs = 512 tasks
#pragma unroll
            for (int q = 0; q < 2; q++) {
                int t = tid + q * 256;
                int pl = t >> 8, row = (t >> 2) & 63, seg = t & 3;
                const u16* src;
                if (!conv) src = (pl ? gt2 : gt1) + (size_t)(rt + row) * 128 + k0 + seg * 8;
                else       src = (pl ? hc2 : hc1) + ((size_t)b * 512 + rt + row) * 128 + k0 + seg * 8;
                *(uint4*)((pl ? B2 : B1) + row * 40 + seg * 8) = *(const uint4*)src;
            }
        }
        __syncthreads();
        bf16x8 bfr[2][2];
#pragma unroll
        for (int rf = 0; rf < 2; rf++) {
            bfr[rf][0] = *(const bf16x8*)&B1[(wr0 + rf * 16 + arow) * 40 + kgrp];
            bfr[rf][1] = *(const bf16x8*)&B2[(wr0 + rf * 16 + arow) * 40 + kgrp];
        }
#pragma unroll
        for (int of = 0; of < 2; of++) {
            bf16x8 a1 = *(const bf16x8*)&A1[(wo0 + of * 16 + arow) * 40 + kgrp];
            bf16x8 a2 = *(const bf16x8*)&A2[(wo0 + of * 16 + arow) * 40 + kgrp];
#pragma unroll
            for (int rf = 0; rf < 2; rf++) {
                acc[of][rf] = MFMA16(a1, bfr[rf][0], acc[of][rf]);
                acc[of][rf] = MFMA16(a1, bfr[rf][1], acc[of][rf]);
                acc[of][rf] = MFMA16(a2, bfr[rf][0], acc[of][rf]);
            }
        }
    }
#pragma unroll
    for (int of = 0; of < 2; of++) {
        int obl = wo0 + of * 16 + (l >> 4) * 4;   // local o base
        int ob = ot + obl;
#pragma unroll
        for (int rf = 0; rf < 2; rf++) {
            int rloc = wr0 + rf * 16 + (l & 15);  // local r
            int r = rt + rloc;
            float v0 = gelu_exact(acc[of][rf][0] + conv_b[layer * 128 + ob + 0]);
            float v1 = gelu_exact(acc[of][rf][1] + conv_b[layer * 128 + ob + 1]);
            float v2 = gelu_exact(acc[of][rf][2] + conv_b[layer * 128 + ob + 2]);
            float v3 = gelu_exact(acc[of][rf][3] + conv_b[layer * 128 + ob + 3]);
            ushort4 hv, lv;
            hv.x = f2bf_hi(v0); hv.y = f2bf_hi(v1); hv.z = f2bf_hi(v2); hv.w = f2bf_hi(v3);
            lv.x = f2bf_lo(v0); lv.y = f2bf_lo(v1); lv.z = f2bf_lo(v2); lv.w = f2bf_lo(v3);
            size_t off = ((size_t)b * 512 + r) * 128 + ob;
            *(ushort4*)&hn1[off] = hv;
            *(ushort4*)&hn2[off] = lv;
            if (wtr) {
                T1[(obl + 0) * 66 + rloc] = hv.x; T1[(obl + 1) * 66 + rloc] = hv.y;
                T1[(obl + 2) * 66 + rloc] = hv.z; T1[(obl + 3) * 66 + rloc] = hv.w;
                T2[(obl + 0) * 66 + rloc] = lv.x; T2[(obl + 1) * 66 + rloc] = lv.y;
                T2[(obl + 2) * 66 + rloc] = lv.z; T2[(obl + 3) * 66 + rloc] = lv.w;
            }
        }
    }
    if (wtr) {
        __syncthreads();
#pragma unroll
        for (int q = 0; q < 8; q++) {
            int t = tid + q * 256;
            int o = t >> 5, ru = t & 31;
            u32 vh = *(const u32*)&T1[o * 66 + ru * 2];
            u32 vl = *(const u32*)&T2[o * 66 + ru * 2];
            size_t off = ((size_t)b * 128 + ot + o) * 512 + rt + ru * 2;
            *(u32*)&htc1[off] = vh;
            *(u32*)&htc2[off] = vl;
        }
    }
}

// ---------------------------------------------------------------------------
// head (MFMA, split-3): D[j=256][n] = fc1t(j,c) * ht(n,c); dx[n] =
// sum_j gelu(D+fc1b[j])*fc2w[j]; z_next = seq_last + dx + fc2b.
// grid 256 blocks (64 rows each), 4 waves x 16 rows; j reduced in-register
// + __shfl_xor across lane-groups.
// ---------------------------------------------------------------------------
__global__ __launch_bounds__(256) void head_mfma(const u16* __restrict__ ht1, const u16* __restrict__ ht2,
        const u16* __restrict__ f11, const u16* __restrict__ f12,
        const float* __restrict__ fc1_b, const float* __restrict__ fc2_w,
        const float* __restrict__ fc2_b,
        float* __restrict__ seq, float* __restrict__ preds, int step) {
    __shared__ __align__(16) u16 HA1[256 * 40], HA2[256 * 40];
    __shared__ __align__(16) u16 HB1[64 * 40], HB2[64 * 40];
    __shared__ float fc2s[256], fc1bs[256];
    int blk = blockIdx.x;            // 0..255
    int b = blk >> 3, r0 = (blk & 7) * 64;
    int tid = threadIdx.x, wid = tid >> 6, l = tid & 63;
    fc2s[tid] = fc2_w[tid];
    fc1bs[tid] = fc1_b[tid];
    int arow = l & 15, kgrp = (l >> 4) * 8;
    f32x4 acc[16];
#pragma unroll
    for (int jf = 0; jf < 16; jf++) acc[jf] = (f32x4){0.f, 0.f, 0.f, 0.f};
    for (int k0 = 0; k0 < 128; k0 += 32) {
        __syncthreads();
        // stage A (fc1t): 2 planes x 256 j x 4 segs = 2048 tasks
#pragma unroll
        for (int q = 0; q < 8; q++) {
            int t = tid + q * 256;
            int pl = t >> 10, j = (t >> 2) & 255, seg = t & 3;
            const u16* src = (pl ? f12 : f11) + (size_t)j * 128 + k0 + seg * 8;
            *(uint4*)((pl ? HA2 : HA1) + j * 40 + seg * 8) = *(const uint4*)src;
        }
        // stage B (h rows): 2 planes x 64 rows x 4 segs = 512 tasks
#pragma unroll
        for (int q = 0; q < 2; q++) {
            int t = tid + q * 256;
            int pl = t >> 8, rr = (t >> 2) & 63, seg = t & 3;
            const u16* src = (pl ? ht2 : ht1) + ((size_t)b * 512 + r0 + rr) * 128 + k0 + seg * 8;
            *(uint4*)((pl ? HB2 : HB1) + rr * 40 + seg * 8) = *(const uint4*)src;
        }
        __syncthreads();
        int bo = (wid * 16 + arow) * 40 + kgrp;
        bf16x8 b1 = *(const bf16x8*)&HB1[bo];
        bf16x8 b2 = *(const bf16x8*)&HB2[bo];
#pragma unroll 4
        for (int jf = 0; jf < 16; jf++) {
            int ao = (jf * 16 + arow) * 40 + kgrp;
            bf16x8 a1 = *(const bf16x8*)&HA1[ao];
            bf16x8 a2 = *(const bf16x8*)&HA2[ao];
            acc[jf] = MFMA16(a1, b1, acc[jf]);
            acc[jf] = MFMA16(a1, b2, acc[jf]);
            acc[jf] = MFMA16(a2, b1, acc[jf]);
        }
    }
    float dx = 0.0f;
#pragma unroll 4
    for (int jf = 0; jf < 16; jf++) {
        int jbase = jf * 16 + (l >> 4) * 4;
#pragma unroll
        for (int jj = 0; jj < 4; jj++) {
            int j = jbase + jj;
            dx += gelu_exact(acc[jf][jj] + fc1bs[j]) * fc2s[j];
        }
    }
    dx += __shfl_xor(dx, 16);
    dx += __shfl_xor(dx, 32);
    if ((l >> 4) == 0) {
        int r = r0 + wid * 16 + arow;
        float zn = seq[((size_t)b * SEQROWS + step + 23) * NR + r] + dx + fc2_b[0];
        seq[((size_t)b * SEQROWS + step + 24) * NR + r] = zn;
        preds[((size_t)b * NSTEPS + step) * NR + r] = zn;
    }
}

// ---------------------------------------------------------------------------
extern "C" void kernel_launch(void* const* d_in, const int* in_sizes, int n_in,
                              void* d_out, int out_size, void* d_ws, size_t ws_size,
                              hipStream_t stream) {
    (void)in_sizes; (void)n_in; (void)out_size; (void)ws_size;
    const float* z       = (const float*)d_in[0];
    const float* t_grid  = (const float*)d_in[1];
    const float* fc0_w   = (const float*)d_in[2];
    const float* fc0_b   = (const float*)d_in[3];
    const float* spec_wr = (const float*)d_in[4];
    const float* spec_wi = (const float*)d_in[5];
    const float* conv_w  = (const float*)d_in[6];
    const float* conv_b  = (const float*)d_in[7];
    const float* fc1_w   = (const float*)d_in[8];
    const float* fc1_b   = (const float*)d_in[9];
    const float* fc2_w   = (const float*)d_in[10];
    const float* fc2_b   = (const float*)d_in[11];
    float* preds = (float*)d_out;

    // workspace carve-up: ~65 MB
    char* p = (char*)d_ws;
    float* seq = (float*)p;  p += (size_t)NB * SEQROWS * NR * 4;
    u16* ht1 = (u16*)p;  p += (size_t)2 * NB * NR * NW * 2;   // [2 buf][b][r][c] hi
    u16* ht2 = (u16*)p;  p += (size_t)2 * NB * NR * NW * 2;   // lo
    u16* htc1 = (u16*)p; p += (size_t)NB * NW * NR * 2;       // [b][c][r] hi (single buf)
    u16* htc2 = (u16*)p; p += (size_t)NB * NW * NR * 2;       // lo
    u16* x1  = (u16*)p;  p += (size_t)128 * 4096 * 2;
    u16* x2  = (u16*)p;  p += (size_t)128 * 4096 * 2;
    u16* y1  = (u16*)p;  p += (size_t)NB * NW * 128 * 2;
    u16* y2  = (u16*)p;  p += (size_t)NB * NW * 128 * 2;
    u16* f1  = (u16*)p;  p += (size_t)128 * 512 * 2;
    u16* f2  = (u16*)p;  p += (size_t)128 * 512 * 2;
    u16* gt1 = (u16*)p;  p += (size_t)512 * 128 * 2;
    u16* gt2 = (u16*)p;  p += (size_t)512 * 128 * 2;
    u16* wr1 = (u16*)p;  p += (size_t)NLAY * NM * NW * NW * 2;
    u16* wr2 = (u16*)p;  p += (size_t)NLAY * NM * NW * NW * 2;
    u16* wi1 = (u16*)p;  p += (size_t)NLAY * NM * NW * NW * 2;
    u16* wi2 = (u16*)p;  p += (size_t)NLAY * NM * NW * NW * 2;
    u16* cw1 = (u16*)p;  p += (size_t)NLAY * NW * NW * 2;
    u16* cw2 = (u16*)p;  p += (size_t)NLAY * NW * NW * 2;
    u16* f11 = (u16*)p;  p += (size_t)256 * 128 * 2;
    u16* f12 = (u16*)p;  p += (size_t)256 * 128 * 2;

    const size_t htplane = (size_t)NB * NR * NW;   // one buffer within ht1/ht2

    build_tables_planes<<<256, 256, 0, stream>>>(f1, f2, gt1, gt2);
    prep_specw<<<256, 256, 0, stream>>>(spec_wr, spec_wi, wr1, wr2, wi1, wi2);
    prep_cw<<<256, 256, 0, stream>>>(conv_w, cw1, cw2);
    prep_fc1t<<<128, 256, 0, stream>>>(fc1_w, f11, f12);
    init_seq_kernel<<<(NB * NTH * NR) / 256, 256, 0, stream>>>(z, seq);

    for (int step = 0; step < NSTEPS; step++) {
        fc0_kernel<<<dim3(8, 32), 256, 0, stream>>>(seq, t_grid, fc0_w, fc0_b,
                                                    ht1, ht2, htc1, htc2, step);
        int cur = 0;
        for (int l = 0; l < NLAY; l++) {
            const u16* hc1 = ht1 + (size_t)cur * htplane;
            const u16* hc2 = ht2 + (size_t)cur * htplane;
            u16* hn1 = ht1 + (size_t)(cur ^ 1) * htplane;
            u16* hn2 = ht2 + (size_t)(cur ^ 1) * htplane;
            dft_mfma<<<dim3(64, 4), 256, 0, stream>>>(f1, f2, htc1, htc2, x1, x2);
            modemix_mfma<<<dim3(64, 4), 256, 0, stream>>>(x1, x2, wr1, wr2, wi1, wi2,
                                                          y1, y2, l);
            idft_conv_mfma<<<dim3(8, 2, 32), 256, 0, stream>>>(y1, y2, gt1, gt2,
                                                               hc1, hc2, cw1, cw2,
                                                               conv_b, hn1, hn2,
                                                               htc1, htc2, l, (l < 3) ? 1 : 0);
            cur ^= 1;
        }
        // after 4 layers cur == 0
        head_mfma<<<256, 256, 0, stream>>>(ht1, ht2, f11, f12, fc1_b, fc2_w, fc2_b,
                                           seq, preds, step);
    }
}

// Round 5
// 2109.768 us; speedup vs baseline: 48.0485x; 1.0585x over previous
//
#include <hip/hip_runtime.h>
#include <math.h>

// LatentFNO: B=32, T=24, R=512, W=128, M=64 modes, 4 layers, 12 steps.
// Round 5: K-loop latency was the bottleneck (serial load->barrier->MFMA at
// 1 wave/SIMD paid ~900cy/chunk). All MFMA kernels now use register prefetch
// + double-buffered LDS (1 barrier/chunk); head uses reg-prefetch single-buf.
// prep_specw rewritten as coalesced LDS-tile transpose.
// Math unchanged: exact 3-term bf16 split (A1B1+A1B2+A2B1).

#define NB 32
#define NR 512
#define NW 128
#define NM 64
#define NTH 24
#define NLAY 4
#define NSTEPS 12
#define SEQROWS 36

typedef unsigned short u16;
typedef unsigned int u32;
typedef __attribute__((ext_vector_type(8))) short bf16x8;
typedef __attribute__((ext_vector_type(4))) float f32x4;
#define MFMA16(a, b, c) __builtin_amdgcn_mfma_f32_16x16x32_bf16((a), (b), (c), 0, 0, 0)

__device__ __forceinline__ float gelu_exact(float x) {
    return 0.5f * x * (1.0f + erff(x * 0.70710678118654752f));
}
__device__ __forceinline__ float bf2f(u16 u) {
    union { u32 i; float f; } v; v.i = ((u32)u) << 16; return v.f;
}
__device__ __forceinline__ u16 f2bf_hi(float x) {
    union { float f; u32 i; } v; v.f = x; return (u16)(v.i >> 16);
}
__device__ __forceinline__ u16 f2bf_lo(float x) {
    float h = bf2f(f2bf_hi(x));
    return f2bf_hi(x - h);
}
__device__ __forceinline__ bf16x8 negbf(bf16x8 a) {
#pragma unroll
    for (int i = 0; i < 8; i++) a[i] ^= (short)0x8000;
    return a;
}

// ---------------------------------------------------------------------------
// Tables: F planes [mc=128][r=512]; GT planes [r=512][mc=128].
// ---------------------------------------------------------------------------
__global__ void build_tables_planes(u16* __restrict__ f1, u16* __restrict__ f2,
                                    u16* __restrict__ gt1, u16* __restrict__ gt2) {
    int idx = blockIdx.x * 256 + threadIdx.x;   // 65536: mc*512 + r
    int mc = idx >> 9, r = idx & 511, m = mc & 63;
    int p = (m * r) & 511;
    float a = (float)p * (1.0f / 256.0f);
    float c = cospif(a), s = sinpif(a);
    float Fv = (mc < 64) ? c : -s;
    float cm = (m == 0) ? (1.0f / 512.0f) : (2.0f / 512.0f);
    float Gv = (mc < 64) ? cm * c : ((m == 0) ? 0.0f : -cm * s);
    f1[idx] = f2bf_hi(Fv); f2[idx] = f2bf_lo(Fv);
    size_t g = (size_t)r * 128 + mc;
    gt1[g] = f2bf_hi(Gv); gt2[g] = f2bf_lo(Gv);
}

// spec_w (l,i,o,m) -> planes [l][m][o][i] hi/lo, coalesced both directions.
// Block per (l,o): read (i,m) tile m-contiguous, write i-contiguous.
__global__ __launch_bounds__(256) void prep_specw(const float* __restrict__ wr, const float* __restrict__ wi,
                           u16* __restrict__ wr1, u16* __restrict__ wr2,
                           u16* __restrict__ wi1, u16* __restrict__ wi2) {
    __shared__ float tile[128][65];
    int l = blockIdx.x >> 7, o = blockIdx.x & 127;
    int tid = threadIdx.x;
    size_t sbase = (size_t)l * 1048576 + (size_t)o * 64;          // + i*8192 + m
    size_t dbase = (size_t)l * 64 * 16384 + (size_t)o * 128;      // + m*16384 + i
    for (int pass = 0; pass < 2; pass++) {
        const float* src = pass ? wi : wr;
        u16* d1 = pass ? wi1 : wr1;
        u16* d2 = pass ? wi2 : wr2;
        if (pass) __syncthreads();
        for (int e = tid; e < 8192; e += 256) {
            int i = e >> 6, m = e & 63;
            tile[i][m] = src[sbase + (size_t)i * 8192 + m];
        }
        __syncthreads();
        for (int e = tid; e < 4096; e += 256) {
            int m = e >> 6, i2 = (e & 63) * 2;
            float v0 = tile[i2][m], v1 = tile[i2 + 1][m];
            u32 hh = (u32)f2bf_hi(v0) | ((u32)f2bf_hi(v1) << 16);
            u32 ll = (u32)f2bf_lo(v0) | ((u32)f2bf_lo(v1) << 16);
            size_t d = dbase + (size_t)m * 16384 + i2;
            *(u32*)&d1[d] = hh;
            *(u32*)&d2[d] = ll;
        }
    }
}

__global__ void prep_cw(const float* __restrict__ cw, u16* __restrict__ c1, u16* __restrict__ c2) {
    int idx = blockIdx.x * 256 + threadIdx.x;   // 65536
    float v = cw[idx];
    c1[idx] = f2bf_hi(v); c2[idx] = f2bf_lo(v);
}

// fc1_w [c=128][j=256] -> fc1t planes [j][c] hi/lo
__global__ void prep_fc1t(const float* __restrict__ fc1_w,
                          u16* __restrict__ f11, u16* __restrict__ f12) {
    int idx = blockIdx.x * 256 + threadIdx.x;   // 32768: j*128 + c
    int j = idx >> 7, c = idx & 127;
    float v = fc1_w[(size_t)c * 256 + j];
    f11[idx] = f2bf_hi(v); f12[idx] = f2bf_lo(v);
}

__global__ void init_seq_kernel(const float* __restrict__ z, float* __restrict__ seq) {
    int idx = blockIdx.x * 256 + threadIdx.x;    // < 32*24*512
    int b = idx / (NTH * NR);
    int rem = idx - b * (NTH * NR);
    seq[(size_t)b * SEQROWS * NR + rem] = z[idx];
}

// ---------------------------------------------------------------------------
// fc0 (fp32): writes ht[b][r][c] AND htc[b][c][r] planes (hi/lo).
// ---------------------------------------------------------------------------
__global__ __launch_bounds__(256) void fc0_kernel(const float* __restrict__ seq,
        const float* __restrict__ t_grid, const float* __restrict__ fc0_w,
        const float* __restrict__ fc0_b, u16* __restrict__ ht1, u16* __restrict__ ht2,
        u16* __restrict__ htc1, u16* __restrict__ htc2, int step) {
    __shared__ float wlds[28 * 128];
    __shared__ float blds[128];
    int b = blockIdx.y, rblk = blockIdx.x;
    int tid = threadIdx.x;
    for (int t = tid; t < 28 * 128; t += 256) wlds[t] = fc0_w[t];
    if (tid < 128) blds[tid] = fc0_b[tid];
    __syncthreads();
    int lane = tid & 63, wq = tid >> 6;
    int r = rblk * 64 + lane;
    float sv[24];
    const float* sp = seq + ((size_t)b * SEQROWS + step) * NR + r;
#pragma unroll
    for (int t = 0; t < 24; t++) sv[t] = sp[(size_t)t * NR];
    float tt = t_grid[b * 24 + 23] + (float)(step + 1);
    float ang24 = 6.28318530717958647692f * tt * (1.0f / 24.0f);
    float ang168 = 6.28318530717958647692f * tt * (1.0f / 168.0f);
    float s24 = sinf(ang24), c24 = cosf(ang24), s168 = sinf(ang168);
    float xc = (float)r * (1.0f / 511.0f);
    size_t rowoff = ((size_t)b * NR + r) * NW;
#pragma unroll 2
    for (int w0 = 0; w0 < 32; w0 += 2) {
        float acc2[2];
#pragma unroll
        for (int q = 0; q < 2; q++) {
            int w = wq * 32 + w0 + q;
            float acc = blds[w];
#pragma unroll
            for (int t = 0; t < 24; t++) acc += sv[t] * wlds[t * 128 + w];
            acc += s24 * wlds[24 * 128 + w] + c24 * wlds[25 * 128 + w]
                 + s168 * wlds[26 * 128 + w] + xc * wlds[27 * 128 + w];
            acc2[q] = acc;
        }
        u16 h0 = f2bf_hi(acc2[0]), h1 = f2bf_hi(acc2[1]);
        u16 l0 = f2bf_lo(acc2[0]), l1 = f2bf_lo(acc2[1]);
        size_t off = rowoff + wq * 32 + w0;
        *(u32*)&ht1[off] = (u32)h0 | ((u32)h1 << 16);
        *(u32*)&ht2[off] = (u32)l0 | ((u32)l1 << 16);
        int w = wq * 32 + w0;
        size_t coff = ((size_t)b * 128 + w) * 512 + r;
        htc1[coff] = h0; htc1[coff + 512] = h1;
        htc2[coff] = l0; htc2[coff + 512] = l1;
    }
}

// ---------------------------------------------------------------------------
// dft (MFMA, pipelined): X[mc=128][n=4096] = F[mc][r] * h[n][r]^T, K=512.
// grid (64 n-tiles, 4 mc-tiles), 256 thr = 4 waves (2 mc x 2 n).
// Double-buffered LDS, reg prefetch 2 chunks ahead, 1 barrier/chunk.
// ---------------------------------------------------------------------------
__global__ __launch_bounds__(256) void dft_mfma(const u16* __restrict__ f1, const u16* __restrict__ f2,
        const u16* __restrict__ htc1, const u16* __restrict__ htc2,
        u16* __restrict__ x1, u16* __restrict__ x2) {
    __shared__ __align__(16) u16 A1[2][1280], A2[2][1280];  // 32x40
    __shared__ __align__(16) u16 B1[2][2560], B2[2][2560];  // 64x40
    int bx = blockIdx.x;
    int b = bx >> 1, ch = bx & 1;
    int mct = blockIdx.y * 32;
    int tid = threadIdx.x, wid = tid >> 6, l = tid & 63;
    int wm0 = (wid >> 1) * 16, wn0 = (wid & 1) * 32;
    int arow = (l & 15), kgrp = (l >> 4) * 8;
    f32x4 acc0 = {0.f, 0.f, 0.f, 0.f}, acc1 = {0.f, 0.f, 0.f, 0.f};
    // per-thread fixed staging roles
    int pa_pl = tid >> 7, pa_row = (tid >> 2) & 31, pa_seg = tid & 3;
    const u16* asrc = (pa_pl ? f2 : f1) + (size_t)(mct + pa_row) * 512 + pa_seg * 8;
    int aoff = pa_row * 40 + pa_seg * 8;
    int b_row = (tid >> 2) & 63, b_seg = tid & 3;
    const u16* bsrc1 = htc1 + ((size_t)b * 128 + ch * 64 + b_row) * 512 + b_seg * 8;
    const u16* bsrc2 = htc2 + ((size_t)b * 128 + ch * 64 + b_row) * 512 + b_seg * 8;
    int boff = b_row * 40 + b_seg * 8;
    uint4 ra, rb0, rb1;
    // prologue: chunk 0 -> buf0; issue chunk 1
    ra  = *(const uint4*)(asrc);
    rb0 = *(const uint4*)(bsrc1);
    rb1 = *(const uint4*)(bsrc2);
    *(uint4*)((pa_pl ? A2[0] : A1[0]) + aoff) = ra;
    *(uint4*)(B1[0] + boff) = rb0;
    *(uint4*)(B2[0] + boff) = rb1;
    ra  = *(const uint4*)(asrc + 32);
    rb0 = *(const uint4*)(bsrc1 + 32);
    rb1 = *(const uint4*)(bsrc2 + 32);
    __syncthreads();
    for (int k = 0; k < 16; k++) {
        int cur = k & 1;
        bf16x8 a1 = *(const bf16x8*)&A1[cur][(wm0 + arow) * 40 + kgrp];
        bf16x8 a2 = *(const bf16x8*)&A2[cur][(wm0 + arow) * 40 + kgrp];
        bf16x8 b10 = *(const bf16x8*)&B1[cur][(wn0 + arow) * 40 + kgrp];
        bf16x8 b20 = *(const bf16x8*)&B2[cur][(wn0 + arow) * 40 + kgrp];
        bf16x8 b11 = *(const bf16x8*)&B1[cur][(wn0 + 16 + arow) * 40 + kgrp];
        bf16x8 b21 = *(const bf16x8*)&B2[cur][(wn0 + 16 + arow) * 40 + kgrp];
        acc0 = MFMA16(a1, b10, acc0);
        acc0 = MFMA16(a1, b20, acc0);
        acc0 = MFMA16(a2, b10, acc0);
        acc1 = MFMA16(a1, b11, acc1);
        acc1 = MFMA16(a1, b21, acc1);
        acc1 = MFMA16(a2, b11, acc1);
        if (k < 15) {
            *(uint4*)((pa_pl ? A2[cur ^ 1] : A1[cur ^ 1]) + aoff) = ra;
            *(uint4*)(B1[cur ^ 1] + boff) = rb0;
            *(uint4*)(B2[cur ^ 1] + boff) = rb1;
            if (k < 14) {
                int ko = (k + 2) * 32;
                ra  = *(const uint4*)(asrc + ko);
                rb0 = *(const uint4*)(bsrc1 + ko);
                rb1 = *(const uint4*)(bsrc2 + ko);
            }
        }
        __syncthreads();
    }
    int mcr = mct + wm0 + (l >> 4) * 4;
    int n0 = bx * 64 + wn0 + (l & 15);
#pragma unroll
    for (int j = 0; j < 4; j++) {
        size_t o0 = (size_t)(mcr + j) * 4096 + n0;
        x1[o0] = f2bf_hi(acc0[j]); x2[o0] = f2bf_lo(acc0[j]);
        size_t o1 = o0 + 16;
        x1[o1] = f2bf_hi(acc1[j]); x2[o1] = f2bf_lo(acc1[j]);
    }
}

// ---------------------------------------------------------------------------
// modemix (MFMA, pipelined): per mode m: Y[o][b] = W[m](o,i) *c X[b,i,m], K=128.
// grid (64 m, 4 oq), 256 thr = 4 waves (2 o x 2 b). Double-buffered.
// ---------------------------------------------------------------------------
__global__ __launch_bounds__(256) void modemix_mfma(const u16* __restrict__ x1, const u16* __restrict__ x2,
        const u16* __restrict__ wr1, const u16* __restrict__ wr2,
        const u16* __restrict__ wi1, const u16* __restrict__ wi2,
        u16* __restrict__ y1, u16* __restrict__ y2, int layer) {
    __shared__ __align__(16) u16 WR1[2][1280], WR2[2][1280], WI1[2][1280], WI2[2][1280];
    __shared__ __align__(16) u16 XR1[2][1280], XR2[2][1280], XI1[2][1280], XI2[2][1280];
    int m = blockIdx.x, oq = blockIdx.y;
    int tid = threadIdx.x, wid = tid >> 6, l = tid & 63;
    int wo0 = (wid >> 1) * 16, wb0 = (wid & 1) * 16;
    int arow = (l & 15), kgrp = (l >> 4) * 8;
    f32x4 ar = {0.f, 0.f, 0.f, 0.f}, ai = {0.f, 0.f, 0.f, 0.f};
    size_t wbase = (((size_t)layer * 64 + m) * 128 + oq * 32) * 128;
    // per-thread fixed roles: s0 = tid>>7 in {0,1}; handles W slabs s0,s0+2 and X slabs s0,s0+2
    int s0 = tid >> 7, srow = (tid >> 2) & 31, sseg = tid & 3;
    const u16* wsrc0 = (s0 ? wr2 : wr1) + wbase + (size_t)srow * 128 + sseg * 8;
    const u16* wsrc1 = (s0 ? wi2 : wi1) + wbase + (size_t)srow * 128 + sseg * 8;
    const u16* xb = s0 ? x2 : x1;
    const u16* xsrc0 = xb + (size_t)m * 4096 + srow * 128 + sseg * 8;
    const u16* xsrc1 = xb + (size_t)(64 + m) * 4096 + srow * 128 + sseg * 8;
    int soff = srow * 40 + sseg * 8;
    u16* wd0_0 = (s0 ? WR2[0] : WR1[0]) + soff;  u16* wd0_1 = (s0 ? WR2[1] : WR1[1]) + soff;
    u16* wd1_0 = (s0 ? WI2[0] : WI1[0]) + soff;  u16* wd1_1 = (s0 ? WI2[1] : WI1[1]) + soff;
    u16* xd0_0 = (s0 ? XR2[0] : XR1[0]) + soff;  u16* xd0_1 = (s0 ? XR2[1] : XR1[1]) + soff;
    u16* xd1_0 = (s0 ? XI2[0] : XI1[0]) + soff;  u16* xd1_1 = (s0 ? XI2[1] : XI1[1]) + soff;
    uint4 rw0, rw1, rx0, rx1;
    rw0 = *(const uint4*)(wsrc0); rw1 = *(const uint4*)(wsrc1);
    rx0 = *(const uint4*)(xsrc0); rx1 = *(const uint4*)(xsrc1);
    *(uint4*)wd0_0 = rw0; *(uint4*)wd1_0 = rw1;
    *(uint4*)xd0_0 = rx0; *(uint4*)xd1_0 = rx1;
    rw0 = *(const uint4*)(wsrc0 + 32); rw1 = *(const uint4*)(wsrc1 + 32);
    rx0 = *(const uint4*)(xsrc0 + 32); rx1 = *(const uint4*)(xsrc1 + 32);
    __syncthreads();
    for (int k = 0; k < 4; k++) {
        int cur = k & 1;
        int ao = (wo0 + arow) * 40 + kgrp;
        int bo = (wb0 + arow) * 40 + kgrp;
        bf16x8 Wr1 = *(const bf16x8*)&WR1[cur][ao], Wr2 = *(const bf16x8*)&WR2[cur][ao];
        bf16x8 Wi1 = *(const bf16x8*)&WI1[cur][ao], Wi2 = *(const bf16x8*)&WI2[cur][ao];
        bf16x8 Xr1 = *(const bf16x8*)&XR1[cur][bo], Xr2 = *(const bf16x8*)&XR2[cur][bo];
        bf16x8 Xi1 = *(const bf16x8*)&XI1[cur][bo], Xi2 = *(const bf16x8*)&XI2[cur][bo];
        bf16x8 nWi1 = negbf(Wi1), nWi2 = negbf(Wi2);
        ar = MFMA16(Wr1, Xr1, ar); ar = MFMA16(Wr1, Xr2, ar); ar = MFMA16(Wr2, Xr1, ar);
        ar = MFMA16(nWi1, Xi1, ar); ar = MFMA16(nWi1, Xi2, ar); ar = MFMA16(nWi2, Xi1, ar);
        ai = MFMA16(Wi1, Xr1, ai); ai = MFMA16(Wi1, Xr2, ai); ai = MFMA16(Wi2, Xr1, ai);
        ai = MFMA16(Wr1, Xi1, ai); ai = MFMA16(Wr1, Xi2, ai); ai = MFMA16(Wr2, Xi1, ai);
        if (k < 3) {
            if (cur) { *(uint4*)wd0_0 = rw0; *(uint4*)wd1_0 = rw1; *(uint4*)xd0_0 = rx0; *(uint4*)xd1_0 = rx1; }
            else     { *(uint4*)wd0_1 = rw0; *(uint4*)wd1_1 = rw1; *(uint4*)xd0_1 = rx0; *(uint4*)xd1_1 = rx1; }
            if (k < 2) {
                int ko = (k + 2) * 32;
                rw0 = *(const uint4*)(wsrc0 + ko); rw1 = *(const uint4*)(wsrc1 + ko);
                rx0 = *(const uint4*)(xsrc0 + ko); rx1 = *(const uint4*)(xsrc1 + ko);
            }
        }
        __syncthreads();
    }
    int ob = oq * 32 + wo0 + (l >> 4) * 4;
    int bb = wb0 + (l & 15);
#pragma unroll
    for (int j = 0; j < 4; j++) {
        size_t o = ((size_t)bb * 128 + ob + j) * 128;
        y1[o + m] = f2bf_hi(ar[j]); y2[o + m] = f2bf_lo(ar[j]);
        y1[o + 64 + m] = f2bf_hi(ai[j]); y2[o + 64 + m] = f2bf_lo(ai[j]);
    }
}

// ---------------------------------------------------------------------------
// idft+conv (MFMA, pipelined): C[o][r] = [Y|CW](o,k=256)*[GT;ht](k,r)+bias,GELU.
// grid (8 rt, 2 ot, 32 b). Double-buffered; T-transpose epilogue for htc.
// ---------------------------------------------------------------------------
__global__ __launch_bounds__(256) void idft_conv_mfma(const u16* __restrict__ y1, const u16* __restrict__ y2,
        const u16* __restrict__ gt1, const u16* __restrict__ gt2,
        const u16* __restrict__ hc1, const u16* __restrict__ hc2,
        const u16* __restrict__ cw1, const u16* __restrict__ cw2,
        const float* __restrict__ conv_b,
        u16* __restrict__ hn1, u16* __restrict__ hn2,
        u16* __restrict__ htc1, u16* __restrict__ htc2, int layer, int wtr) {
    __shared__ __align__(16) u16 A1[2][2560], A2[2][2560];
    __shared__ __align__(16) u16 B1[2][2560], B2[2][2560];
    __shared__ __align__(16) u16 T1[64 * 66], T2[64 * 66];
    int rt = blockIdx.x * 64, ot = blockIdx.y * 64, b = blockIdx.z;
    int tid = threadIdx.x, wid = tid >> 6, l = tid & 63;
    int wo0 = (wid >> 1) * 32, wr0 = (wid & 1) * 32;
    int arow = (l & 15), kgrp = (l >> 4) * 8;
    int srow = (tid >> 2) & 63, sseg = tid & 3;
    int soff = srow * 40 + sseg * 8;
    // fixed source bases (chunk-dependent choice made in loader)
    const u16* ya = y1 + ((size_t)b * 128 + ot + srow) * 128 + sseg * 8;
    const u16* yb = y2 + ((size_t)b * 128 + ot + srow) * 128 + sseg * 8;
    const u16* ca = cw1 + ((size_t)layer * 128 + ot + srow) * 128 + sseg * 8;
    const u16* cb = cw2 + ((size_t)layer * 128 + ot + srow) * 128 + sseg * 8;
    const u16* ga = gt1 + (size_t)(rt + srow) * 128 + sseg * 8;
    const u16* gb = gt2 + (size_t)(rt + srow) * 128 + sseg * 8;
    const u16* ha = hc1 + ((size_t)b * 512 + rt + srow) * 128 + sseg * 8;
    const u16* hb = hc2 + ((size_t)b * 512 + rt + srow) * 128 + sseg * 8;
    f32x4 acc[2][2] = {{{0.f,0.f,0.f,0.f},{0.f,0.f,0.f,0.f}},{{0.f,0.f,0.f,0.f},{0.f,0.f,0.f,0.f}}};
    uint4 ra0, ra1, rb0, rb1;
#define IDFT_LOAD(chk)                                                        \
    {   int k0_ = ((chk) & 3) * 32;                                           \
        if ((chk) < 4) {                                                      \
            ra0 = *(const uint4*)(ya + k0_); ra1 = *(const uint4*)(yb + k0_); \
            rb0 = *(const uint4*)(ga + k0_); rb1 = *(const uint4*)(gb + k0_); \
        } else {                                                              \
            ra0 = *(const uint4*)(ca + k0_); ra1 = *(const uint4*)(cb + k0_); \
            rb0 = *(const uint4*)(ha + k0_); rb1 = *(const uint4*)(hb + k0_); \
        } }
    IDFT_LOAD(0)
    *(uint4*)(A1[0] + soff) = ra0; *(uint4*)(A2[0] + soff) = ra1;
    *(uint4*)(B1[0] + soff) = rb0; *(uint4*)(B2[0] + soff) = rb1;
    IDFT_LOAD(1)
    __syncthreads();
    for (int k = 0; k < 8; k++) {
        int cur = k & 1;
        bf16x8 bfr[2][2];
#pragma unroll
        for (int rf = 0; rf < 2; rf++) {
            bfr[rf][0] = *(const bf16x8*)&B1[cur][(wr0 + rf * 16 + arow) * 40 + kgrp];
            bfr[rf][1] = *(const bf16x8*)&B2[cur][(wr0 + rf * 16 + arow) * 40 + kgrp];
        }
#pragma unroll
        for (int of = 0; of < 2; of++) {
            bf16x8 a1 = *(const bf16x8*)&A1[cur][(wo0 + of * 16 + arow) * 40 + kgrp];
            bf16x8 a2 = *(const bf16x8*)&A2[cur][(wo0 + of * 16 + arow) * 40 + kgrp];
#pragma unroll
            for (int rf = 0; rf < 2; rf++) {
                acc[of][rf] = MFMA16(a1, bfr[rf][0], acc[of][rf]);
                acc[of][rf] = MFMA16(a1, bfr[rf][1], acc[of][rf]);
                acc[of][rf] = MFMA16(a2, bfr[rf][0], acc[of][rf]);
            }
        }
        if (k < 7) {
            *(uint4*)(A1[cur ^ 1] + soff) = ra0; *(uint4*)(A2[cur ^ 1] + soff) = ra1;
            *(uint4*)(B1[cur ^ 1] + soff) = rb0; *(uint4*)(B2[cur ^ 1] + soff) = rb1;
            if (k < 6) IDFT_LOAD(k + 2)
        }
        __syncthreads();
    }
#undef IDFT_LOAD
#pragma unroll
    for (int of = 0; of < 2; of++) {
        int obl = wo0 + of * 16 + (l >> 4) * 4;
        int ob = ot + obl;
#pragma unroll
        for (int rf = 0; rf < 2; rf++) {
            int rloc = wr0 + rf * 16 + (l & 15);
            int r = rt + rloc;
            float v0 = gelu_exact(acc[of][rf][0] + conv_b[layer * 128 + ob + 0]);
            float v1 = gelu_exact(acc[of][rf][1] + conv_b[layer * 128 + ob + 1]);
            float v2 = gelu_exact(acc[of][rf][2] + conv_b[layer * 128 + ob + 2]);
            float v3 = gelu_exact(acc[of][rf][3] + conv_b[layer * 128 + ob + 3]);
            ushort4 hv, lv;
            hv.x = f2bf_hi(v0); hv.y = f2bf_hi(v1); hv.z = f2bf_hi(v2); hv.w = f2bf_hi(v3);
            lv.x = f2bf_lo(v0); lv.y = f2bf_lo(v1); lv.z = f2bf_lo(v2); lv.w = f2bf_lo(v3);
            size_t off = ((size_t)b * 512 + r) * 128 + ob;
            *(ushort4*)&hn1[off] = hv;
            *(ushort4*)&hn2[off] = lv;
            if (wtr) {
                T1[(obl + 0) * 66 + rloc] = hv.x; T1[(obl + 1) * 66 + rloc] = hv.y;
                T1[(obl + 2) * 66 + rloc] = hv.z; T1[(obl + 3) * 66 + rloc] = hv.w;
                T2[(obl + 0) * 66 + rloc] = lv.x; T2[(obl + 1) * 66 + rloc] = lv.y;
                T2[(obl + 2) * 66 + rloc] = lv.z; T2[(obl + 3) * 66 + rloc] = lv.w;
            }
        }
    }
    if (wtr) {
        __syncthreads();
#pragma unroll
        for (int q = 0; q < 8; q++) {
            int t = tid + q * 256;
            int o = t >> 5, ru = t & 31;
            u32 vh = *(const u32*)&T1[o * 66 + ru * 2];
            u32 vl = *(const u32*)&T2[o * 66 + ru * 2];
            size_t off = ((size_t)b * 128 + ot + o) * 512 + rt + ru * 2;
            *(u32*)&htc1[off] = vh;
            *(u32*)&htc2[off] = vl;
        }
    }
}

// ---------------------------------------------------------------------------
// head (MFMA, reg-prefetch single-buffer): fc1 GEMM + gelu + fc2 reduce + z.
// grid 256 blocks (64 rows each), 4 waves x 16 rows.
// ---------------------------------------------------------------------------
__global__ __launch_bounds__(256) void head_mfma(const u16* __restrict__ ht1, const u16* __restrict__ ht2,
        const u16* __restrict__ f11, const u16* __restrict__ f12,
        const float* __restrict__ fc1_b, const float* __restrict__ fc2_w,
        const float* __restrict__ fc2_b,
        float* __restrict__ seq, float* __restrict__ preds, int step) {
    __shared__ __align__(16) u16 HA1[256 * 40], HA2[256 * 40];
    __shared__ __align__(16) u16 HB1[64 * 40], HB2[64 * 40];
    __shared__ float fc2s[256], fc1bs[256];
    int blk = blockIdx.x;
    int b = blk >> 3, r0 = (blk & 7) * 64;
    int tid = threadIdx.x, wid = tid >> 6, l = tid & 63;
    fc2s[tid] = fc2_w[tid];
    fc1bs[tid] = fc1_b[tid];
    int arow = l & 15, kgrp = (l >> 4) * 8;
    int jrow = tid >> 2, seg = tid & 3;        // jrow in [0,64)
    const u16* a1src = f11 + (size_t)jrow * 128 + seg * 8;
    const u16* a2src = f12 + (size_t)jrow * 128 + seg * 8;
    const u16* b1src = ht1 + ((size_t)b * 512 + r0 + jrow) * 128 + seg * 8;
    const u16* b2src = ht2 + ((size_t)b * 512 + r0 + jrow) * 128 + seg * 8;
    int aoff = jrow * 40 + seg * 8;
    f32x4 acc[16];
#pragma unroll
    for (int jf = 0; jf < 16; jf++) acc[jf] = (f32x4){0.f, 0.f, 0.f, 0.f};
    uint4 ra[8], rb[2];
#define HEAD_LOAD(k0_)                                                         \
    {   _Pragma("unroll")                                                      \
        for (int q = 0; q < 4; q++) {                                          \
            ra[q]     = *(const uint4*)(a1src + (size_t)q * 64 * 128 + (k0_)); \
            ra[q + 4] = *(const uint4*)(a2src + (size_t)q * 64 * 128 + (k0_)); \
        }                                                                      \
        rb[0] = *(const uint4*)(b1src + (k0_));                                \
        rb[1] = *(const uint4*)(b2src + (k0_)); }
#define HEAD_WRITE()                                                           \
    {   _Pragma("unroll")                                                      \
        for (int q = 0; q < 4; q++) {                                          \
            *(uint4*)(HA1 + aoff + q * 64 * 40) = ra[q];                       \
            *(uint4*)(HA2 + aoff + q * 64 * 40) = ra[q + 4];                   \
        }                                                                      \
        *(uint4*)(HB1 + aoff) = rb[0];                                         \
        *(uint4*)(HB2 + aoff) = rb[1]; }
    HEAD_LOAD(0)
    HEAD_WRITE()
    HEAD_LOAD(32)
    __syncthreads();
    for (int k = 0; k < 4; k++) {
        int bo = (wid * 16 + arow) * 40 + kgrp;
        bf16x8 b1 = *(const bf16x8*)&HB1[bo];
        bf16x8 b2 = *(const bf16x8*)&HB2[bo];
#pragma unroll 4
        for (int jf = 0; jf < 16; jf++) {
            int ao = (jf * 16 + arow) * 40 + kgrp;
            bf16x8 a1 = *(const bf16x8*)&HA1[ao];
            bf16x8 a2 = *(const bf16x8*)&HA2[ao];
            acc[jf] = MFMA16(a1, b1, acc[jf]);
            acc[jf] = MFMA16(a1, b2, acc[jf]);
            acc[jf] = MFMA16(a2, b1, acc[jf]);
        }
        __syncthreads();
        if (k < 3) {
            HEAD_WRITE()
            if (k < 2) HEAD_LOAD((k + 2) * 32)
            __syncthreads();
        }
    }
#undef HEAD_LOAD
#undef HEAD_WRITE
    float dx = 0.0f;
#pragma unroll 4
    for (int jf = 0; jf < 16; jf++) {
        int jbase = jf * 16 + (l >> 4) * 4;
#pragma unroll
        for (int jj = 0; jj < 4; jj++) {
            int j = jbase + jj;
            dx += gelu_exact(acc[jf][jj] + fc1bs[j]) * fc2s[j];
        }
    }
    dx += __shfl_xor(dx, 16);
    dx += __shfl_xor(dx, 32);
    if ((l >> 4) == 0) {
        int r = r0 + wid * 16 + arow;
        float zn = seq[((size_t)b * SEQROWS + step + 23) * NR + r] + dx + fc2_b[0];
        seq[((size_t)b * SEQROWS + step + 24) * NR + r] = zn;
        preds[((size_t)b * NSTEPS + step) * NR + r] = zn;
    }
}

// ---------------------------------------------------------------------------
extern "C" void kernel_launch(void* const* d_in, const int* in_sizes, int n_in,
                              void* d_out, int out_size, void* d_ws, size_t ws_size,
                              hipStream_t stream) {
    (void)in_sizes; (void)n_in; (void)out_size; (void)ws_size;
    const float* z       = (const float*)d_in[0];
    const float* t_grid  = (const float*)d_in[1];
    const float* fc0_w   = (const float*)d_in[2];
    const float* fc0_b   = (const float*)d_in[3];
    const float* spec_wr = (const float*)d_in[4];
    const float* spec_wi = (const float*)d_in[5];
    const float* conv_w  = (const float*)d_in[6];
    const float* conv_b  = (const float*)d_in[7];
    const float* fc1_b   = (const float*)d_in[9];
    const float* fc1_w   = (const float*)d_in[8];
    const float* fc2_w   = (const float*)d_in[10];
    const float* fc2_b   = (const float*)d_in[11];
    float* preds = (float*)d_out;

    char* p = (char*)d_ws;
    float* seq = (float*)p;  p += (size_t)NB * SEQROWS * NR * 4;
    u16* ht1 = (u16*)p;  p += (size_t)2 * NB * NR * NW * 2;   // [2 buf][b][r][c] hi
    u16* ht2 = (u16*)p;  p += (size_t)2 * NB * NR * NW * 2;   // lo
    u16* htc1 = (u16*)p; p += (size_t)NB * NW * NR * 2;       // [b][c][r] hi
    u16* htc2 = (u16*)p; p += (size_t)NB * NW * NR * 2;       // lo
    u16* x1  = (u16*)p;  p += (size_t)128 * 4096 * 2;
    u16* x2  = (u16*)p;  p += (size_t)128 * 4096 * 2;
    u16* y1  = (u16*)p;  p += (size_t)NB * NW * 128 * 2;
    u16* y2  = (u16*)p;  p += (size_t)NB * NW * 128 * 2;
    u16* f1  = (u16*)p;  p += (size_t)128 * 512 * 2;
    u16* f2  = (u16*)p;  p += (size_t)128 * 512 * 2;
    u16* gt1 = (u16*)p;  p += (size_t)512 * 128 * 2;
    u16* gt2 = (u16*)p;  p += (size_t)512 * 128 * 2;
    u16* wr1 = (u16*)p;  p += (size_t)NLAY * NM * NW * NW * 2;
    u16* wr2 = (u16*)p;  p += (size_t)NLAY * NM * NW * NW * 2;
    u16* wi1 = (u16*)p;  p += (size_t)NLAY * NM * NW * NW * 2;
    u16* wi2 = (u16*)p;  p += (size_t)NLAY * NM * NW * NW * 2;
    u16* cw1 = (u16*)p;  p += (size_t)NLAY * NW * NW * 2;
    u16* cw2 = (u16*)p;  p += (size_t)NLAY * NW * NW * 2;
    u16* f11 = (u16*)p;  p += (size_t)256 * 128 * 2;
    u16* f12 = (u16*)p;  p += (size_t)256 * 128 * 2;

    const size_t htplane = (size_t)NB * NR * NW;

    build_tables_planes<<<256, 256, 0, stream>>>(f1, f2, gt1, gt2);
    prep_specw<<<512, 256, 0, stream>>>(spec_wr, spec_wi, wr1, wr2, wi1, wi2);
    prep_cw<<<256, 256, 0, stream>>>(conv_w, cw1, cw2);
    prep_fc1t<<<128, 256, 0, stream>>>(fc1_w, f11, f12);
    init_seq_kernel<<<(NB * NTH * NR) / 256, 256, 0, stream>>>(z, seq);

    for (int step = 0; step < NSTEPS; step++) {
        fc0_kernel<<<dim3(8, 32), 256, 0, stream>>>(seq, t_grid, fc0_w, fc0_b,
                                                    ht1, ht2, htc1, htc2, step);
        int cur = 0;
        for (int l = 0; l < NLAY; l++) {
            const u16* hc1 = ht1 + (size_t)cur * htplane;
            const u16* hc2 = ht2 + (size_t)cur * htplane;
            u16* hn1 = ht1 + (size_t)(cur ^ 1) * htplane;
            u16* hn2 = ht2 + (size_t)(cur ^ 1) * htplane;
            dft_mfma<<<dim3(64, 4), 256, 0, stream>>>(f1, f2, htc1, htc2, x1, x2);
            modemix_mfma<<<dim3(64, 4), 256, 0, stream>>>(x1, x2, wr1, wr2, wi1, wi2,
                                                          y1, y2, l);
            idft_conv_mfma<<<dim3(8, 2, 32), 256, 0, stream>>>(y1, y2, gt1, gt2,
                                                               hc1, hc2, cw1, cw2,
                                                               conv_b, hn1, hn2,
                                                               htc1, htc2, l, (l < 3) ? 1 : 0);
            cur ^= 1;
        }
        head_mfma<<<256, 256, 0, stream>>>(ht1, ht2, f11, f12, fc1_b, fc2_w, fc2_b,
                                           seq, preds, step);
    }
}

// Round 6
// 2105.882 us; speedup vs baseline: 48.1372x; 1.0018x over previous
//
#include <hip/hip_runtime.h>
#include <math.h>

// LatentFNO: B=32, T=24, R=512, W=128, M=64 modes, 4 layers, 12 steps.
// Round 5: K-loop latency was the bottleneck (serial load->barrier->MFMA at
// 1 wave/SIMD paid ~900cy/chunk). All MFMA kernels now use register prefetch
// + double-buffered LDS (1 barrier/chunk); head uses reg-prefetch single-buf.
// prep_specw rewritten as coalesced LDS-tile transpose.
// Math unchanged: exact 3-term bf16 split (A1B1+A1B2+A2B1).

#define NB 32
#define NR 512
#define NW 128
#define NM 64
#define NTH 24
#define NLAY 4
#define NSTEPS 12
#define SEQROWS 36

typedef unsigned short u16;
typedef unsigned int u32;
typedef __attribute__((ext_vector_type(8))) short bf16x8;
typedef __attribute__((ext_vector_type(4))) float f32x4;
#define MFMA16(a, b, c) __builtin_amdgcn_mfma_f32_16x16x32_bf16((a), (b), (c), 0, 0, 0)

__device__ __forceinline__ float gelu_exact(float x) {
    return 0.5f * x * (1.0f + erff(x * 0.70710678118654752f));
}
__device__ __forceinline__ float bf2f(u16 u) {
    union { u32 i; float f; } v; v.i = ((u32)u) << 16; return v.f;
}
__device__ __forceinline__ u16 f2bf_hi(float x) {
    union { float f; u32 i; } v; v.f = x; return (u16)(v.i >> 16);
}
__device__ __forceinline__ u16 f2bf_lo(float x) {
    float h = bf2f(f2bf_hi(x));
    return f2bf_hi(x - h);
}
__device__ __forceinline__ bf16x8 negbf(bf16x8 a) {
#pragma unroll
    for (int i = 0; i < 8; i++) a[i] ^= (short)0x8000;
    return a;
}

// ---------------------------------------------------------------------------
// Tables: F planes [mc=128][r=512]; GT planes [r=512][mc=128].
// ---------------------------------------------------------------------------
__global__ void build_tables_planes(u16* __restrict__ f1, u16* __restrict__ f2,
                                    u16* __restrict__ gt1, u16* __restrict__ gt2) {
    int idx = blockIdx.x * 256 + threadIdx.x;   // 65536: mc*512 + r
    int mc = idx >> 9, r = idx & 511, m = mc & 63;
    int p = (m * r) & 511;
    float a = (float)p * (1.0f / 256.0f);
    float c = cospif(a), s = sinpif(a);
    float Fv = (mc < 64) ? c : -s;
    float cm = (m == 0) ? (1.0f / 512.0f) : (2.0f / 512.0f);
    float Gv = (mc < 64) ? cm * c : ((m == 0) ? 0.0f : -cm * s);
    f1[idx] = f2bf_hi(Fv); f2[idx] = f2bf_lo(Fv);
    size_t g = (size_t)r * 128 + mc;
    gt1[g] = f2bf_hi(Gv); gt2[g] = f2bf_lo(Gv);
}

// spec_w (l,i,o,m) -> planes [l][m][o][i] hi/lo, coalesced both directions.
// Block per (l,o): read (i,m) tile m-contiguous, write i-contiguous.
__global__ __launch_bounds__(256) void prep_specw(const float* __restrict__ wr, const float* __restrict__ wi,
                           u16* __restrict__ wr1, u16* __restrict__ wr2,
                           u16* __restrict__ wi1, u16* __restrict__ wi2) {
    __shared__ float tile[128][65];
    int l = blockIdx.x >> 7, o = blockIdx.x & 127;
    int tid = threadIdx.x;
    size_t sbase = (size_t)l * 1048576 + (size_t)o * 64;          // + i*8192 + m
    size_t dbase = (size_t)l * 64 * 16384 + (size_t)o * 128;      // + m*16384 + i
    for (int pass = 0; pass < 2; pass++) {
        const float* src = pass ? wi : wr;
        u16* d1 = pass ? wi1 : wr1;
        u16* d2 = pass ? wi2 : wr2;
        if (pass) __syncthreads();
        for (int e = tid; e < 8192; e += 256) {
            int i = e >> 6, m = e & 63;
            tile[i][m] = src[sbase + (size_t)i * 8192 + m];
        }
        __syncthreads();
        for (int e = tid; e < 4096; e += 256) {
            int m = e >> 6, i2 = (e & 63) * 2;
            float v0 = tile[i2][m], v1 = tile[i2 + 1][m];
            u32 hh = (u32)f2bf_hi(v0) | ((u32)f2bf_hi(v1) << 16);
            u32 ll = (u32)f2bf_lo(v0) | ((u32)f2bf_lo(v1) << 16);
            size_t d = dbase + (size_t)m * 16384 + i2;
            *(u32*)&d1[d] = hh;
            *(u32*)&d2[d] = ll;
        }
    }
}

__global__ void prep_cw(const float* __restrict__ cw, u16* __restrict__ c1, u16* __restrict__ c2) {
    int idx = blockIdx.x * 256 + threadIdx.x;   // 65536
    float v = cw[idx];
    c1[idx] = f2bf_hi(v); c2[idx] = f2bf_lo(v);
}

// fc1_w [c=128][j=256] -> fc1t planes [j][c] hi/lo
__global__ void prep_fc1t(const float* __restrict__ fc1_w,
                          u16* __restrict__ f11, u16* __restrict__ f12) {
    int idx = blockIdx.x * 256 + threadIdx.x;   // 32768: j*128 + c
    int j = idx >> 7, c = idx & 127;
    float v = fc1_w[(size_t)c * 256 + j];
    f11[idx] = f2bf_hi(v); f12[idx] = f2bf_lo(v);
}

__global__ void init_seq_kernel(const float* __restrict__ z, float* __restrict__ seq) {
    int idx = blockIdx.x * 256 + threadIdx.x;    // < 32*24*512
    int b = idx / (NTH * NR);
    int rem = idx - b * (NTH * NR);
    seq[(size_t)b * SEQROWS * NR + rem] = z[idx];
}

// ---------------------------------------------------------------------------
// fc0 (fp32): writes ht[b][r][c] AND htc[b][c][r] planes (hi/lo).
// ---------------------------------------------------------------------------
__global__ __launch_bounds__(256) void fc0_kernel(const float* __restrict__ seq,
        const float* __restrict__ t_grid, const float* __restrict__ fc0_w,
        const float* __restrict__ fc0_b, u16* __restrict__ ht1, u16* __restrict__ ht2,
        u16* __restrict__ htc1, u16* __restrict__ htc2, int step) {
    __shared__ float wlds[28 * 128];
    __shared__ float blds[128];
    int b = blockIdx.y, rblk = blockIdx.x;
    int tid = threadIdx.x;
    for (int t = tid; t < 28 * 128; t += 256) wlds[t] = fc0_w[t];
    if (tid < 128) blds[tid] = fc0_b[tid];
    __syncthreads();
    int lane = tid & 63, wq = tid >> 6;
    int r = rblk * 64 + lane;
    float sv[24];
    const float* sp = seq + ((size_t)b * SEQROWS + step) * NR + r;
#pragma unroll
    for (int t = 0; t < 24; t++) sv[t] = sp[(size_t)t * NR];
    float tt = t_grid[b * 24 + 23] + (float)(step + 1);
    float ang24 = 6.28318530717958647692f * tt * (1.0f / 24.0f);
    float ang168 = 6.28318530717958647692f * tt * (1.0f / 168.0f);
    float s24 = sinf(ang24), c24 = cosf(ang24), s168 = sinf(ang168);
    float xc = (float)r * (1.0f / 511.0f);
    size_t rowoff = ((size_t)b * NR + r) * NW;
#pragma unroll 2
    for (int w0 = 0; w0 < 32; w0 += 2) {
        float acc2[2];
#pragma unroll
        for (int q = 0; q < 2; q++) {
            int w = wq * 32 + w0 + q;
            float acc = blds[w];
#pragma unroll
            for (int t = 0; t < 24; t++) acc += sv[t] * wlds[t * 128 + w];
            acc += s24 * wlds[24 * 128 + w] + c24 * wlds[25 * 128 + w]
                 + s168 * wlds[26 * 128 + w] + xc * wlds[27 * 128 + w];
            acc2[q] = acc;
        }
        u16 h0 = f2bf_hi(acc2[0]), h1 = f2bf_hi(acc2[1]);
        u16 l0 = f2bf_lo(acc2[0]), l1 = f2bf_lo(acc2[1]);
        size_t off = rowoff + wq * 32 + w0;
        *(u32*)&ht1[off] = (u32)h0 | ((u32)h1 << 16);
        *(u32*)&ht2[off] = (u32)l0 | ((u32)l1 << 16);
        int w = wq * 32 + w0;
        size_t coff = ((size_t)b * 128 + w) * 512 + r;
        htc1[coff] = h0; htc1[coff + 512] = h1;
        htc2[coff] = l0; htc2[coff + 512] = l1;
    }
}

// ---------------------------------------------------------------------------
// dft (MFMA, pipelined): X[mc=128][n=4096] = F[mc][r] * h[n][r]^T, K=512.
// grid (64 n-tiles, 4 mc-tiles), 256 thr = 4 waves (2 mc x 2 n).
// Double-buffered LDS, reg prefetch 2 chunks ahead, 1 barrier/chunk.
// ---------------------------------------------------------------------------
__global__ __launch_bounds__(256) void dft_mfma(const u16* __restrict__ f1, const u16* __restrict__ f2,
        const u16* __restrict__ htc1, const u16* __restrict__ htc2,
        u16* __restrict__ x1, u16* __restrict__ x2) {
    __shared__ __align__(16) u16 A1[2][1280], A2[2][1280];  // 32x40
    __shared__ __align__(16) u16 B1[2][2560], B2[2][2560];  // 64x40
    int bx = blockIdx.x;
    int b = bx >> 1, ch = bx & 1;
    int mct = blockIdx.y * 32;
    int tid = threadIdx.x, wid = tid >> 6, l = tid & 63;
    int wm0 = (wid >> 1) * 16, wn0 = (wid & 1) * 32;
    int arow = (l & 15), kgrp = (l >> 4) * 8;
    f32x4 acc0 = {0.f, 0.f, 0.f, 0.f}, acc1 = {0.f, 0.f, 0.f, 0.f};
    // per-thread fixed staging roles
    int pa_pl = tid >> 7, pa_row = (tid >> 2) & 31, pa_seg = tid & 3;
    const u16* asrc = (pa_pl ? f2 : f1) + (size_t)(mct + pa_row) * 512 + pa_seg * 8;
    int aoff = pa_row * 40 + pa_seg * 8;
    int b_row = (tid >> 2) & 63, b_seg = tid & 3;
    const u16* bsrc1 = htc1 + ((size_t)b * 128 + ch * 64 + b_row) * 512 + b_seg * 8;
    const u16* bsrc2 = htc2 + ((size_t)b * 128 + ch * 64 + b_row) * 512 + b_seg * 8;
    int boff = b_row * 40 + b_seg * 8;
    uint4 ra, rb0, rb1;
    // prologue: chunk 0 -> buf0; issue chunk 1
    ra  = *(const uint4*)(asrc);
    rb0 = *(const uint4*)(bsrc1);
    rb1 = *(const uint4*)(bsrc2);
    *(uint4*)((pa_pl ? A2[0] : A1[0]) + aoff) = ra;
    *(uint4*)(B1[0] + boff) = rb0;
    *(uint4*)(B2[0] + boff) = rb1;
    ra  = *(const uint4*)(asrc + 32);
    rb0 = *(const uint4*)(bsrc1 + 32);
    rb1 = *(const uint4*)(bsrc2 + 32);
    __syncthreads();
    for (int k = 0; k < 16; k++) {
        int cur = k & 1;
        bf16x8 a1 = *(const bf16x8*)&A1[cur][(wm0 + arow) * 40 + kgrp];
        bf16x8 a2 = *(const bf16x8*)&A2[cur][(wm0 + arow) * 40 + kgrp];
        bf16x8 b10 = *(const bf16x8*)&B1[cur][(wn0 + arow) * 40 + kgrp];
        bf16x8 b20 = *(const bf16x8*)&B2[cur][(wn0 + arow) * 40 + kgrp];
        bf16x8 b11 = *(const bf16x8*)&B1[cur][(wn0 + 16 + arow) * 40 + kgrp];
        bf16x8 b21 = *(const bf16x8*)&B2[cur][(wn0 + 16 + arow) * 40 + kgrp];
        acc0 = MFMA16(a1, b10, acc0);
        acc0 = MFMA16(a1, b20, acc0);
        acc0 = MFMA16(a2, b10, acc0);
        acc1 = MFMA16(a1, b11, acc1);
        acc1 = MFMA16(a1, b21, acc1);
        acc1 = MFMA16(a2, b11, acc1);
        if (k < 15) {
            *(uint4*)((pa_pl ? A2[cur ^ 1] : A1[cur ^ 1]) + aoff) = ra;
            *(uint4*)(B1[cur ^ 1] + boff) = rb0;
            *(uint4*)(B2[cur ^ 1] + boff) = rb1;
            if (k < 14) {
                int ko = (k + 2) * 32;
                ra  = *(const uint4*)(asrc + ko);
                rb0 = *(const uint4*)(bsrc1 + ko);
                rb1 = *(const uint4*)(bsrc2 + ko);
            }
        }
        __syncthreads();
    }
    int mcr = mct + wm0 + (l >> 4) * 4;
    int n0 = bx * 64 + wn0 + (l & 15);
#pragma unroll
    for (int j = 0; j < 4; j++) {
        size_t o0 = (size_t)(mcr + j) * 4096 + n0;
        x1[o0] = f2bf_hi(acc0[j]); x2[o0] = f2bf_lo(acc0[j]);
        size_t o1 = o0 + 16;
        x1[o1] = f2bf_hi(acc1[j]); x2[o1] = f2bf_lo(acc1[j]);
    }
}

// ---------------------------------------------------------------------------
// modemix (MFMA, pipelined): per mode m: Y[o][b] = W[m](o,i) *c X[b,i,m], K=128.
// grid (64 m, 4 oq), 256 thr = 4 waves (2 o x 2 b). Double-buffered.
// ---------------------------------------------------------------------------
__global__ __launch_bounds__(256) void modemix_mfma(const u16* __restrict__ x1, const u16* __restrict__ x2,
        const u16* __restrict__ wr1, const u16* __restrict__ wr2,
        const u16* __restrict__ wi1, const u16* __restrict__ wi2,
        u16* __restrict__ y1, u16* __restrict__ y2, int layer) {
    __shared__ __align__(16) u16 WR1[2][1280], WR2[2][1280], WI1[2][1280], WI2[2][1280];
    __shared__ __align__(16) u16 XR1[2][1280], XR2[2][1280], XI1[2][1280], XI2[2][1280];
    int m = blockIdx.x, oq = blockIdx.y;
    int tid = threadIdx.x, wid = tid >> 6, l = tid & 63;
    int wo0 = (wid >> 1) * 16, wb0 = (wid & 1) * 16;
    int arow = (l & 15), kgrp = (l >> 4) * 8;
    f32x4 ar = {0.f, 0.f, 0.f, 0.f}, ai = {0.f, 0.f, 0.f, 0.f};
    size_t wbase = (((size_t)layer * 64 + m) * 128 + oq * 32) * 128;
    // per-thread fixed roles: s0 = tid>>7 in {0,1}; handles W slabs s0,s0+2 and X slabs s0,s0+2
    int s0 = tid >> 7, srow = (tid >> 2) & 31, sseg = tid & 3;
    const u16* wsrc0 = (s0 ? wr2 : wr1) + wbase + (size_t)srow * 128 + sseg * 8;
    const u16* wsrc1 = (s0 ? wi2 : wi1) + wbase + (size_t)srow * 128 + sseg * 8;
    const u16* xb = s0 ? x2 : x1;
    const u16* xsrc0 = xb + (size_t)m * 4096 + srow * 128 + sseg * 8;
    const u16* xsrc1 = xb + (size_t)(64 + m) * 4096 + srow * 128 + sseg * 8;
    int soff = srow * 40 + sseg * 8;
    u16* wd0_0 = (s0 ? WR2[0] : WR1[0]) + soff;  u16* wd0_1 = (s0 ? WR2[1] : WR1[1]) + soff;
    u16* wd1_0 = (s0 ? WI2[0] : WI1[0]) + soff;  u16* wd1_1 = (s0 ? WI2[1] : WI1[1]) + soff;
    u16* xd0_0 = (s0 ? XR2[0] : XR1[0]) + soff;  u16* xd0_1 = (s0 ? XR2[1] : XR1[1]) + soff;
    u16* xd1_0 = (s0 ? XI2[0] : XI1[0]) + soff;  u16* xd1_1 = (s0 ? XI2[1] : XI1[1]) + soff;
    uint4 rw0, rw1, rx0, rx1;
    rw0 = *(const uint4*)(wsrc0); rw1 = *(const uint4*)(wsrc1);
    rx0 = *(const uint4*)(xsrc0); rx1 = *(const uint4*)(xsrc1);
    *(uint4*)wd0_0 = rw0; *(uint4*)wd1_0 = rw1;
    *(uint4*)xd0_0 = rx0; *(uint4*)xd1_0 = rx1;
    rw0 = *(const uint4*)(wsrc0 + 32); rw1 = *(const uint4*)(wsrc1 + 32);
    rx0 = *(const uint4*)(xsrc0 + 32); rx1 = *(const uint4*)(xsrc1 + 32);
    __syncthreads();
    for (int k = 0; k < 4; k++) {
        int cur = k & 1;
        int ao = (wo0 + arow) * 40 + kgrp;
        int bo = (wb0 + arow) * 40 + kgrp;
        bf16x8 Wr1 = *(const bf16x8*)&WR1[cur][ao], Wr2 = *(const bf16x8*)&WR2[cur][ao];
        bf16x8 Wi1 = *(const bf16x8*)&WI1[cur][ao], Wi2 = *(const bf16x8*)&WI2[cur][ao];
        bf16x8 Xr1 = *(const bf16x8*)&XR1[cur][bo], Xr2 = *(const bf16x8*)&XR2[cur][bo];
        bf16x8 Xi1 = *(const bf16x8*)&XI1[cur][bo], Xi2 = *(const bf16x8*)&XI2[cur][bo];
        bf16x8 nWi1 = negbf(Wi1), nWi2 = negbf(Wi2);
        ar = MFMA16(Wr1, Xr1, ar); ar = MFMA16(Wr1, Xr2, ar); ar = MFMA16(Wr2, Xr1, ar);
        ar = MFMA16(nWi1, Xi1, ar); ar = MFMA16(nWi1, Xi2, ar); ar = MFMA16(nWi2, Xi1, ar);
        ai = MFMA16(Wi1, Xr1, ai); ai = MFMA16(Wi1, Xr2, ai); ai = MFMA16(Wi2, Xr1, ai);
        ai = MFMA16(Wr1, Xi1, ai); ai = MFMA16(Wr1, Xi2, ai); ai = MFMA16(Wr2, Xi1, ai);
        if (k < 3) {
            if (cur) { *(uint4*)wd0_0 = rw0; *(uint4*)wd1_0 = rw1; *(uint4*)xd0_0 = rx0; *(uint4*)xd1_0 = rx1; }
            else     { *(uint4*)wd0_1 = rw0; *(uint4*)wd1_1 = rw1; *(uint4*)xd0_1 = rx0; *(uint4*)xd1_1 = rx1; }
            if (k < 2) {
                int ko = (k + 2) * 32;
                rw0 = *(const uint4*)(wsrc0 + ko); rw1 = *(const uint4*)(wsrc1 + ko);
                rx0 = *(const uint4*)(xsrc0 + ko); rx1 = *(const uint4*)(xsrc1 + ko);
            }
        }
        __syncthreads();
    }
    int ob = oq * 32 + wo0 + (l >> 4) * 4;
    int bb = wb0 + (l & 15);
#pragma unroll
    for (int j = 0; j < 4; j++) {
        size_t o = ((size_t)bb * 128 + ob + j) * 128;
        y1[o + m] = f2bf_hi(ar[j]); y2[o + m] = f2bf_lo(ar[j]);
        y1[o + 64 + m] = f2bf_hi(ai[j]); y2[o + 64 + m] = f2bf_lo(ai[j]);
    }
}

// ---------------------------------------------------------------------------
// idft+conv (MFMA, pipelined): C[o][r] = [Y|CW](o,k=256)*[GT;ht](k,r)+bias,GELU.
// grid (8 rt, 2 ot, 32 b). Double-buffered; T-transpose epilogue for htc.
// ---------------------------------------------------------------------------
__global__ __launch_bounds__(256) void idft_conv_mfma(const u16* __restrict__ y1, const u16* __restrict__ y2,
        const u16* __restrict__ gt1, const u16* __restrict__ gt2,
        const u16* __restrict__ hc1, const u16* __restrict__ hc2,
        const u16* __restrict__ cw1, const u16* __restrict__ cw2,
        const float* __restrict__ conv_b,
        u16* __restrict__ hn1, u16* __restrict__ hn2,
        u16* __restrict__ htc1, u16* __restrict__ htc2, int layer, int wtr) {
    __shared__ __align__(16) u16 A1[2][2560], A2[2][2560];
    __shared__ __align__(16) u16 B1[2][2560], B2[2][2560];
    __shared__ __align__(16) u16 T1[64 * 66], T2[64 * 66];
    int rt = blockIdx.x * 64, ot = blockIdx.y * 64, b = blockIdx.z;
    int tid = threadIdx.x, wid = tid >> 6, l = tid & 63;
    int wo0 = (wid >> 1) * 32, wr0 = (wid & 1) * 32;
    int arow = (l & 15), kgrp = (l >> 4) * 8;
    int srow = (tid >> 2) & 63, sseg = tid & 3;
    int soff = srow * 40 + sseg * 8;
    // fixed source bases (chunk-dependent choice made in loader)
    const u16* ya = y1 + ((size_t)b * 128 + ot + srow) * 128 + sseg * 8;
    const u16* yb = y2 + ((size_t)b * 128 + ot + srow) * 128 + sseg * 8;
    const u16* ca = cw1 + ((size_t)layer * 128 + ot + srow) * 128 + sseg * 8;
    const u16* cb = cw2 + ((size_t)layer * 128 + ot + srow) * 128 + sseg * 8;
    const u16* ga = gt1 + (size_t)(rt + srow) * 128 + sseg * 8;
    const u16* gb = gt2 + (size_t)(rt + srow) * 128 + sseg * 8;
    const u16* ha = hc1 + ((size_t)b * 512 + rt + srow) * 128 + sseg * 8;
    const u16* hb = hc2 + ((size_t)b * 512 + rt + srow) * 128 + sseg * 8;
    f32x4 acc[2][2] = {{{0.f,0.f,0.f,0.f},{0.f,0.f,0.f,0.f}},{{0.f,0.f,0.f,0.f},{0.f,0.f,0.f,0.f}}};
    uint4 ra0, ra1, rb0, rb1;
#define IDFT_LOAD(chk)                                                        \
    {   int k0_ = ((chk) & 3) * 32;                                           \
        if ((chk) < 4) {                                                      \
            ra0 = *(const uint4*)(ya + k0_); ra1 = *(const uint4*)(yb + k0_); \
            rb0 = *(const uint4*)(ga + k0_); rb1 = *(const uint4*)(gb + k0_); \
        } else {                                                              \
            ra0 = *(const uint4*)(ca + k0_); ra1 = *(const uint4*)(cb + k0_); \
            rb0 = *(const uint4*)(ha + k0_); rb1 = *(const uint4*)(hb + k0_); \
        } }
    IDFT_LOAD(0)
    *(uint4*)(A1[0] + soff) = ra0; *(uint4*)(A2[0] + soff) = ra1;
    *(uint4*)(B1[0] + soff) = rb0; *(uint4*)(B2[0] + soff) = rb1;
    IDFT_LOAD(1)
    __syncthreads();
    for (int k = 0; k < 8; k++) {
        int cur = k & 1;
        bf16x8 bfr[2][2];
#pragma unroll
        for (int rf = 0; rf < 2; rf++) {
            bfr[rf][0] = *(const bf16x8*)&B1[cur][(wr0 + rf * 16 + arow) * 40 + kgrp];
            bfr[rf][1] = *(const bf16x8*)&B2[cur][(wr0 + rf * 16 + arow) * 40 + kgrp];
        }
#pragma unroll
        for (int of = 0; of < 2; of++) {
            bf16x8 a1 = *(const bf16x8*)&A1[cur][(wo0 + of * 16 + arow) * 40 + kgrp];
            bf16x8 a2 = *(const bf16x8*)&A2[cur][(wo0 + of * 16 + arow) * 40 + kgrp];
#pragma unroll
            for (int rf = 0; rf < 2; rf++) {
                acc[of][rf] = MFMA16(a1, bfr[rf][0], acc[of][rf]);
                acc[of][rf] = MFMA16(a1, bfr[rf][1], acc[of][rf]);
                acc[of][rf] = MFMA16(a2, bfr[rf][0], acc[of][rf]);
            }
        }
        if (k < 7) {
            *(uint4*)(A1[cur ^ 1] + soff) = ra0; *(uint4*)(A2[cur ^ 1] + soff) = ra1;
            *(uint4*)(B1[cur ^ 1] + soff) = rb0; *(uint4*)(B2[cur ^ 1] + soff) = rb1;
            if (k < 6) IDFT_LOAD(k + 2)
        }
        __syncthreads();
    }
#undef IDFT_LOAD
#pragma unroll
    for (int of = 0; of < 2; of++) {
        int obl = wo0 + of * 16 + (l >> 4) * 4;
        int ob = ot + obl;
#pragma unroll
        for (int rf = 0; rf < 2; rf++) {
            int rloc = wr0 + rf * 16 + (l & 15);
            int r = rt + rloc;
            float v0 = gelu_exact(acc[of][rf][0] + conv_b[layer * 128 + ob + 0]);
            float v1 = gelu_exact(acc[of][rf][1] + conv_b[layer * 128 + ob + 1]);
            float v2 = gelu_exact(acc[of][rf][2] + conv_b[layer * 128 + ob + 2]);
            float v3 = gelu_exact(acc[of][rf][3] + conv_b[layer * 128 + ob + 3]);
            ushort4 hv, lv;
            hv.x = f2bf_hi(v0); hv.y = f2bf_hi(v1); hv.z = f2bf_hi(v2); hv.w = f2bf_hi(v3);
            lv.x = f2bf_lo(v0); lv.y = f2bf_lo(v1); lv.z = f2bf_lo(v2); lv.w = f2bf_lo(v3);
            size_t off = ((size_t)b * 512 + r) * 128 + ob;
            *(ushort4*)&hn1[off] = hv;
            *(ushort4*)&hn2[off] = lv;
            if (wtr) {
                T1[(obl + 0) * 66 + rloc] = hv.x; T1[(obl + 1) * 66 + rloc] = hv.y;
                T1[(obl + 2) * 66 + rloc] = hv.z; T1[(obl + 3) * 66 + rloc] = hv.w;
                T2[(obl + 0) * 66 + rloc] = lv.x; T2[(obl + 1) * 66 + rloc] = lv.y;
                T2[(obl + 2) * 66 + rloc] = lv.z; T2[(obl + 3) * 66 + rloc] = lv.w;
            }
        }
    }
    if (wtr) {
        __syncthreads();
#pragma unroll
        for (int q = 0; q < 8; q++) {
            int t = tid + q * 256;
            int o = t >> 5, ru = t & 31;
            u32 vh = *(const u32*)&T1[o * 66 + ru * 2];
            u32 vl = *(const u32*)&T2[o * 66 + ru * 2];
            size_t off = ((size_t)b * 128 + ot + o) * 512 + rt + ru * 2;
            *(u32*)&htc1[off] = vh;
            *(u32*)&htc2[off] = vl;
        }
    }
}

// ---------------------------------------------------------------------------
// head (MFMA, reg-prefetch single-buffer): fc1 GEMM + gelu + fc2 reduce + z.
// grid 256 blocks (64 rows each), 4 waves x 16 rows.
// ---------------------------------------------------------------------------
__global__ __launch_bounds__(256) void head_mfma(const u16* __restrict__ ht1, const u16* __restrict__ ht2,
        const u16* __restrict__ f11, const u16* __restrict__ f12,
        const float* __restrict__ fc1_b, const float* __restrict__ fc2_w,
        const float* __restrict__ fc2_b,
        float* __restrict__ seq, float* __restrict__ preds, int step) {
    __shared__ __align__(16) u16 HA1[256 * 40], HA2[256 * 40];
    __shared__ __align__(16) u16 HB1[64 * 40], HB2[64 * 40];
    __shared__ float fc2s[256], fc1bs[256];
    int blk = blockIdx.x;
    int b = blk >> 3, r0 = (blk & 7) * 64;
    int tid = threadIdx.x, wid = tid >> 6, l = tid & 63;
    fc2s[tid] = fc2_w[tid];
    fc1bs[tid] = fc1_b[tid];
    int arow = l & 15, kgrp = (l >> 4) * 8;
    int jrow = tid >> 2, seg = tid & 3;        // jrow in [0,64)
    const u16* a1src = f11 + (size_t)jrow * 128 + seg * 8;
    const u16* a2src = f12 + (size_t)jrow * 128 + seg * 8;
    const u16* b1src = ht1 + ((size_t)b * 512 + r0 + jrow) * 128 + seg * 8;
    const u16* b2src = ht2 + ((size_t)b * 512 + r0 + jrow) * 128 + seg * 8;
    int aoff = jrow * 40 + seg * 8;
    f32x4 acc[16];
#pragma unroll
    for (int jf = 0; jf < 16; jf++) acc[jf] = (f32x4){0.f, 0.f, 0.f, 0.f};
    uint4 ra[8], rb[2];
#define HEAD_LOAD(k0_)                                                         \
    {   _Pragma("unroll")                                                      \
        for (int q = 0; q < 4; q++) {                                          \
            ra[q]     = *(const uint4*)(a1src + (size_t)q * 64 * 128 + (k0_)); \
            ra[q + 4] = *(const uint4*)(a2src + (size_t)q * 64 * 128 + (k0_)); \
        }                                                                      \
        rb[0] = *(const uint4*)(b1src + (k0_));                                \
        rb[1] = *(const uint4*)(b2src + (k0_)); }
#define HEAD_WRITE()                                                           \
    {   _Pragma("unroll")                                                      \
        for (int q = 0; q < 4; q++) {                                          \
            *(uint4*)(HA1 + aoff + q * 64 * 40) = ra[q];                       \
            *(uint4*)(HA2 + aoff + q * 64 * 40) = ra[q + 4];                   \
        }                                                                      \
        *(uint4*)(HB1 + aoff) = rb[0];                                         \
        *(uint4*)(HB2 + aoff) = rb[1]; }
    HEAD_LOAD(0)
    HEAD_WRITE()
    HEAD_LOAD(32)
    __syncthreads();
    for (int k = 0; k < 4; k++) {
        int bo = (wid * 16 + arow) * 40 + kgrp;
        bf16x8 b1 = *(const bf16x8*)&HB1[bo];
        bf16x8 b2 = *(const bf16x8*)&HB2[bo];
#pragma unroll 4
        for (int jf = 0; jf < 16; jf++) {
            int ao = (jf * 16 + arow) * 40 + kgrp;
            bf16x8 a1 = *(const bf16x8*)&HA1[ao];
            bf16x8 a2 = *(const bf16x8*)&HA2[ao];
            acc[jf] = MFMA16(a1, b1, acc[jf]);
            acc[jf] = MFMA16(a1, b2, acc[jf]);
            acc[jf] = MFMA16(a2, b1, acc[jf]);
        }
        __syncthreads();
        if (k < 3) {
            HEAD_WRITE()
            if (k < 2) HEAD_LOAD((k + 2) * 32)
            __syncthreads();
        }
    }
#undef HEAD_LOAD
#undef HEAD_WRITE
    float dx = 0.0f;
#pragma unroll 4
    for (int jf = 0; jf < 16; jf++) {
        int jbase = jf * 16 + (l >> 4) * 4;
#pragma unroll
        for (int jj = 0; jj < 4; jj++) {
            int j = jbase + jj;
            dx += gelu_exact(acc[jf][jj] + fc1bs[j]) * fc2s[j];
        }
    }
    dx += __shfl_xor(dx, 16);
    dx += __shfl_xor(dx, 32);
    if ((l >> 4) == 0) {
        int r = r0 + wid * 16 + arow;
        float zn = seq[((size_t)b * SEQROWS + step + 23) * NR + r] + dx + fc2_b[0];
        seq[((size_t)b * SEQROWS + step + 24) * NR + r] = zn;
        preds[((size_t)b * NSTEPS + step) * NR + r] = zn;
    }
}

// ---------------------------------------------------------------------------
extern "C" void kernel_launch(void* const* d_in, const int* in_sizes, int n_in,
                              void* d_out, int out_size, void* d_ws, size_t ws_size,
                              hipStream_t stream) {
    (void)in_sizes; (void)n_in; (void)out_size; (void)ws_size;
    const float* z       = (const float*)d_in[0];
    const float* t_grid  = (const float*)d_in[1];
    const float* fc0_w   = (const float*)d_in[2];
    const float* fc0_b   = (const float*)d_in[3];
    const float* spec_wr = (const float*)d_in[4];
    const float* spec_wi = (const float*)d_in[5];
    const float* conv_w  = (const float*)d_in[6];
    const float* conv_b  = (const float*)d_in[7];
    const float* fc1_b   = (const float*)d_in[9];
    const float* fc1_w   = (const float*)d_in[8];
    const float* fc2_w   = (const float*)d_in[10];
    const float* fc2_b   = (const float*)d_in[11];
    float* preds = (float*)d_out;

    char* p = (char*)d_ws;
    float* seq = (float*)p;  p += (size_t)NB * SEQROWS * NR * 4;
    u16* ht1 = (u16*)p;  p += (size_t)2 * NB * NR * NW * 2;   // [2 buf][b][r][c] hi
    u16* ht2 = (u16*)p;  p += (size_t)2 * NB * NR * NW * 2;   // lo
    u16* htc1 = (u16*)p; p += (size_t)NB * NW * NR * 2;       // [b][c][r] hi
    u16* htc2 = (u16*)p; p += (size_t)NB * NW * NR * 2;       // lo
    u16* x1  = (u16*)p;  p += (size_t)128 * 4096 * 2;
    u16* x2  = (u16*)p;  p += (size_t)128 * 4096 * 2;
    u16* y1  = (u16*)p;  p += (size_t)NB * NW * 128 * 2;
    u16* y2  = (u16*)p;  p += (size_t)NB * NW * 128 * 2;
    u16* f1  = (u16*)p;  p += (size_t)128 * 512 * 2;
    u16* f2  = (u16*)p;  p += (size_t)128 * 512 * 2;
    u16* gt1 = (u16*)p;  p += (size_t)512 * 128 * 2;
    u16* gt2 = (u16*)p;  p += (size_t)512 * 128 * 2;
    u16* wr1 = (u16*)p;  p += (size_t)NLAY * NM * NW * NW * 2;
    u16* wr2 = (u16*)p;  p += (size_t)NLAY * NM * NW * NW * 2;
    u16* wi1 = (u16*)p;  p += (size_t)NLAY * NM * NW * NW * 2;
    u16* wi2 = (u16*)p;  p += (size_t)NLAY * NM * NW * NW * 2;
    u16* cw1 = (u16*)p;  p += (size_t)NLAY * NW * NW * 2;
    u16* cw2 = (u16*)p;  p += (size_t)NLAY * NW * NW * 2;
    u16* f11 = (u16*)p;  p += (size_t)256 * 128 * 2;
    u16* f12 = (u16*)p;  p += (size_t)256 * 128 * 2;

    const size_t htplane = (size_t)NB * NR * NW;

    build_tables_planes<<<256, 256, 0, stream>>>(f1, f2, gt1, gt2);
    prep_specw<<<512, 256, 0, stream>>>(spec_wr, spec_wi, wr1, wr2, wi1, wi2);
    prep_cw<<<256, 256, 0, stream>>>(conv_w, cw1, cw2);
    prep_fc1t<<<128, 256, 0, stream>>>(fc1_w, f11, f12);
    init_seq_kernel<<<(NB * NTH * NR) / 256, 256, 0, stream>>>(z, seq);

    for (int step = 0; step < NSTEPS; step++) {
        fc0_kernel<<<dim3(8, 32), 256, 0, stream>>>(seq, t_grid, fc0_w, fc0_b,
                                                    ht1, ht2, htc1, htc2, step);
        int cur = 0;
        for (int l = 0; l < NLAY; l++) {
            const u16* hc1 = ht1 + (size_t)cur * htplane;
            const u16* hc2 = ht2 + (size_t)cur * htplane;
            u16* hn1 = ht1 + (size_t)(cur ^ 1) * htplane;
            u16* hn2 = ht2 + (size_t)(cur ^ 1) * htplane;
            dft_mfma<<<dim3(64, 4), 256, 0, stream>>>(f1, f2, htc1, htc2, x1, x2);
            modemix_mfma<<<dim3(64, 4), 256, 0, stream>>>(x1, x2, wr1, wr2, wi1, wi2,
                                                          y1, y2, l);
            idft_conv_mfma<<<dim3(8, 2, 32), 256, 0, stream>>>(y1, y2, gt1, gt2,
                                                               hc1, hc2, cw1, cw2,
                                                               conv_b, hn1, hn2,
                                                               htc1, htc2, l, (l < 3) ? 1 : 0);
            cur ^= 1;
        }
        head_mfma<<<256, 256, 0, stream>>>(ht1, ht2, f11, f12, fc1_b, fc2_w, fc2_b,
                                           seq, preds, step);
    }
}

// Round 7
// 1978.055 us; speedup vs baseline: 51.2479x; 1.0646x over previous
//
#include <hip/hip_runtime.h>
#include <math.h>

// LatentFNO: B=32, T=24, R=512, W=128, M=64 modes, 4 layers, 12 steps.
// Round 6: (a) head reverted to round-4 staging (round-5 reg-array prefetch
// spilled: 110 MB/dispatch scratch writes); (b) fc0 fused into head epilogue
// (steps 1..11) via LDS aliasing; (c) depth-3 prefetch (named even/odd reg
// sets) in dft/modemix/idft. Math: exact 3-term bf16 split (A1B1+A1B2+A2B1).

#define NB 32
#define NR 512
#define NW 128
#define NM 64
#define NTH 24
#define NLAY 4
#define NSTEPS 12
#define SEQROWS 36

typedef unsigned short u16;
typedef unsigned int u32;
typedef __attribute__((ext_vector_type(8))) short bf16x8;
typedef __attribute__((ext_vector_type(4))) float f32x4;
#define MFMA16(a, b, c) __builtin_amdgcn_mfma_f32_16x16x32_bf16((a), (b), (c), 0, 0, 0)

__device__ __forceinline__ float gelu_exact(float x) {
    return 0.5f * x * (1.0f + erff(x * 0.70710678118654752f));
}
__device__ __forceinline__ float bf2f(u16 u) {
    union { u32 i; float f; } v; v.i = ((u32)u) << 16; return v.f;
}
__device__ __forceinline__ u16 f2bf_hi(float x) {
    union { float f; u32 i; } v; v.f = x; return (u16)(v.i >> 16);
}
__device__ __forceinline__ u16 f2bf_lo(float x) {
    float h = bf2f(f2bf_hi(x));
    return f2bf_hi(x - h);
}
__device__ __forceinline__ bf16x8 negbf(bf16x8 a) {
#pragma unroll
    for (int i = 0; i < 8; i++) a[i] ^= (short)0x8000;
    return a;
}

// ---------------------------------------------------------------------------
// Tables: F planes [mc=128][r=512]; GT planes [r=512][mc=128].
// ---------------------------------------------------------------------------
__global__ void build_tables_planes(u16* __restrict__ f1, u16* __restrict__ f2,
                                    u16* __restrict__ gt1, u16* __restrict__ gt2) {
    int idx = blockIdx.x * 256 + threadIdx.x;   // 65536: mc*512 + r
    int mc = idx >> 9, r = idx & 511, m = mc & 63;
    int p = (m * r) & 511;
    float a = (float)p * (1.0f / 256.0f);
    float c = cospif(a), s = sinpif(a);
    float Fv = (mc < 64) ? c : -s;
    float cm = (m == 0) ? (1.0f / 512.0f) : (2.0f / 512.0f);
    float Gv = (mc < 64) ? cm * c : ((m == 0) ? 0.0f : -cm * s);
    f1[idx] = f2bf_hi(Fv); f2[idx] = f2bf_lo(Fv);
    size_t g = (size_t)r * 128 + mc;
    gt1[g] = f2bf_hi(Gv); gt2[g] = f2bf_lo(Gv);
}

// spec_w (l,i,o,m) -> planes [l][m][o][i] hi/lo, coalesced both directions.
__global__ __launch_bounds__(256) void prep_specw(const float* __restrict__ wr, const float* __restrict__ wi,
                           u16* __restrict__ wr1, u16* __restrict__ wr2,
                           u16* __restrict__ wi1, u16* __restrict__ wi2) {
    __shared__ float tile[128][65];
    int l = blockIdx.x >> 7, o = blockIdx.x & 127;
    int tid = threadIdx.x;
    size_t sbase = (size_t)l * 1048576 + (size_t)o * 64;
    size_t dbase = (size_t)l * 64 * 16384 + (size_t)o * 128;
    for (int pass = 0; pass < 2; pass++) {
        const float* src = pass ? wi : wr;
        u16* d1 = pass ? wi1 : wr1;
        u16* d2 = pass ? wi2 : wr2;
        if (pass) __syncthreads();
        for (int e = tid; e < 8192; e += 256) {
            int i = e >> 6, m = e & 63;
            tile[i][m] = src[sbase + (size_t)i * 8192 + m];
        }
        __syncthreads();
        for (int e = tid; e < 4096; e += 256) {
            int m = e >> 6, i2 = (e & 63) * 2;
            float v0 = tile[i2][m], v1 = tile[i2 + 1][m];
            u32 hh = (u32)f2bf_hi(v0) | ((u32)f2bf_hi(v1) << 16);
            u32 ll = (u32)f2bf_lo(v0) | ((u32)f2bf_lo(v1) << 16);
            size_t d = dbase + (size_t)m * 16384 + i2;
            *(u32*)&d1[d] = hh;
            *(u32*)&d2[d] = ll;
        }
    }
}

__global__ void prep_cw(const float* __restrict__ cw, u16* __restrict__ c1, u16* __restrict__ c2) {
    int idx = blockIdx.x * 256 + threadIdx.x;   // 65536
    float v = cw[idx];
    c1[idx] = f2bf_hi(v); c2[idx] = f2bf_lo(v);
}

// fc1_w [c=128][j=256] -> fc1t planes [j][c] hi/lo
__global__ void prep_fc1t(const float* __restrict__ fc1_w,
                          u16* __restrict__ f11, u16* __restrict__ f12) {
    int idx = blockIdx.x * 256 + threadIdx.x;   // 32768: j*128 + c
    int j = idx >> 7, c = idx & 127;
    float v = fc1_w[(size_t)c * 256 + j];
    f11[idx] = f2bf_hi(v); f12[idx] = f2bf_lo(v);
}

__global__ void init_seq_kernel(const float* __restrict__ z, float* __restrict__ seq) {
    int idx = blockIdx.x * 256 + threadIdx.x;    // < 32*24*512
    int b = idx / (NTH * NR);
    int rem = idx - b * (NTH * NR);
    seq[(size_t)b * SEQROWS * NR + rem] = z[idx];
}

// ---------------------------------------------------------------------------
// fc0 (fp32), step 0 only: writes ht[b][r][c] AND htc[b][c][r] planes.
// ---------------------------------------------------------------------------
__global__ __launch_bounds__(256) void fc0_kernel(const float* __restrict__ seq,
        const float* __restrict__ t_grid, const float* __restrict__ fc0_w,
        const float* __restrict__ fc0_b, u16* __restrict__ ht1, u16* __restrict__ ht2,
        u16* __restrict__ htc1, u16* __restrict__ htc2, int step) {
    __shared__ float wlds[28 * 128];
    __shared__ float blds[128];
    int b = blockIdx.y, rblk = blockIdx.x;
    int tid = threadIdx.x;
    for (int t = tid; t < 28 * 128; t += 256) wlds[t] = fc0_w[t];
    if (tid < 128) blds[tid] = fc0_b[tid];
    __syncthreads();
    int lane = tid & 63, wq = tid >> 6;
    int r = rblk * 64 + lane;
    float sv[24];
    const float* sp = seq + ((size_t)b * SEQROWS + step) * NR + r;
#pragma unroll
    for (int t = 0; t < 24; t++) sv[t] = sp[(size_t)t * NR];
    float tt = t_grid[b * 24 + 23] + (float)(step + 1);
    float ang24 = 6.28318530717958647692f * tt * (1.0f / 24.0f);
    float ang168 = 6.28318530717958647692f * tt * (1.0f / 168.0f);
    float s24 = sinf(ang24), c24 = cosf(ang24), s168 = sinf(ang168);
    float xc = (float)r * (1.0f / 511.0f);
    size_t rowoff = ((size_t)b * NR + r) * NW;
#pragma unroll 2
    for (int w0 = 0; w0 < 32; w0 += 2) {
        float acc2[2];
#pragma unroll
        for (int q = 0; q < 2; q++) {
            int w = wq * 32 + w0 + q;
            float acc = blds[w];
#pragma unroll
            for (int t = 0; t < 24; t++) acc += sv[t] * wlds[t * 128 + w];
            acc += s24 * wlds[24 * 128 + w] + c24 * wlds[25 * 128 + w]
                 + s168 * wlds[26 * 128 + w] + xc * wlds[27 * 128 + w];
            acc2[q] = acc;
        }
        u16 h0 = f2bf_hi(acc2[0]), h1 = f2bf_hi(acc2[1]);
        u16 l0 = f2bf_lo(acc2[0]), l1 = f2bf_lo(acc2[1]);
        size_t off = rowoff + wq * 32 + w0;
        *(u32*)&ht1[off] = (u32)h0 | ((u32)h1 << 16);
        *(u32*)&ht2[off] = (u32)l0 | ((u32)l1 << 16);
        int w = wq * 32 + w0;
        size_t coff = ((size_t)b * 128 + w) * 512 + r;
        htc1[coff] = h0; htc1[coff + 512] = h1;
        htc2[coff] = l0; htc2[coff + 512] = l1;
    }
}

// ---------------------------------------------------------------------------
// dft (MFMA, depth-3 pipelined): X[128][4096] = F * htc^T, K=512.
// grid (64, 4), 256 thr = 4 waves (2 mc x 2 n).
// ---------------------------------------------------------------------------
__global__ __launch_bounds__(256) void dft_mfma(const u16* __restrict__ f1, const u16* __restrict__ f2,
        const u16* __restrict__ htc1, const u16* __restrict__ htc2,
        u16* __restrict__ x1, u16* __restrict__ x2) {
    __shared__ __align__(16) u16 A1[2][1280], A2[2][1280];
    __shared__ __align__(16) u16 B1[2][2560], B2[2][2560];
    int bx = blockIdx.x;
    int b = bx >> 1, ch = bx & 1;
    int mct = blockIdx.y * 32;
    int tid = threadIdx.x, wid = tid >> 6, l = tid & 63;
    int wm0 = (wid >> 1) * 16, wn0 = (wid & 1) * 32;
    int arow = (l & 15), kgrp = (l >> 4) * 8;
    f32x4 acc0 = {0.f, 0.f, 0.f, 0.f}, acc1 = {0.f, 0.f, 0.f, 0.f};
    int pa_pl = tid >> 7, pa_row = (tid >> 2) & 31, pa_seg = tid & 3;
    const u16* asrc = (pa_pl ? f2 : f1) + (size_t)(mct + pa_row) * 512 + pa_seg * 8;
    int aoff = pa_row * 40 + pa_seg * 8;
    int b_row = (tid >> 2) & 63, b_seg = tid & 3;
    const u16* bsrc1 = htc1 + ((size_t)b * 128 + ch * 64 + b_row) * 512 + b_seg * 8;
    const u16* bsrc2 = htc2 + ((size_t)b * 128 + ch * 64 + b_row) * 512 + b_seg * 8;
    int boff = b_row * 40 + b_seg * 8;
    uint4 raO, rbO0, rbO1, raE, rbE0, rbE1;
    // chunk 0 -> buf0
    raO = *(const uint4*)(asrc); rbO0 = *(const uint4*)(bsrc1); rbO1 = *(const uint4*)(bsrc2);
    *(uint4*)((pa_pl ? A2[0] : A1[0]) + aoff) = raO;
    *(uint4*)(B1[0] + boff) = rbO0;
    *(uint4*)(B2[0] + boff) = rbO1;
    // chunk 1 -> O, chunk 2 -> E
    raO = *(const uint4*)(asrc + 32); rbO0 = *(const uint4*)(bsrc1 + 32); rbO1 = *(const uint4*)(bsrc2 + 32);
    raE = *(const uint4*)(asrc + 64); rbE0 = *(const uint4*)(bsrc1 + 64); rbE1 = *(const uint4*)(bsrc2 + 64);
    __syncthreads();
#define DFT_COMPUTE(BUF)                                                       \
    {   bf16x8 a1 = *(const bf16x8*)&A1[BUF][(wm0 + arow) * 40 + kgrp];        \
        bf16x8 a2 = *(const bf16x8*)&A2[BUF][(wm0 + arow) * 40 + kgrp];        \
        bf16x8 b10 = *(const bf16x8*)&B1[BUF][(wn0 + arow) * 40 + kgrp];       \
        bf16x8 b20 = *(const bf16x8*)&B2[BUF][(wn0 + arow) * 40 + kgrp];       \
        bf16x8 b11 = *(const bf16x8*)&B1[BUF][(wn0 + 16 + arow) * 40 + kgrp];  \
        bf16x8 b21 = *(const bf16x8*)&B2[BUF][(wn0 + 16 + arow) * 40 + kgrp];  \
        acc0 = MFMA16(a1, b10, acc0);                                          \
        acc0 = MFMA16(a1, b20, acc0);                                          \
        acc0 = MFMA16(a2, b10, acc0);                                          \
        acc1 = MFMA16(a1, b11, acc1);                                          \
        acc1 = MFMA16(a1, b21, acc1);                                          \
        acc1 = MFMA16(a2, b11, acc1); }
    for (int k = 0; k < 16; k += 2) {
        // even: chunk k in buf0; O holds k+1
        DFT_COMPUTE(0)
        *(uint4*)((pa_pl ? A2[1] : A1[1]) + aoff) = raO;
        *(uint4*)(B1[1] + boff) = rbO0;
        *(uint4*)(B2[1] + boff) = rbO1;
        if (k < 13) {
            int ko = (k + 3) * 32;
            raO = *(const uint4*)(asrc + ko); rbO0 = *(const uint4*)(bsrc1 + ko); rbO1 = *(const uint4*)(bsrc2 + ko);
        }
        __syncthreads();
        // odd: chunk k+1 in buf1; E holds k+2
        DFT_COMPUTE(1)
        if (k < 14) {
            *(uint4*)((pa_pl ? A2[0] : A1[0]) + aoff) = raE;
            *(uint4*)(B1[0] + boff) = rbE0;
            *(uint4*)(B2[0] + boff) = rbE1;
            if (k < 12) {
                int ko = (k + 4) * 32;
                raE = *(const uint4*)(asrc + ko); rbE0 = *(const uint4*)(bsrc1 + ko); rbE1 = *(const uint4*)(bsrc2 + ko);
            }
        }
        __syncthreads();
    }
#undef DFT_COMPUTE
    int mcr = mct + wm0 + (l >> 4) * 4;
    int n0 = bx * 64 + wn0 + (l & 15);
#pragma unroll
    for (int j = 0; j < 4; j++) {
        size_t o0 = (size_t)(mcr + j) * 4096 + n0;
        x1[o0] = f2bf_hi(acc0[j]); x2[o0] = f2bf_lo(acc0[j]);
        size_t o1 = o0 + 16;
        x1[o1] = f2bf_hi(acc1[j]); x2[o1] = f2bf_lo(acc1[j]);
    }
}

// ---------------------------------------------------------------------------
// modemix (MFMA, depth-3): per mode m: Y = W *c X, K=128. grid (64, 4).
// ---------------------------------------------------------------------------
__global__ __launch_bounds__(256) void modemix_mfma(const u16* __restrict__ x1, const u16* __restrict__ x2,
        const u16* __restrict__ wr1, const u16* __restrict__ wr2,
        const u16* __restrict__ wi1, const u16* __restrict__ wi2,
        u16* __restrict__ y1, u16* __restrict__ y2, int layer) {
    __shared__ __align__(16) u16 WR1[2][1280], WR2[2][1280], WI1[2][1280], WI2[2][1280];
    __shared__ __align__(16) u16 XR1[2][1280], XR2[2][1280], XI1[2][1280], XI2[2][1280];
    int m = blockIdx.x, oq = blockIdx.y;
    int tid = threadIdx.x, wid = tid >> 6, l = tid & 63;
    int wo0 = (wid >> 1) * 16, wb0 = (wid & 1) * 16;
    int arow = (l & 15), kgrp = (l >> 4) * 8;
    f32x4 ar = {0.f, 0.f, 0.f, 0.f}, ai = {0.f, 0.f, 0.f, 0.f};
    size_t wbase = (((size_t)layer * 64 + m) * 128 + oq * 32) * 128;
    int s0 = tid >> 7, srow = (tid >> 2) & 31, sseg = tid & 3;
    const u16* wsrc0 = (s0 ? wr2 : wr1) + wbase + (size_t)srow * 128 + sseg * 8;
    const u16* wsrc1 = (s0 ? wi2 : wi1) + wbase + (size_t)srow * 128 + sseg * 8;
    const u16* xb = s0 ? x2 : x1;
    const u16* xsrc0 = xb + (size_t)m * 4096 + srow * 128 + sseg * 8;
    const u16* xsrc1 = xb + (size_t)(64 + m) * 4096 + srow * 128 + sseg * 8;
    int soff = srow * 40 + sseg * 8;
    u16* wd0_0 = (s0 ? WR2[0] : WR1[0]) + soff;  u16* wd0_1 = (s0 ? WR2[1] : WR1[1]) + soff;
    u16* wd1_0 = (s0 ? WI2[0] : WI1[0]) + soff;  u16* wd1_1 = (s0 ? WI2[1] : WI1[1]) + soff;
    u16* xd0_0 = (s0 ? XR2[0] : XR1[0]) + soff;  u16* xd0_1 = (s0 ? XR2[1] : XR1[1]) + soff;
    u16* xd1_0 = (s0 ? XI2[0] : XI1[0]) + soff;  u16* xd1_1 = (s0 ? XI2[1] : XI1[1]) + soff;
    uint4 rwO0, rwO1, rxO0, rxO1, rwE0, rwE1, rxE0, rxE1;
    rwO0 = *(const uint4*)(wsrc0); rwO1 = *(const uint4*)(wsrc1);
    rxO0 = *(const uint4*)(xsrc0); rxO1 = *(const uint4*)(xsrc1);
    *(uint4*)wd0_0 = rwO0; *(uint4*)wd1_0 = rwO1;
    *(uint4*)xd0_0 = rxO0; *(uint4*)xd1_0 = rxO1;
    rwO0 = *(const uint4*)(wsrc0 + 32); rwO1 = *(const uint4*)(wsrc1 + 32);
    rxO0 = *(const uint4*)(xsrc0 + 32); rxO1 = *(const uint4*)(xsrc1 + 32);
    rwE0 = *(const uint4*)(wsrc0 + 64); rwE1 = *(const uint4*)(wsrc1 + 64);
    rxE0 = *(const uint4*)(xsrc0 + 64); rxE1 = *(const uint4*)(xsrc1 + 64);
    __syncthreads();
#define MM_COMPUTE(BUF)                                                        \
    {   int ao = (wo0 + arow) * 40 + kgrp;                                     \
        int bo = (wb0 + arow) * 40 + kgrp;                                     \
        bf16x8 Wr1 = *(const bf16x8*)&WR1[BUF][ao], Wr2 = *(const bf16x8*)&WR2[BUF][ao]; \
        bf16x8 Wi1 = *(const bf16x8*)&WI1[BUF][ao], Wi2 = *(const bf16x8*)&WI2[BUF][ao]; \
        bf16x8 Xr1 = *(const bf16x8*)&XR1[BUF][bo], Xr2 = *(const bf16x8*)&XR2[BUF][bo]; \
        bf16x8 Xi1 = *(const bf16x8*)&XI1[BUF][bo], Xi2 = *(const bf16x8*)&XI2[BUF][bo]; \
        bf16x8 nWi1 = negbf(Wi1), nWi2 = negbf(Wi2);                           \
        ar = MFMA16(Wr1, Xr1, ar); ar = MFMA16(Wr1, Xr2, ar); ar = MFMA16(Wr2, Xr1, ar); \
        ar = MFMA16(nWi1, Xi1, ar); ar = MFMA16(nWi1, Xi2, ar); ar = MFMA16(nWi2, Xi1, ar); \
        ai = MFMA16(Wi1, Xr1, ai); ai = MFMA16(Wi1, Xr2, ai); ai = MFMA16(Wi2, Xr1, ai); \
        ai = MFMA16(Wr1, Xi1, ai); ai = MFMA16(Wr1, Xi2, ai); ai = MFMA16(Wr2, Xi1, ai); }
    for (int k = 0; k < 4; k += 2) {
        MM_COMPUTE(0)
        *(uint4*)wd0_1 = rwO0; *(uint4*)wd1_1 = rwO1;
        *(uint4*)xd0_1 = rxO0; *(uint4*)xd1_1 = rxO1;
        if (k == 0) {
            rwO0 = *(const uint4*)(wsrc0 + 96); rwO1 = *(const uint4*)(wsrc1 + 96);
            rxO0 = *(const uint4*)(xsrc0 + 96); rxO1 = *(const uint4*)(xsrc1 + 96);
        }
        __syncthreads();
        MM_COMPUTE(1)
        if (k == 0) {
            *(uint4*)wd0_0 = rwE0; *(uint4*)wd1_0 = rwE1;
            *(uint4*)xd0_0 = rxE0; *(uint4*)xd1_0 = rxE1;
        }
        __syncthreads();
    }
#undef MM_COMPUTE
    int ob = oq * 32 + wo0 + (l >> 4) * 4;
    int bb = wb0 + (l & 15);
#pragma unroll
    for (int j = 0; j < 4; j++) {
        size_t o = ((size_t)bb * 128 + ob + j) * 128;
        y1[o + m] = f2bf_hi(ar[j]); y2[o + m] = f2bf_lo(ar[j]);
        y1[o + 64 + m] = f2bf_hi(ai[j]); y2[o + 64 + m] = f2bf_lo(ai[j]);
    }
}

// ---------------------------------------------------------------------------
// idft+conv (MFMA, depth-3): C[o][r] = [Y|CW](o,256)*[GT;ht](256,r)+bias,GELU.
// grid (8 rt, 2 ot, 32 b). T-transpose epilogue writes htc when wtr.
// ---------------------------------------------------------------------------
__global__ __launch_bounds__(256) void idft_conv_mfma(const u16* __restrict__ y1, const u16* __restrict__ y2,
        const u16* __restrict__ gt1, const u16* __restrict__ gt2,
        const u16* __restrict__ hc1, const u16* __restrict__ hc2,
        const u16* __restrict__ cw1, const u16* __restrict__ cw2,
        const float* __restrict__ conv_b,
        u16* __restrict__ hn1, u16* __restrict__ hn2,
        u16* __restrict__ htc1, u16* __restrict__ htc2, int layer, int wtr) {
    __shared__ __align__(16) u16 A1[2][2560], A2[2][2560];
    __shared__ __align__(16) u16 B1[2][2560], B2[2][2560];
    __shared__ __align__(16) u16 T1[64 * 66], T2[64 * 66];
    int rt = blockIdx.x * 64, ot = blockIdx.y * 64, b = blockIdx.z;
    int tid = threadIdx.x, wid = tid >> 6, l = tid & 63;
    int wo0 = (wid >> 1) * 32, wr0 = (wid & 1) * 32;
    int arow = (l & 15), kgrp = (l >> 4) * 8;
    int srow = (tid >> 2) & 63, sseg = tid & 3;
    int soff = srow * 40 + sseg * 8;
    const u16* ya = y1 + ((size_t)b * 128 + ot + srow) * 128 + sseg * 8;
    const u16* yb = y2 + ((size_t)b * 128 + ot + srow) * 128 + sseg * 8;
    const u16* ca = cw1 + ((size_t)layer * 128 + ot + srow) * 128 + sseg * 8;
    const u16* cb = cw2 + ((size_t)layer * 128 + ot + srow) * 128 + sseg * 8;
    const u16* ga = gt1 + (size_t)(rt + srow) * 128 + sseg * 8;
    const u16* gb = gt2 + (size_t)(rt + srow) * 128 + sseg * 8;
    const u16* ha = hc1 + ((size_t)b * 512 + rt + srow) * 128 + sseg * 8;
    const u16* hb = hc2 + ((size_t)b * 512 + rt + srow) * 128 + sseg * 8;
    f32x4 acc[2][2] = {{{0.f,0.f,0.f,0.f},{0.f,0.f,0.f,0.f}},{{0.f,0.f,0.f,0.f},{0.f,0.f,0.f,0.f}}};
    uint4 raO0, raO1, rbO0, rbO1, raE0, raE1, rbE0, rbE1;
#define IDFT_LOAD(chk, Ra0, Ra1, Rb0, Rb1)                                    \
    {   int k0_ = ((chk) & 3) * 32;                                           \
        if ((chk) < 4) {                                                      \
            Ra0 = *(const uint4*)(ya + k0_); Ra1 = *(const uint4*)(yb + k0_); \
            Rb0 = *(const uint4*)(ga + k0_); Rb1 = *(const uint4*)(gb + k0_); \
        } else {                                                              \
            Ra0 = *(const uint4*)(ca + k0_); Ra1 = *(const uint4*)(cb + k0_); \
            Rb0 = *(const uint4*)(ha + k0_); Rb1 = *(const uint4*)(hb + k0_); \
        } }
#define IDFT_STORE(BUF, Ra0, Ra1, Rb0, Rb1)                                   \
    {   *(uint4*)(A1[BUF] + soff) = Ra0; *(uint4*)(A2[BUF] + soff) = Ra1;     \
        *(uint4*)(B1[BUF] + soff) = Rb0; *(uint4*)(B2[BUF] + soff) = Rb1; }
#define IDFT_COMPUTE(BUF)                                                     \
    {   bf16x8 bfr[2][2];                                                     \
        _Pragma("unroll")                                                     \
        for (int rf = 0; rf < 2; rf++) {                                      \
            bfr[rf][0] = *(const bf16x8*)&B1[BUF][(wr0 + rf * 16 + arow) * 40 + kgrp]; \
            bfr[rf][1] = *(const bf16x8*)&B2[BUF][(wr0 + rf * 16 + arow) * 40 + kgrp]; \
        }                                                                     \
        _Pragma("unroll")                                                     \
        for (int of = 0; of < 2; of++) {                                      \
            bf16x8 a1 = *(const bf16x8*)&A1[BUF][(wo0 + of * 16 + arow) * 40 + kgrp]; \
            bf16x8 a2 = *(const bf16x8*)&A2[BUF][(wo0 + of * 16 + arow) * 40 + kgrp]; \
            _Pragma("unroll")                                                 \
            for (int rf = 0; rf < 2; rf++) {                                  \
                acc[of][rf] = MFMA16(a1, bfr[rf][0], acc[of][rf]);            \
                acc[of][rf] = MFMA16(a1, bfr[rf][1], acc[of][rf]);            \
                acc[of][rf] = MFMA16(a2, bfr[rf][0], acc[of][rf]);            \
            }                                                                 \
        } }
    IDFT_LOAD(0, raO0, raO1, rbO0, rbO1)
    IDFT_STORE(0, raO0, raO1, rbO0, rbO1)
    IDFT_LOAD(1, raO0, raO1, rbO0, rbO1)
    IDFT_LOAD(2, raE0, raE1, rbE0, rbE1)
    __syncthreads();
    for (int k = 0; k < 8; k += 2) {
        IDFT_COMPUTE(0)
        IDFT_STORE(1, raO0, raO1, rbO0, rbO1)
        if (k < 5) IDFT_LOAD(k + 3, raO0, raO1, rbO0, rbO1)
        __syncthreads();
        IDFT_COMPUTE(1)
        if (k < 6) {
            IDFT_STORE(0, raE0, raE1, rbE0, rbE1)
            if (k < 4) IDFT_LOAD(k + 4, raE0, raE1, rbE0, rbE1)
        }
        __syncthreads();
    }
#undef IDFT_LOAD
#undef IDFT_STORE
#undef IDFT_COMPUTE
#pragma unroll
    for (int of = 0; of < 2; of++) {
        int obl = wo0 + of * 16 + (l >> 4) * 4;
        int ob = ot + obl;
#pragma unroll
        for (int rf = 0; rf < 2; rf++) {
            int rloc = wr0 + rf * 16 + (l & 15);
            int r = rt + rloc;
            float v0 = gelu_exact(acc[of][rf][0] + conv_b[layer * 128 + ob + 0]);
            float v1 = gelu_exact(acc[of][rf][1] + conv_b[layer * 128 + ob + 1]);
            float v2 = gelu_exact(acc[of][rf][2] + conv_b[layer * 128 + ob + 2]);
            float v3 = gelu_exact(acc[of][rf][3] + conv_b[layer * 128 + ob + 3]);
            ushort4 hv, lv;
            hv.x = f2bf_hi(v0); hv.y = f2bf_hi(v1); hv.z = f2bf_hi(v2); hv.w = f2bf_hi(v3);
            lv.x = f2bf_lo(v0); lv.y = f2bf_lo(v1); lv.z = f2bf_lo(v2); lv.w = f2bf_lo(v3);
            size_t off = ((size_t)b * 512 + r) * 128 + ob;
            *(ushort4*)&hn1[off] = hv;
            *(ushort4*)&hn2[off] = lv;
            if (wtr) {
                T1[(obl + 0) * 66 + rloc] = hv.x; T1[(obl + 1) * 66 + rloc] = hv.y;
                T1[(obl + 2) * 66 + rloc] = hv.z; T1[(obl + 3) * 66 + rloc] = hv.w;
                T2[(obl + 0) * 66 + rloc] = lv.x; T2[(obl + 1) * 66 + rloc] = lv.y;
                T2[(obl + 2) * 66 + rloc] = lv.z; T2[(obl + 3) * 66 + rloc] = lv.w;
            }
        }
    }
    if (wtr) {
        __syncthreads();
#pragma unroll
        for (int q = 0; q < 8; q++) {
            int t = tid + q * 256;
            int o = t >> 5, ru = t & 31;
            u32 vh = *(const u32*)&T1[o * 66 + ru * 2];
            u32 vl = *(const u32*)&T2[o * 66 + ru * 2];
            size_t off = ((size_t)b * 128 + ot + o) * 512 + rt + ru * 2;
            *(u32*)&htc1[off] = vh;
            *(u32*)&htc2[off] = vl;
        }
    }
}

// ---------------------------------------------------------------------------
// head (MFMA, round-4 staging) + fused fc0 for next step (when do_fc0).
// grid 256 blocks (b x 8 r-chunks of 64), 4 waves x 16 rows.
// ---------------------------------------------------------------------------
__global__ __launch_bounds__(256) void head_mfma(const u16* __restrict__ ht1, const u16* __restrict__ ht2,
        const u16* __restrict__ f11, const u16* __restrict__ f12,
        const float* __restrict__ fc1_b, const float* __restrict__ fc2_w,
        const float* __restrict__ fc2_b,
        const float* __restrict__ t_grid, const float* __restrict__ fc0_w,
        const float* __restrict__ fc0_b,
        float* __restrict__ seq, float* __restrict__ preds,
        u16* __restrict__ nht1, u16* __restrict__ nht2,
        u16* __restrict__ nhtc1, u16* __restrict__ nhtc2,
        int step, int do_fc0) {
    __shared__ __align__(16) u16 POOL[25600];     // 51.2 KB, aliased in epilogue
    __shared__ float fc2s[256], fc1bs[256];
    u16* HA1 = POOL;                // 256*40
    u16* HA2 = POOL + 10240;
    u16* HB1 = POOL + 20480;        // 64*40
    u16* HB2 = POOL + 23040;
    int blk = blockIdx.x;
    int b = blk >> 3, r0 = (blk & 7) * 64;
    int tid = threadIdx.x, wid = tid >> 6, l = tid & 63;
    fc2s[tid] = fc2_w[tid];
    fc1bs[tid] = fc1_b[tid];
    int arow = l & 15, kgrp = (l >> 4) * 8;
    f32x4 acc[16];
#pragma unroll
    for (int jf = 0; jf < 16; jf++) acc[jf] = (f32x4){0.f, 0.f, 0.f, 0.f};
    for (int k0 = 0; k0 < 128; k0 += 32) {
        __syncthreads();
        // stage A (fc1t): 2 planes x 256 j x 4 segs = 2048 tasks
#pragma unroll
        for (int q = 0; q < 8; q++) {
            int t = tid + q * 256;
            int pl = t >> 10, j = (t >> 2) & 255, seg = t & 3;
            const u16* src = (pl ? f12 : f11) + (size_t)j * 128 + k0 + seg * 8;
            *(uint4*)((pl ? HA2 : HA1) + j * 40 + seg * 8) = *(const uint4*)src;
        }
        // stage B (h rows): 2 planes x 64 rows x 4 segs = 512 tasks
#pragma unroll
        for (int q = 0; q < 2; q++) {
            int t = tid + q * 256;
            int pl = t >> 8, rr = (t >> 2) & 63, seg = t & 3;
            const u16* src = (pl ? ht2 : ht1) + ((size_t)b * 512 + r0 + rr) * 128 + k0 + seg * 8;
            *(uint4*)((pl ? HB2 : HB1) + rr * 40 + seg * 8) = *(const uint4*)src;
        }
        __syncthreads();
        int bo = (wid * 16 + arow) * 40 + kgrp;
        bf16x8 b1 = *(const bf16x8*)&HB1[bo];
        bf16x8 b2 = *(const bf16x8*)&HB2[bo];
#pragma unroll 4
        for (int jf = 0; jf < 16; jf++) {
            int ao = (jf * 16 + arow) * 40 + kgrp;
            bf16x8 a1 = *(const bf16x8*)&HA1[ao];
            bf16x8 a2 = *(const bf16x8*)&HA2[ao];
            acc[jf] = MFMA16(a1, b1, acc[jf]);
            acc[jf] = MFMA16(a1, b2, acc[jf]);
            acc[jf] = MFMA16(a2, b1, acc[jf]);
        }
    }
    __syncthreads();   // all POOL reads done; safe to alias below
    float dx = 0.0f;
#pragma unroll 4
    for (int jf = 0; jf < 16; jf++) {
        int jbase = jf * 16 + (l >> 4) * 4;
#pragma unroll
        for (int jj = 0; jj < 4; jj++) {
            int j = jbase + jj;
            dx += gelu_exact(acc[jf][jj] + fc1bs[j]) * fc2s[j];
        }
    }
    dx += __shfl_xor(dx, 16);
    dx += __shfl_xor(dx, 32);
    bool zlane = ((l >> 4) == 0);
    int rml = wid * 16 + arow;            // local r within [0,64)
    float zn = 0.0f;
    if (zlane) {
        int r = r0 + rml;
        zn = seq[((size_t)b * SEQROWS + step + 23) * NR + r] + dx + fc2_b[0];
        seq[((size_t)b * SEQROWS + step + 24) * NR + r] = zn;
        preds[((size_t)b * NSTEPS + step) * NR + r] = zn;
    }
    if (!do_fc0) return;
    // ---- fused fc0 for step+1: window rows (step+1 .. step+24) ----
    float* win = (float*)POOL;                 // [24][64]
    float* wl  = (float*)POOL + 2048;          // [28][128]
    float* bl  = (float*)POOL + 2048 + 3584;   // [128]
    for (int t = tid; t < 23 * 64; t += 256) {
        int tr = t >> 6, c = t & 63;
        win[tr * 64 + c] = seq[((size_t)b * SEQROWS + step + 1 + tr) * NR + r0 + c];
    }
    for (int t = tid; t < 28 * 128; t += 256) wl[t] = fc0_w[t];
    if (tid < 128) bl[tid] = fc0_b[tid];
    if (zlane) win[23 * 64 + rml] = zn;
    __syncthreads();
    int lane = tid & 63, wq = tid >> 6;
    int r = r0 + lane;
    float sv[24];
#pragma unroll
    for (int t = 0; t < 24; t++) sv[t] = win[t * 64 + lane];
    float tt = t_grid[b * 24 + 23] + (float)(step + 2);
    float ang24 = 6.28318530717958647692f * tt * (1.0f / 24.0f);
    float ang168 = 6.28318530717958647692f * tt * (1.0f / 168.0f);
    float s24 = sinf(ang24), c24 = cosf(ang24), s168 = sinf(ang168);
    float xc = (float)r * (1.0f / 511.0f);
    size_t rowoff = ((size_t)b * NR + r) * NW;
#pragma unroll 2
    for (int w0 = 0; w0 < 32; w0 += 2) {
        float acc2[2];
#pragma unroll
        for (int q = 0; q < 2; q++) {
            int w = wq * 32 + w0 + q;
            float a = bl[w];
#pragma unroll
            for (int t = 0; t < 24; t++) a += sv[t] * wl[t * 128 + w];
            a += s24 * wl[24 * 128 + w] + c24 * wl[25 * 128 + w]
               + s168 * wl[26 * 128 + w] + xc * wl[27 * 128 + w];
            acc2[q] = a;
        }
        u16 h0 = f2bf_hi(acc2[0]), h1 = f2bf_hi(acc2[1]);
        u16 l0 = f2bf_lo(acc2[0]), l1 = f2bf_lo(acc2[1]);
        size_t off = rowoff + wq * 32 + w0;
        *(u32*)&nht1[off] = (u32)h0 | ((u32)h1 << 16);
        *(u32*)&nht2[off] = (u32)l0 | ((u32)l1 << 16);
        int w = wq * 32 + w0;
        size_t coff = ((size_t)b * 128 + w) * 512 + r;
        nhtc1[coff] = h0; nhtc1[coff + 512] = h1;
        nhtc2[coff] = l0; nhtc2[coff + 512] = l1;
    }
}

// ---------------------------------------------------------------------------
extern "C" void kernel_launch(void* const* d_in, const int* in_sizes, int n_in,
                              void* d_out, int out_size, void* d_ws, size_t ws_size,
                              hipStream_t stream) {
    (void)in_sizes; (void)n_in; (void)out_size; (void)ws_size;
    const float* z       = (const float*)d_in[0];
    const float* t_grid  = (const float*)d_in[1];
    const float* fc0_w   = (const float*)d_in[2];
    const float* fc0_b   = (const float*)d_in[3];
    const float* spec_wr = (const float*)d_in[4];
    const float* spec_wi = (const float*)d_in[5];
    const float* conv_w  = (const float*)d_in[6];
    const float* conv_b  = (const float*)d_in[7];
    const float* fc1_w   = (const float*)d_in[8];
    const float* fc1_b   = (const float*)d_in[9];
    const float* fc2_w   = (const float*)d_in[10];
    const float* fc2_b   = (const float*)d_in[11];
    float* preds = (float*)d_out;

    char* p = (char*)d_ws;
    float* seq = (float*)p;  p += (size_t)NB * SEQROWS * NR * 4;
    u16* ht1 = (u16*)p;  p += (size_t)2 * NB * NR * NW * 2;   // [2 buf][b][r][c] hi
    u16* ht2 = (u16*)p;  p += (size_t)2 * NB * NR * NW * 2;   // lo
    u16* htc1 = (u16*)p; p += (size_t)NB * NW * NR * 2;       // [b][c][r] hi
    u16* htc2 = (u16*)p; p += (size_t)NB * NW * NR * 2;       // lo
    u16* x1  = (u16*)p;  p += (size_t)128 * 4096 * 2;
    u16* x2  = (u16*)p;  p += (size_t)128 * 4096 * 2;
    u16* y1  = (u16*)p;  p += (size_t)NB * NW * 128 * 2;
    u16* y2  = (u16*)p;  p += (size_t)NB * NW * 128 * 2;
    u16* f1  = (u16*)p;  p += (size_t)128 * 512 * 2;
    u16* f2  = (u16*)p;  p += (size_t)128 * 512 * 2;
    u16* gt1 = (u16*)p;  p += (size_t)512 * 128 * 2;
    u16* gt2 = (u16*)p;  p += (size_t)512 * 128 * 2;
    u16* wr1 = (u16*)p;  p += (size_t)NLAY * NM * NW * NW * 2;
    u16* wr2 = (u16*)p;  p += (size_t)NLAY * NM * NW * NW * 2;
    u16* wi1 = (u16*)p;  p += (size_t)NLAY * NM * NW * NW * 2;
    u16* wi2 = (u16*)p;  p += (size_t)NLAY * NM * NW * NW * 2;
    u16* cw1 = (u16*)p;  p += (size_t)NLAY * NW * NW * 2;
    u16* cw2 = (u16*)p;  p += (size_t)NLAY * NW * NW * 2;
    u16* f11 = (u16*)p;  p += (size_t)256 * 128 * 2;
    u16* f12 = (u16*)p;  p += (size_t)256 * 128 * 2;

    const size_t htplane = (size_t)NB * NR * NW;

    build_tables_planes<<<256, 256, 0, stream>>>(f1, f2, gt1, gt2);
    prep_specw<<<512, 256, 0, stream>>>(spec_wr, spec_wi, wr1, wr2, wi1, wi2);
    prep_cw<<<256, 256, 0, stream>>>(conv_w, cw1, cw2);
    prep_fc1t<<<128, 256, 0, stream>>>(fc1_w, f11, f12);
    init_seq_kernel<<<(NB * NTH * NR) / 256, 256, 0, stream>>>(z, seq);

    for (int step = 0; step < NSTEPS; step++) {
        if (step == 0) {
            fc0_kernel<<<dim3(8, 32), 256, 0, stream>>>(seq, t_grid, fc0_w, fc0_b,
                                                        ht1, ht2, htc1, htc2, step);
        }
        int cur = 0;
        for (int l = 0; l < NLAY; l++) {
            const u16* hc1 = ht1 + (size_t)cur * htplane;
            const u16* hc2 = ht2 + (size_t)cur * htplane;
            u16* hn1 = ht1 + (size_t)(cur ^ 1) * htplane;
            u16* hn2 = ht2 + (size_t)(cur ^ 1) * htplane;
            dft_mfma<<<dim3(64, 4), 256, 0, stream>>>(f1, f2, htc1, htc2, x1, x2);
            modemix_mfma<<<dim3(64, 4), 256, 0, stream>>>(x1, x2, wr1, wr2, wi1, wi2,
                                                          y1, y2, l);
            idft_conv_mfma<<<dim3(8, 2, 32), 256, 0, stream>>>(y1, y2, gt1, gt2,
                                                               hc1, hc2, cw1, cw2,
                                                               conv_b, hn1, hn2,
                                                               htc1, htc2, l, (l < 3) ? 1 : 0);
            cur ^= 1;
        }
        // after 4 layers cur == 0; head reads buffer 0 and (if step<11)
        // writes next step's fc0 output into buffer 0 + htc.
        head_mfma<<<256, 256, 0, stream>>>(ht1, ht2, f11, f12, fc1_b, fc2_w, fc2_b,
                                           t_grid, fc0_w, fc0_b, seq, preds,
                                           ht1, ht2, htc1, htc2,
                                           step, (step < NSTEPS - 1) ? 1 : 0);
    }
}

// Round 8
// 1807.043 us; speedup vs baseline: 56.0979x; 1.0946x over previous
//
#include <hip/hip_runtime.h>
#include <math.h>

// LatentFNO: B=32, T=24, R=512, W=128, M=64 modes, 4 layers, 12 steps.
// Round 7: head_mfma spill root-caused: "#pragma unroll 4" on the jf loop
// left acc[jf] runtime-indexed -> whole acc array in scratch (rule #20),
// 76 MB HBM writes/dispatch since round 4. Fix: FULL unroll of both jf
// loops (static indices -> register-resident acc). Everything else as r6.
// Math: exact 3-term bf16 split (A1B1+A1B2+A2B1).

#define NB 32
#define NR 512
#define NW 128
#define NM 64
#define NTH 24
#define NLAY 4
#define NSTEPS 12
#define SEQROWS 36

typedef unsigned short u16;
typedef unsigned int u32;
typedef __attribute__((ext_vector_type(8))) short bf16x8;
typedef __attribute__((ext_vector_type(4))) float f32x4;
#define MFMA16(a, b, c) __builtin_amdgcn_mfma_f32_16x16x32_bf16((a), (b), (c), 0, 0, 0)

__device__ __forceinline__ float gelu_exact(float x) {
    return 0.5f * x * (1.0f + erff(x * 0.70710678118654752f));
}
__device__ __forceinline__ float bf2f(u16 u) {
    union { u32 i; float f; } v; v.i = ((u32)u) << 16; return v.f;
}
__device__ __forceinline__ u16 f2bf_hi(float x) {
    union { float f; u32 i; } v; v.f = x; return (u16)(v.i >> 16);
}
__device__ __forceinline__ u16 f2bf_lo(float x) {
    float h = bf2f(f2bf_hi(x));
    return f2bf_hi(x - h);
}
__device__ __forceinline__ bf16x8 negbf(bf16x8 a) {
#pragma unroll
    for (int i = 0; i < 8; i++) a[i] ^= (short)0x8000;
    return a;
}

// ---------------------------------------------------------------------------
// Tables: F planes [mc=128][r=512]; GT planes [r=512][mc=128].
// ---------------------------------------------------------------------------
__global__ void build_tables_planes(u16* __restrict__ f1, u16* __restrict__ f2,
                                    u16* __restrict__ gt1, u16* __restrict__ gt2) {
    int idx = blockIdx.x * 256 + threadIdx.x;   // 65536: mc*512 + r
    int mc = idx >> 9, r = idx & 511, m = mc & 63;
    int p = (m * r) & 511;
    float a = (float)p * (1.0f / 256.0f);
    float c = cospif(a), s = sinpif(a);
    float Fv = (mc < 64) ? c : -s;
    float cm = (m == 0) ? (1.0f / 512.0f) : (2.0f / 512.0f);
    float Gv = (mc < 64) ? cm * c : ((m == 0) ? 0.0f : -cm * s);
    f1[idx] = f2bf_hi(Fv); f2[idx] = f2bf_lo(Fv);
    size_t g = (size_t)r * 128 + mc;
    gt1[g] = f2bf_hi(Gv); gt2[g] = f2bf_lo(Gv);
}

// spec_w (l,i,o,m) -> planes [l][m][o][i] hi/lo, coalesced both directions.
__global__ __launch_bounds__(256) void prep_specw(const float* __restrict__ wr, const float* __restrict__ wi,
                           u16* __restrict__ wr1, u16* __restrict__ wr2,
                           u16* __restrict__ wi1, u16* __restrict__ wi2) {
    __shared__ float tile[128][65];
    int l = blockIdx.x >> 7, o = blockIdx.x & 127;
    int tid = threadIdx.x;
    size_t sbase = (size_t)l * 1048576 + (size_t)o * 64;
    size_t dbase = (size_t)l * 64 * 16384 + (size_t)o * 128;
    for (int pass = 0; pass < 2; pass++) {
        const float* src = pass ? wi : wr;
        u16* d1 = pass ? wi1 : wr1;
        u16* d2 = pass ? wi2 : wr2;
        if (pass) __syncthreads();
        for (int e = tid; e < 8192; e += 256) {
            int i = e >> 6, m = e & 63;
            tile[i][m] = src[sbase + (size_t)i * 8192 + m];
        }
        __syncthreads();
        for (int e = tid; e < 4096; e += 256) {
            int m = e >> 6, i2 = (e & 63) * 2;
            float v0 = tile[i2][m], v1 = tile[i2 + 1][m];
            u32 hh = (u32)f2bf_hi(v0) | ((u32)f2bf_hi(v1) << 16);
            u32 ll = (u32)f2bf_lo(v0) | ((u32)f2bf_lo(v1) << 16);
            size_t d = dbase + (size_t)m * 16384 + i2;
            *(u32*)&d1[d] = hh;
            *(u32*)&d2[d] = ll;
        }
    }
}

__global__ void prep_cw(const float* __restrict__ cw, u16* __restrict__ c1, u16* __restrict__ c2) {
    int idx = blockIdx.x * 256 + threadIdx.x;   // 65536
    float v = cw[idx];
    c1[idx] = f2bf_hi(v); c2[idx] = f2bf_lo(v);
}

// fc1_w [c=128][j=256] -> fc1t planes [j][c] hi/lo
__global__ void prep_fc1t(const float* __restrict__ fc1_w,
                          u16* __restrict__ f11, u16* __restrict__ f12) {
    int idx = blockIdx.x * 256 + threadIdx.x;   // 32768: j*128 + c
    int j = idx >> 7, c = idx & 127;
    float v = fc1_w[(size_t)c * 256 + j];
    f11[idx] = f2bf_hi(v); f12[idx] = f2bf_lo(v);
}

__global__ void init_seq_kernel(const float* __restrict__ z, float* __restrict__ seq) {
    int idx = blockIdx.x * 256 + threadIdx.x;    // < 32*24*512
    int b = idx / (NTH * NR);
    int rem = idx - b * (NTH * NR);
    seq[(size_t)b * SEQROWS * NR + rem] = z[idx];
}

// ---------------------------------------------------------------------------
// fc0 (fp32), step 0 only: writes ht[b][r][c] AND htc[b][c][r] planes.
// ---------------------------------------------------------------------------
__global__ __launch_bounds__(256) void fc0_kernel(const float* __restrict__ seq,
        const float* __restrict__ t_grid, const float* __restrict__ fc0_w,
        const float* __restrict__ fc0_b, u16* __restrict__ ht1, u16* __restrict__ ht2,
        u16* __restrict__ htc1, u16* __restrict__ htc2, int step) {
    __shared__ float wlds[28 * 128];
    __shared__ float blds[128];
    int b = blockIdx.y, rblk = blockIdx.x;
    int tid = threadIdx.x;
    for (int t = tid; t < 28 * 128; t += 256) wlds[t] = fc0_w[t];
    if (tid < 128) blds[tid] = fc0_b[tid];
    __syncthreads();
    int lane = tid & 63, wq = tid >> 6;
    int r = rblk * 64 + lane;
    float sv[24];
    const float* sp = seq + ((size_t)b * SEQROWS + step) * NR + r;
#pragma unroll
    for (int t = 0; t < 24; t++) sv[t] = sp[(size_t)t * NR];
    float tt = t_grid[b * 24 + 23] + (float)(step + 1);
    float ang24 = 6.28318530717958647692f * tt * (1.0f / 24.0f);
    float ang168 = 6.28318530717958647692f * tt * (1.0f / 168.0f);
    float s24 = sinf(ang24), c24 = cosf(ang24), s168 = sinf(ang168);
    float xc = (float)r * (1.0f / 511.0f);
    size_t rowoff = ((size_t)b * NR + r) * NW;
#pragma unroll 2
    for (int w0 = 0; w0 < 32; w0 += 2) {
        float acc2[2];
#pragma unroll
        for (int q = 0; q < 2; q++) {
            int w = wq * 32 + w0 + q;
            float acc = blds[w];
#pragma unroll
            for (int t = 0; t < 24; t++) acc += sv[t] * wlds[t * 128 + w];
            acc += s24 * wlds[24 * 128 + w] + c24 * wlds[25 * 128 + w]
                 + s168 * wlds[26 * 128 + w] + xc * wlds[27 * 128 + w];
            acc2[q] = acc;
        }
        u16 h0 = f2bf_hi(acc2[0]), h1 = f2bf_hi(acc2[1]);
        u16 l0 = f2bf_lo(acc2[0]), l1 = f2bf_lo(acc2[1]);
        size_t off = rowoff + wq * 32 + w0;
        *(u32*)&ht1[off] = (u32)h0 | ((u32)h1 << 16);
        *(u32*)&ht2[off] = (u32)l0 | ((u32)l1 << 16);
        int w = wq * 32 + w0;
        size_t coff = ((size_t)b * 128 + w) * 512 + r;
        htc1[coff] = h0; htc1[coff + 512] = h1;
        htc2[coff] = l0; htc2[coff + 512] = l1;
    }
}

// ---------------------------------------------------------------------------
// dft (MFMA, depth-3 pipelined): X[128][4096] = F * htc^T, K=512.
// grid (64, 4), 256 thr = 4 waves (2 mc x 2 n).
// ---------------------------------------------------------------------------
__global__ __launch_bounds__(256) void dft_mfma(const u16* __restrict__ f1, const u16* __restrict__ f2,
        const u16* __restrict__ htc1, const u16* __restrict__ htc2,
        u16* __restrict__ x1, u16* __restrict__ x2) {
    __shared__ __align__(16) u16 A1[2][1280], A2[2][1280];
    __shared__ __align__(16) u16 B1[2][2560], B2[2][2560];
    int bx = blockIdx.x;
    int b = bx >> 1, ch = bx & 1;
    int mct = blockIdx.y * 32;
    int tid = threadIdx.x, wid = tid >> 6, l = tid & 63;
    int wm0 = (wid >> 1) * 16, wn0 = (wid & 1) * 32;
    int arow = (l & 15), kgrp = (l >> 4) * 8;
    f32x4 acc0 = {0.f, 0.f, 0.f, 0.f}, acc1 = {0.f, 0.f, 0.f, 0.f};
    int pa_pl = tid >> 7, pa_row = (tid >> 2) & 31, pa_seg = tid & 3;
    const u16* asrc = (pa_pl ? f2 : f1) + (size_t)(mct + pa_row) * 512 + pa_seg * 8;
    int aoff = pa_row * 40 + pa_seg * 8;
    int b_row = (tid >> 2) & 63, b_seg = tid & 3;
    const u16* bsrc1 = htc1 + ((size_t)b * 128 + ch * 64 + b_row) * 512 + b_seg * 8;
    const u16* bsrc2 = htc2 + ((size_t)b * 128 + ch * 64 + b_row) * 512 + b_seg * 8;
    int boff = b_row * 40 + b_seg * 8;
    uint4 raO, rbO0, rbO1, raE, rbE0, rbE1;
    raO = *(const uint4*)(asrc); rbO0 = *(const uint4*)(bsrc1); rbO1 = *(const uint4*)(bsrc2);
    *(uint4*)((pa_pl ? A2[0] : A1[0]) + aoff) = raO;
    *(uint4*)(B1[0] + boff) = rbO0;
    *(uint4*)(B2[0] + boff) = rbO1;
    raO = *(const uint4*)(asrc + 32); rbO0 = *(const uint4*)(bsrc1 + 32); rbO1 = *(const uint4*)(bsrc2 + 32);
    raE = *(const uint4*)(asrc + 64); rbE0 = *(const uint4*)(bsrc1 + 64); rbE1 = *(const uint4*)(bsrc2 + 64);
    __syncthreads();
#define DFT_COMPUTE(BUF)                                                       \
    {   bf16x8 a1 = *(const bf16x8*)&A1[BUF][(wm0 + arow) * 40 + kgrp];        \
        bf16x8 a2 = *(const bf16x8*)&A2[BUF][(wm0 + arow) * 40 + kgrp];        \
        bf16x8 b10 = *(const bf16x8*)&B1[BUF][(wn0 + arow) * 40 + kgrp];       \
        bf16x8 b20 = *(const bf16x8*)&B2[BUF][(wn0 + arow) * 40 + kgrp];       \
        bf16x8 b11 = *(const bf16x8*)&B1[BUF][(wn0 + 16 + arow) * 40 + kgrp];  \
        bf16x8 b21 = *(const bf16x8*)&B2[BUF][(wn0 + 16 + arow) * 40 + kgrp];  \
        acc0 = MFMA16(a1, b10, acc0);                                          \
        acc0 = MFMA16(a1, b20, acc0);                                          \
        acc0 = MFMA16(a2, b10, acc0);                                          \
        acc1 = MFMA16(a1, b11, acc1);                                          \
        acc1 = MFMA16(a1, b21, acc1);                                          \
        acc1 = MFMA16(a2, b11, acc1); }
    for (int k = 0; k < 16; k += 2) {
        DFT_COMPUTE(0)
        *(uint4*)((pa_pl ? A2[1] : A1[1]) + aoff) = raO;
        *(uint4*)(B1[1] + boff) = rbO0;
        *(uint4*)(B2[1] + boff) = rbO1;
        if (k < 13) {
            int ko = (k + 3) * 32;
            raO = *(const uint4*)(asrc + ko); rbO0 = *(const uint4*)(bsrc1 + ko); rbO1 = *(const uint4*)(bsrc2 + ko);
        }
        __syncthreads();
        DFT_COMPUTE(1)
        if (k < 14) {
            *(uint4*)((pa_pl ? A2[0] : A1[0]) + aoff) = raE;
            *(uint4*)(B1[0] + boff) = rbE0;
            *(uint4*)(B2[0] + boff) = rbE1;
            if (k < 12) {
                int ko = (k + 4) * 32;
                raE = *(const uint4*)(asrc + ko); rbE0 = *(const uint4*)(bsrc1 + ko); rbE1 = *(const uint4*)(bsrc2 + ko);
            }
        }
        __syncthreads();
    }
#undef DFT_COMPUTE
    int mcr = mct + wm0 + (l >> 4) * 4;
    int n0 = bx * 64 + wn0 + (l & 15);
#pragma unroll
    for (int j = 0; j < 4; j++) {
        size_t o0 = (size_t)(mcr + j) * 4096 + n0;
        x1[o0] = f2bf_hi(acc0[j]); x2[o0] = f2bf_lo(acc0[j]);
        size_t o1 = o0 + 16;
        x1[o1] = f2bf_hi(acc1[j]); x2[o1] = f2bf_lo(acc1[j]);
    }
}

// ---------------------------------------------------------------------------
// modemix (MFMA, depth-3): per mode m: Y = W *c X, K=128. grid (64, 4).
// ---------------------------------------------------------------------------
__global__ __launch_bounds__(256) void modemix_mfma(const u16* __restrict__ x1, const u16* __restrict__ x2,
        const u16* __restrict__ wr1, const u16* __restrict__ wr2,
        const u16* __restrict__ wi1, const u16* __restrict__ wi2,
        u16* __restrict__ y1, u16* __restrict__ y2, int layer) {
    __shared__ __align__(16) u16 WR1[2][1280], WR2[2][1280], WI1[2][1280], WI2[2][1280];
    __shared__ __align__(16) u16 XR1[2][1280], XR2[2][1280], XI1[2][1280], XI2[2][1280];
    int m = blockIdx.x, oq = blockIdx.y;
    int tid = threadIdx.x, wid = tid >> 6, l = tid & 63;
    int wo0 = (wid >> 1) * 16, wb0 = (wid & 1) * 16;
    int arow = (l & 15), kgrp = (l >> 4) * 8;
    f32x4 ar = {0.f, 0.f, 0.f, 0.f}, ai = {0.f, 0.f, 0.f, 0.f};
    size_t wbase = (((size_t)layer * 64 + m) * 128 + oq * 32) * 128;
    int s0 = tid >> 7, srow = (tid >> 2) & 31, sseg = tid & 3;
    const u16* wsrc0 = (s0 ? wr2 : wr1) + wbase + (size_t)srow * 128 + sseg * 8;
    const u16* wsrc1 = (s0 ? wi2 : wi1) + wbase + (size_t)srow * 128 + sseg * 8;
    const u16* xb = s0 ? x2 : x1;
    const u16* xsrc0 = xb + (size_t)m * 4096 + srow * 128 + sseg * 8;
    const u16* xsrc1 = xb + (size_t)(64 + m) * 4096 + srow * 128 + sseg * 8;
    int soff = srow * 40 + sseg * 8;
    u16* wd0_0 = (s0 ? WR2[0] : WR1[0]) + soff;  u16* wd0_1 = (s0 ? WR2[1] : WR1[1]) + soff;
    u16* wd1_0 = (s0 ? WI2[0] : WI1[0]) + soff;  u16* wd1_1 = (s0 ? WI2[1] : WI1[1]) + soff;
    u16* xd0_0 = (s0 ? XR2[0] : XR1[0]) + soff;  u16* xd0_1 = (s0 ? XR2[1] : XR1[1]) + soff;
    u16* xd1_0 = (s0 ? XI2[0] : XI1[0]) + soff;  u16* xd1_1 = (s0 ? XI2[1] : XI1[1]) + soff;
    uint4 rwO0, rwO1, rxO0, rxO1, rwE0, rwE1, rxE0, rxE1;
    rwO0 = *(const uint4*)(wsrc0); rwO1 = *(const uint4*)(wsrc1);
    rxO0 = *(const uint4*)(xsrc0); rxO1 = *(const uint4*)(xsrc1);
    *(uint4*)wd0_0 = rwO0; *(uint4*)wd1_0 = rwO1;
    *(uint4*)xd0_0 = rxO0; *(uint4*)xd1_0 = rxO1;
    rwO0 = *(const uint4*)(wsrc0 + 32); rwO1 = *(const uint4*)(wsrc1 + 32);
    rxO0 = *(const uint4*)(xsrc0 + 32); rxO1 = *(const uint4*)(xsrc1 + 32);
    rwE0 = *(const uint4*)(wsrc0 + 64); rwE1 = *(const uint4*)(wsrc1 + 64);
    rxE0 = *(const uint4*)(xsrc0 + 64); rxE1 = *(const uint4*)(xsrc1 + 64);
    __syncthreads();
#define MM_COMPUTE(BUF)                                                        \
    {   int ao = (wo0 + arow) * 40 + kgrp;                                     \
        int bo = (wb0 + arow) * 40 + kgrp;                                     \
        bf16x8 Wr1 = *(const bf16x8*)&WR1[BUF][ao], Wr2 = *(const bf16x8*)&WR2[BUF][ao]; \
        bf16x8 Wi1 = *(const bf16x8*)&WI1[BUF][ao], Wi2 = *(const bf16x8*)&WI2[BUF][ao]; \
        bf16x8 Xr1 = *(const bf16x8*)&XR1[BUF][bo], Xr2 = *(const bf16x8*)&XR2[BUF][bo]; \
        bf16x8 Xi1 = *(const bf16x8*)&XI1[BUF][bo], Xi2 = *(const bf16x8*)&XI2[BUF][bo]; \
        bf16x8 nWi1 = negbf(Wi1), nWi2 = negbf(Wi2);                           \
        ar = MFMA16(Wr1, Xr1, ar); ar = MFMA16(Wr1, Xr2, ar); ar = MFMA16(Wr2, Xr1, ar); \
        ar = MFMA16(nWi1, Xi1, ar); ar = MFMA16(nWi1, Xi2, ar); ar = MFMA16(nWi2, Xi1, ar); \
        ai = MFMA16(Wi1, Xr1, ai); ai = MFMA16(Wi1, Xr2, ai); ai = MFMA16(Wi2, Xr1, ai); \
        ai = MFMA16(Wr1, Xi1, ai); ai = MFMA16(Wr1, Xi2, ai); ai = MFMA16(Wr2, Xi1, ai); }
    for (int k = 0; k < 4; k += 2) {
        MM_COMPUTE(0)
        *(uint4*)wd0_1 = rwO0; *(uint4*)wd1_1 = rwO1;
        *(uint4*)xd0_1 = rxO0; *(uint4*)xd1_1 = rxO1;
        if (k == 0) {
            rwO0 = *(const uint4*)(wsrc0 + 96); rwO1 = *(const uint4*)(wsrc1 + 96);
            rxO0 = *(const uint4*)(xsrc0 + 96); rxO1 = *(const uint4*)(xsrc1 + 96);
        }
        __syncthreads();
        MM_COMPUTE(1)
        if (k == 0) {
            *(uint4*)wd0_0 = rwE0; *(uint4*)wd1_0 = rwE1;
            *(uint4*)xd0_0 = rxE0; *(uint4*)xd1_0 = rxE1;
        }
        __syncthreads();
    }
#undef MM_COMPUTE
    int ob = oq * 32 + wo0 + (l >> 4) * 4;
    int bb = wb0 + (l & 15);
#pragma unroll
    for (int j = 0; j < 4; j++) {
        size_t o = ((size_t)bb * 128 + ob + j) * 128;
        y1[o + m] = f2bf_hi(ar[j]); y2[o + m] = f2bf_lo(ar[j]);
        y1[o + 64 + m] = f2bf_hi(ai[j]); y2[o + 64 + m] = f2bf_lo(ai[j]);
    }
}

// ---------------------------------------------------------------------------
// idft+conv (MFMA, depth-3): C[o][r] = [Y|CW](o,256)*[GT;ht](256,r)+bias,GELU.
// grid (8 rt, 2 ot, 32 b). T-transpose epilogue writes htc when wtr.
// ---------------------------------------------------------------------------
__global__ __launch_bounds__(256) void idft_conv_mfma(const u16* __restrict__ y1, const u16* __restrict__ y2,
        const u16* __restrict__ gt1, const u16* __restrict__ gt2,
        const u16* __restrict__ hc1, const u16* __restrict__ hc2,
        const u16* __restrict__ cw1, const u16* __restrict__ cw2,
        const float* __restrict__ conv_b,
        u16* __restrict__ hn1, u16* __restrict__ hn2,
        u16* __restrict__ htc1, u16* __restrict__ htc2, int layer, int wtr) {
    __shared__ __align__(16) u16 A1[2][2560], A2[2][2560];
    __shared__ __align__(16) u16 B1[2][2560], B2[2][2560];
    __shared__ __align__(16) u16 T1[64 * 66], T2[64 * 66];
    int rt = blockIdx.x * 64, ot = blockIdx.y * 64, b = blockIdx.z;
    int tid = threadIdx.x, wid = tid >> 6, l = tid & 63;
    int wo0 = (wid >> 1) * 32, wr0 = (wid & 1) * 32;
    int arow = (l & 15), kgrp = (l >> 4) * 8;
    int srow = (tid >> 2) & 63, sseg = tid & 3;
    int soff = srow * 40 + sseg * 8;
    const u16* ya = y1 + ((size_t)b * 128 + ot + srow) * 128 + sseg * 8;
    const u16* yb = y2 + ((size_t)b * 128 + ot + srow) * 128 + sseg * 8;
    const u16* ca = cw1 + ((size_t)layer * 128 + ot + srow) * 128 + sseg * 8;
    const u16* cb = cw2 + ((size_t)layer * 128 + ot + srow) * 128 + sseg * 8;
    const u16* ga = gt1 + (size_t)(rt + srow) * 128 + sseg * 8;
    const u16* gb = gt2 + (size_t)(rt + srow) * 128 + sseg * 8;
    const u16* ha = hc1 + ((size_t)b * 512 + rt + srow) * 128 + sseg * 8;
    const u16* hb = hc2 + ((size_t)b * 512 + rt + srow) * 128 + sseg * 8;
    f32x4 acc[2][2] = {{{0.f,0.f,0.f,0.f},{0.f,0.f,0.f,0.f}},{{0.f,0.f,0.f,0.f},{0.f,0.f,0.f,0.f}}};
    uint4 raO0, raO1, rbO0, rbO1, raE0, raE1, rbE0, rbE1;
#define IDFT_LOAD(chk, Ra0, Ra1, Rb0, Rb1)                                    \
    {   int k0_ = ((chk) & 3) * 32;                                           \
        if ((chk) < 4) {                                                      \
            Ra0 = *(const uint4*)(ya + k0_); Ra1 = *(const uint4*)(yb + k0_); \
            Rb0 = *(const uint4*)(ga + k0_); Rb1 = *(const uint4*)(gb + k0_); \
        } else {                                                              \
            Ra0 = *(const uint4*)(ca + k0_); Ra1 = *(const uint4*)(cb + k0_); \
            Rb0 = *(const uint4*)(ha + k0_); Rb1 = *(const uint4*)(hb + k0_); \
        } }
#define IDFT_STORE(BUF, Ra0, Ra1, Rb0, Rb1)                                   \
    {   *(uint4*)(A1[BUF] + soff) = Ra0; *(uint4*)(A2[BUF] + soff) = Ra1;     \
        *(uint4*)(B1[BUF] + soff) = Rb0; *(uint4*)(B2[BUF] + soff) = Rb1; }
#define IDFT_COMPUTE(BUF)                                                     \
    {   bf16x8 bfr[2][2];                                                     \
        _Pragma("unroll")                                                     \
        for (int rf = 0; rf < 2; rf++) {                                      \
            bfr[rf][0] = *(const bf16x8*)&B1[BUF][(wr0 + rf * 16 + arow) * 40 + kgrp]; \
            bfr[rf][1] = *(const bf16x8*)&B2[BUF][(wr0 + rf * 16 + arow) * 40 + kgrp]; \
        }                                                                     \
        _Pragma("unroll")                                                     \
        for (int of = 0; of < 2; of++) {                                      \
            bf16x8 a1 = *(const bf16x8*)&A1[BUF][(wo0 + of * 16 + arow) * 40 + kgrp]; \
            bf16x8 a2 = *(const bf16x8*)&A2[BUF][(wo0 + of * 16 + arow) * 40 + kgrp]; \
            _Pragma("unroll")                                                 \
            for (int rf = 0; rf < 2; rf++) {                                  \
                acc[of][rf] = MFMA16(a1, bfr[rf][0], acc[of][rf]);            \
                acc[of][rf] = MFMA16(a1, bfr[rf][1], acc[of][rf]);            \
                acc[of][rf] = MFMA16(a2, bfr[rf][0], acc[of][rf]);            \
            }                                                                 \
        } }
    IDFT_LOAD(0, raO0, raO1, rbO0, rbO1)
    IDFT_STORE(0, raO0, raO1, rbO0, rbO1)
    IDFT_LOAD(1, raO0, raO1, rbO0, rbO1)
    IDFT_LOAD(2, raE0, raE1, rbE0, rbE1)
    __syncthreads();
    for (int k = 0; k < 8; k += 2) {
        IDFT_COMPUTE(0)
        IDFT_STORE(1, raO0, raO1, rbO0, rbO1)
        if (k < 5) IDFT_LOAD(k + 3, raO0, raO1, rbO0, rbO1)
        __syncthreads();
        IDFT_COMPUTE(1)
        if (k < 6) {
            IDFT_STORE(0, raE0, raE1, rbE0, rbE1)
            if (k < 4) IDFT_LOAD(k + 4, raE0, raE1, rbE0, rbE1)
        }
        __syncthreads();
    }
#undef IDFT_LOAD
#undef IDFT_STORE
#undef IDFT_COMPUTE
#pragma unroll
    for (int of = 0; of < 2; of++) {
        int obl = wo0 + of * 16 + (l >> 4) * 4;
        int ob = ot + obl;
#pragma unroll
        for (int rf = 0; rf < 2; rf++) {
            int rloc = wr0 + rf * 16 + (l & 15);
            int r = rt + rloc;
            float v0 = gelu_exact(acc[of][rf][0] + conv_b[layer * 128 + ob + 0]);
            float v1 = gelu_exact(acc[of][rf][1] + conv_b[layer * 128 + ob + 1]);
            float v2 = gelu_exact(acc[of][rf][2] + conv_b[layer * 128 + ob + 2]);
            float v3 = gelu_exact(acc[of][rf][3] + conv_b[layer * 128 + ob + 3]);
            ushort4 hv, lv;
            hv.x = f2bf_hi(v0); hv.y = f2bf_hi(v1); hv.z = f2bf_hi(v2); hv.w = f2bf_hi(v3);
            lv.x = f2bf_lo(v0); lv.y = f2bf_lo(v1); lv.z = f2bf_lo(v2); lv.w = f2bf_lo(v3);
            size_t off = ((size_t)b * 512 + r) * 128 + ob;
            *(ushort4*)&hn1[off] = hv;
            *(ushort4*)&hn2[off] = lv;
            if (wtr) {
                T1[(obl + 0) * 66 + rloc] = hv.x; T1[(obl + 1) * 66 + rloc] = hv.y;
                T1[(obl + 2) * 66 + rloc] = hv.z; T1[(obl + 3) * 66 + rloc] = hv.w;
                T2[(obl + 0) * 66 + rloc] = lv.x; T2[(obl + 1) * 66 + rloc] = lv.y;
                T2[(obl + 2) * 66 + rloc] = lv.z; T2[(obl + 3) * 66 + rloc] = lv.w;
            }
        }
    }
    if (wtr) {
        __syncthreads();
#pragma unroll
        for (int q = 0; q < 8; q++) {
            int t = tid + q * 256;
            int o = t >> 5, ru = t & 31;
            u32 vh = *(const u32*)&T1[o * 66 + ru * 2];
            u32 vl = *(const u32*)&T2[o * 66 + ru * 2];
            size_t off = ((size_t)b * 128 + ot + o) * 512 + rt + ru * 2;
            *(u32*)&htc1[off] = vh;
            *(u32*)&htc2[off] = vl;
        }
    }
}

// ---------------------------------------------------------------------------
// head (MFMA) + fused fc0 for next step. grid 256 blocks, 4 waves x 16 rows.
// acc[16] FULLY static-indexed (full unrolls) -> register resident.
// ---------------------------------------------------------------------------
__global__ __launch_bounds__(256) void head_mfma(const u16* __restrict__ ht1, const u16* __restrict__ ht2,
        const u16* __restrict__ f11, const u16* __restrict__ f12,
        const float* __restrict__ fc1_b, const float* __restrict__ fc2_w,
        const float* __restrict__ fc2_b,
        const float* __restrict__ t_grid, const float* __restrict__ fc0_w,
        const float* __restrict__ fc0_b,
        float* __restrict__ seq, float* __restrict__ preds,
        u16* __restrict__ nht1, u16* __restrict__ nht2,
        u16* __restrict__ nhtc1, u16* __restrict__ nhtc2,
        int step, int do_fc0) {
    __shared__ __align__(16) u16 POOL[25600];     // 51.2 KB, aliased in epilogue
    __shared__ float fc2s[256], fc1bs[256];
    u16* HA1 = POOL;                // 256*40
    u16* HA2 = POOL + 10240;
    u16* HB1 = POOL + 20480;        // 64*40
    u16* HB2 = POOL + 23040;
    int blk = blockIdx.x;
    int b = blk >> 3, r0 = (blk & 7) * 64;
    int tid = threadIdx.x, wid = tid >> 6, l = tid & 63;
    fc2s[tid] = fc2_w[tid];
    fc1bs[tid] = fc1_b[tid];
    int arow = l & 15, kgrp = (l >> 4) * 8;
    f32x4 acc[16];
#pragma unroll
    for (int jf = 0; jf < 16; jf++) acc[jf] = (f32x4){0.f, 0.f, 0.f, 0.f};
    for (int k0 = 0; k0 < 128; k0 += 32) {
        __syncthreads();
        // stage A (fc1t): 2 planes x 256 j x 4 segs = 2048 tasks
#pragma unroll
        for (int q = 0; q < 8; q++) {
            int t = tid + q * 256;
            int pl = t >> 10, j = (t >> 2) & 255, seg = t & 3;
            const u16* src = (pl ? f12 : f11) + (size_t)j * 128 + k0 + seg * 8;
            *(uint4*)((pl ? HA2 : HA1) + j * 40 + seg * 8) = *(const uint4*)src;
        }
        // stage B (h rows): 2 planes x 64 rows x 4 segs = 512 tasks
#pragma unroll
        for (int q = 0; q < 2; q++) {
            int t = tid + q * 256;
            int pl = t >> 8, rr = (t >> 2) & 63, seg = t & 3;
            const u16* src = (pl ? ht2 : ht1) + ((size_t)b * 512 + r0 + rr) * 128 + k0 + seg * 8;
            *(uint4*)((pl ? HB2 : HB1) + rr * 40 + seg * 8) = *(const uint4*)src;
        }
        __syncthreads();
        int bo = (wid * 16 + arow) * 40 + kgrp;
        bf16x8 b1 = *(const bf16x8*)&HB1[bo];
        bf16x8 b2 = *(const bf16x8*)&HB2[bo];
#pragma unroll
        for (int jf = 0; jf < 16; jf++) {
            int ao = (jf * 16 + arow) * 40 + kgrp;
            bf16x8 a1 = *(const bf16x8*)&HA1[ao];
            bf16x8 a2 = *(const bf16x8*)&HA2[ao];
            acc[jf] = MFMA16(a1, b1, acc[jf]);
            acc[jf] = MFMA16(a1, b2, acc[jf]);
            acc[jf] = MFMA16(a2, b1, acc[jf]);
        }
    }
    __syncthreads();   // all POOL reads done; safe to alias below
    float dx = 0.0f;
#pragma unroll
    for (int jf = 0; jf < 16; jf++) {
        int jbase = jf * 16 + (l >> 4) * 4;
#pragma unroll
        for (int jj = 0; jj < 4; jj++) {
            int j = jbase + jj;
            dx += gelu_exact(acc[jf][jj] + fc1bs[j]) * fc2s[j];
        }
    }
    dx += __shfl_xor(dx, 16);
    dx += __shfl_xor(dx, 32);
    bool zlane = ((l >> 4) == 0);
    int rml = wid * 16 + arow;            // local r within [0,64)
    float zn = 0.0f;
    if (zlane) {
        int r = r0 + rml;
        zn = seq[((size_t)b * SEQROWS + step + 23) * NR + r] + dx + fc2_b[0];
        seq[((size_t)b * SEQROWS + step + 24) * NR + r] = zn;
        preds[((size_t)b * NSTEPS + step) * NR + r] = zn;
    }
    if (!do_fc0) return;
    // ---- fused fc0 for step+1: window rows (step+1 .. step+24) ----
    float* win = (float*)POOL;                 // [24][64]
    float* wl  = (float*)POOL + 2048;          // [28][128]
    float* bl  = (float*)POOL + 2048 + 3584;   // [128]
    for (int t = tid; t < 23 * 64; t += 256) {
        int tr = t >> 6, c = t & 63;
        win[tr * 64 + c] = seq[((size_t)b * SEQROWS + step + 1 + tr) * NR + r0 + c];
    }
    for (int t = tid; t < 28 * 128; t += 256) wl[t] = fc0_w[t];
    if (tid < 128) bl[tid] = fc0_b[tid];
    if (zlane) win[23 * 64 + rml] = zn;
    __syncthreads();
    int lane = tid & 63, wq = tid >> 6;
    int r = r0 + lane;
    float sv[24];
#pragma unroll
    for (int t = 0; t < 24; t++) sv[t] = win[t * 64 + lane];
    float tt = t_grid[b * 24 + 23] + (float)(step + 2);
    float ang24 = 6.28318530717958647692f * tt * (1.0f / 24.0f);
    float ang168 = 6.28318530717958647692f * tt * (1.0f / 168.0f);
    float s24 = sinf(ang24), c24 = cosf(ang24), s168 = sinf(ang168);
    float xc = (float)r * (1.0f / 511.0f);
    size_t rowoff = ((size_t)b * NR + r) * NW;
#pragma unroll 2
    for (int w0 = 0; w0 < 32; w0 += 2) {
        float acc2[2];
#pragma unroll
        for (int q = 0; q < 2; q++) {
            int w = wq * 32 + w0 + q;
            float a = bl[w];
#pragma unroll
            for (int t = 0; t < 24; t++) a += sv[t] * wl[t * 128 + w];
            a += s24 * wl[24 * 128 + w] + c24 * wl[25 * 128 + w]
               + s168 * wl[26 * 128 + w] + xc * wl[27 * 128 + w];
            acc2[q] = a;
        }
        u16 h0 = f2bf_hi(acc2[0]), h1 = f2bf_hi(acc2[1]);
        u16 l0 = f2bf_lo(acc2[0]), l1 = f2bf_lo(acc2[1]);
        size_t off = rowoff + wq * 32 + w0;
        *(u32*)&nht1[off] = (u32)h0 | ((u32)h1 << 16);
        *(u32*)&nht2[off] = (u32)l0 | ((u32)l1 << 16);
        int w = wq * 32 + w0;
        size_t coff = ((size_t)b * 128 + w) * 512 + r;
        nhtc1[coff] = h0; nhtc1[coff + 512] = h1;
        nhtc2[coff] = l0; nhtc2[coff + 512] = l1;
    }
}

// ---------------------------------------------------------------------------
extern "C" void kernel_launch(void* const* d_in, const int* in_sizes, int n_in,
                              void* d_out, int out_size, void* d_ws, size_t ws_size,
                              hipStream_t stream) {
    (void)in_sizes; (void)n_in; (void)out_size; (void)ws_size;
    const float* z       = (const float*)d_in[0];
    const float* t_grid  = (const float*)d_in[1];
    const float* fc0_w   = (const float*)d_in[2];
    const float* fc0_b   = (const float*)d_in[3];
    const float* spec_wr = (const float*)d_in[4];
    const float* spec_wi = (const float*)d_in[5];
    const float* conv_w  = (const float*)d_in[6];
    const float* conv_b  = (const float*)d_in[7];
    const float* fc1_w   = (const float*)d_in[8];
    const float* fc1_b   = (const float*)d_in[9];
    const float* fc2_w   = (const float*)d_in[10];
    const float* fc2_b   = (const float*)d_in[11];
    float* preds = (float*)d_out;

    char* p = (char*)d_ws;
    float* seq = (float*)p;  p += (size_t)NB * SEQROWS * NR * 4;
    u16* ht1 = (u16*)p;  p += (size_t)2 * NB * NR * NW * 2;   // [2 buf][b][r][c] hi
    u16* ht2 = (u16*)p;  p += (size_t)2 * NB * NR * NW * 2;   // lo
    u16* htc1 = (u16*)p; p += (size_t)NB * NW * NR * 2;       // [b][c][r] hi
    u16* htc2 = (u16*)p; p += (size_t)NB * NW * NR * 2;       // lo
    u16* x1  = (u16*)p;  p += (size_t)128 * 4096 * 2;
    u16* x2  = (u16*)p;  p += (size_t)128 * 4096 * 2;
    u16* y1  = (u16*)p;  p += (size_t)NB * NW * 128 * 2;
    u16* y2  = (u16*)p;  p += (size_t)NB * NW * 128 * 2;
    u16* f1  = (u16*)p;  p += (size_t)128 * 512 * 2;
    u16* f2  = (u16*)p;  p += (size_t)128 * 512 * 2;
    u16* gt1 = (u16*)p;  p += (size_t)512 * 128 * 2;
    u16* gt2 = (u16*)p;  p += (size_t)512 * 128 * 2;
    u16* wr1 = (u16*)p;  p += (size_t)NLAY * NM * NW * NW * 2;
    u16* wr2 = (u16*)p;  p += (size_t)NLAY * NM * NW * NW * 2;
    u16* wi1 = (u16*)p;  p += (size_t)NLAY * NM * NW * NW * 2;
    u16* wi2 = (u16*)p;  p += (size_t)NLAY * NM * NW * NW * 2;
    u16* cw1 = (u16*)p;  p += (size_t)NLAY * NW * NW * 2;
    u16* cw2 = (u16*)p;  p += (size_t)NLAY * NW * NW * 2;
    u16* f11 = (u16*)p;  p += (size_t)256 * 128 * 2;
    u16* f12 = (u16*)p;  p += (size_t)256 * 128 * 2;

    const size_t htplane = (size_t)NB * NR * NW;

    build_tables_planes<<<256, 256, 0, stream>>>(f1, f2, gt1, gt2);
    prep_specw<<<512, 256, 0, stream>>>(spec_wr, spec_wi, wr1, wr2, wi1, wi2);
    prep_cw<<<256, 256, 0, stream>>>(conv_w, cw1, cw2);
    prep_fc1t<<<128, 256, 0, stream>>>(fc1_w, f11, f12);
    init_seq_kernel<<<(NB * NTH * NR) / 256, 256, 0, stream>>>(z, seq);

    for (int step = 0; step < NSTEPS; step++) {
        if (step == 0) {
            fc0_kernel<<<dim3(8, 32), 256, 0, stream>>>(seq, t_grid, fc0_w, fc0_b,
                                                        ht1, ht2, htc1, htc2, step);
        }
        int cur = 0;
        for (int l = 0; l < NLAY; l++) {
            const u16* hc1 = ht1 + (size_t)cur * htplane;
            const u16* hc2 = ht2 + (size_t)cur * htplane;
            u16* hn1 = ht1 + (size_t)(cur ^ 1) * htplane;
            u16* hn2 = ht2 + (size_t)(cur ^ 1) * htplane;
            dft_mfma<<<dim3(64, 4), 256, 0, stream>>>(f1, f2, htc1, htc2, x1, x2);
            modemix_mfma<<<dim3(64, 4), 256, 0, stream>>>(x1, x2, wr1, wr2, wi1, wi2,
                                                          y1, y2, l);
            idft_conv_mfma<<<dim3(8, 2, 32), 256, 0, stream>>>(y1, y2, gt1, gt2,
                                                               hc1, hc2, cw1, cw2,
                                                               conv_b, hn1, hn2,
                                                               htc1, htc2, l, (l < 3) ? 1 : 0);
            cur ^= 1;
        }
        // after 4 layers cur == 0; head reads buffer 0 and (if step<11)
        // writes next step's fc0 output into buffer 0 + htc.
        head_mfma<<<256, 256, 0, stream>>>(ht1, ht2, f11, f12, fc1_b, fc2_w, fc2_b,
                                           t_grid, fc0_w, fc0_b, seq, preds,
                                           ht1, ht2, htc1, htc2,
                                           step, (step < NSTEPS - 1) ? 1 : 0);
    }
}